// Round 22
// baseline (1574.973 us; speedup 1.0000x reference)
//
#include <hip/hip_runtime.h>
#include <hip/hip_bf16.h>

typedef __hip_bfloat16 bf16;
typedef short bf16x8 __attribute__((ext_vector_type(8)));   // 8 bf16 = 4 VGPRs
typedef float f32x4 __attribute__((ext_vector_type(4)));

// Problem constants
#define CB 2
#define CS 4096
#define CD 1024
#define CL 512
#define CST 64
#define CH 8
#define CT 640      // 2*ST + L
#define CDH 4096
#define NSEG 8
#define MCH 2048    // MLP M-chunk rows
#define LP 80       // padded LDS row length (bf16) for attn tiles

__device__ __forceinline__ float tof(float x) { return x; }
__device__ __forceinline__ float tof(bf16 x) { return __bfloat162float(x); }
__device__ __forceinline__ void storev(float* p, float v) { *p = v; }
__device__ __forceinline__ void storev(bf16* p, float v) { *p = __float2bfloat16(v); }

__device__ __forceinline__ float ldin(const void* p, size_t i, int f32w) {
    if (f32w) return ((const float*)p)[i];
    return __bfloat162float(((const bf16*)p)[i]);
}

// ---------------------------------------------------------------------------
// Dtype sniffer (proven rounds 2/6-21; resolves flag=0 = bf16 here).
// ---------------------------------------------------------------------------
__global__ void sniff_kernel(const void* x, int* flag) {
    if (threadIdx.x == 0 && blockIdx.x == 0) {
        const bf16* hb = (const bf16*)x;
        int plaus = 0;
        for (int i = 0; i < 256; ++i) {
            float v = __bfloat162float(hb[2 * i]);
            float a = fabsf(v);
            if (v == 0.f || (a > 1e-4f && a < 100.f)) ++plaus;
        }
        flag[0] = (plaus < 128) ? 1 : 0;
    }
}

// ---------------------------------------------------------------------------
// bf16 transpose: out[C][R] = in[R][C], 64x64 tiles. PROVEN rounds 7-21.
// ---------------------------------------------------------------------------
__global__ __launch_bounds__(256) void transpose_kernel(
    const void* __restrict__ in, bf16* __restrict__ out, int R, int C,
    const int* __restrict__ flag)
{
    const int f32w = flag[0];
    __shared__ short t[64][72];
    int tid = threadIdx.x;
    int c0 = blockIdx.x * 64, r0 = blockIdx.y * 64;
    int cc = tid & 63, rr = tid >> 6;
#pragma unroll
    for (int i = 0; i < 16; ++i) {
        bf16 v = __float2bfloat16(ldin(in, (size_t)(r0 + rr + i * 4) * C + c0 + cc, f32w));
        t[rr + i * 4][cc] = *(short*)&v;
    }
    __syncthreads();
#pragma unroll
    for (int i = 0; i < 16; ++i)
        ((short*)out)[(size_t)(c0 + rr + i * 4) * R + r0 + cc] = t[cc][rr + i * 4];
}

// ---------------------------------------------------------------------------
// Merged QKV weight transpose (PROVEN round 21): 3 dispatches -> 1.
// ---------------------------------------------------------------------------
__global__ __launch_bounds__(256) void transpose3_kernel(
    const void* __restrict__ in0, const void* __restrict__ in1, const void* __restrict__ in2,
    bf16* __restrict__ out0, bf16* __restrict__ out1, bf16* __restrict__ out2,
    const int* __restrict__ flag)
{
    const int f32w = flag[0];
    const void* in = (blockIdx.z == 0) ? in0 : (blockIdx.z == 1 ? in1 : in2);
    bf16* out = (blockIdx.z == 0) ? out0 : (blockIdx.z == 1 ? out1 : out2);
    const int R = CD, C = 512;
    __shared__ short t[64][72];
    int tid = threadIdx.x;
    int c0 = blockIdx.x * 64, r0 = blockIdx.y * 64;
    int cc = tid & 63, rr = tid >> 6;
#pragma unroll
    for (int i = 0; i < 16; ++i) {
        bf16 v = __float2bfloat16(ldin(in, (size_t)(r0 + rr + i * 4) * C + c0 + cc, f32w));
        t[rr + i * 4][cc] = *(short*)&v;
    }
    __syncthreads();
#pragma unroll
    for (int i = 0; i < 16; ++i)
        ((short*)out)[(size_t)(c0 + rr + i * 4) * R + r0 + cc] = t[cc][rr + i * 4];
}

// ---------------------------------------------------------------------------
// Per-head 64x64 transpose of Wq1/Wk1/Wv1 (PROVEN rounds 15-21).
// ---------------------------------------------------------------------------
__global__ __launch_bounds__(256) void transposeH_kernel(
    const void* __restrict__ Wq1, const void* __restrict__ Wk1, const void* __restrict__ Wv1,
    bf16* __restrict__ oq, bf16* __restrict__ ok, bf16* __restrict__ ov,
    const int* __restrict__ flag)
{
    const int f32w = flag[0];
    int which = blockIdx.x >> 3, hh = blockIdx.x & 7;
    const void* in = (which == 0) ? Wq1 : (which == 1) ? Wk1 : Wv1;
    bf16* out = (which == 0) ? oq : (which == 1) ? ok : ov;
    __shared__ short t[64][72];
    int tid = threadIdx.x;
    int cc = tid & 63, rr = tid >> 6;
    size_t base = (size_t)hh * 4096;
#pragma unroll
    for (int i = 0; i < 16; ++i) {
        bf16 v = __float2bfloat16(ldin(in, base + (size_t)(rr + i * 4) * 64 + cc, f32w));
        t[rr + i * 4][cc] = *(short*)&v;
    }
    __syncthreads();
#pragma unroll
    for (int i = 0; i < 16; ++i)
        ((short*)out)[base + (size_t)(rr + i * 4) * 64 + cc] = t[cc][rr + i * 4];
}

// ---------------------------------------------------------------------------
// MFMA GEMM, register-staged linear LDS, BK=128 (this round's change):
// halves barrier-pair count per K-loop (16 -> 8 for K=1024) at UNCHANGED
// occupancy (already 2 blocks/CU; LDS 64KB still allows 2). Single-depth
// prefetch (round-13-proven pattern, widened). K % 128 == 0 at all call
// sites (1024, 512, 4096). OUTM=1: Wo epilogue split (a / state / discard).
// ---------------------------------------------------------------------------
template <typename TC, int ACT, int OUTM>
__global__ __launch_bounds__(256) void mfma_lds(
    const bf16* __restrict__ A,
    const bf16* __restrict__ Bt0, const bf16* __restrict__ Bt1, const bf16* __restrict__ Bt2,
    TC* __restrict__ C0, TC* __restrict__ C1, TC* __restrict__ C2,
    const void* __restrict__ bias, int M, int N, int K, int seg,
    const int* __restrict__ flag)
{
    const int f32w = flag[0];
    const bf16* Bt = (blockIdx.z == 0) ? Bt0 : (blockIdx.z == 1 ? Bt1 : Bt2);
    TC* C = (blockIdx.z == 0) ? C0 : (blockIdx.z == 1 ? C1 : C2);

    __shared__ __align__(16) short As[128 * 128];   // 32 KB
    __shared__ __align__(16) short Bs[128 * 128];   // 32 KB

    const int tid = threadIdx.x;
    const int lane = tid & 63;
    const int w = tid >> 6;
    const int wm = w >> 1, wn = w & 1;
    const int bm = blockIdx.x * 128, bn = blockIdx.y * 128;

    f32x4 acc[4][4];
#pragma unroll
    for (int i = 0; i < 4; ++i)
#pragma unroll
        for (int j = 0; j < 4; ++j) acc[i][j] = (f32x4){0.f, 0.f, 0.f, 0.f};

    // per-thread chunk geometry: 2048 chunks of 16B per tile, 8 per thread.
    // chunk c -> row c>>4, k-chunk (c&15); LDS offset c*16B (linear).
    int srow[8], skc[8];
#pragma unroll
    for (int i = 0; i < 8; ++i) {
        int c = i * 256 + tid;
        srow[i] = c >> 4;
        skc[i] = (c & 15) * 8;
    }

    bf16x8 rA[8], rB[8];
#pragma unroll
    for (int i = 0; i < 8; ++i) {
        rA[i] = *(const bf16x8*)(A + (size_t)(bm + srow[i]) * K + skc[i]);
        rB[i] = *(const bf16x8*)(Bt + (size_t)(bn + srow[i]) * K + skc[i]);
    }

    for (int k0 = 0; k0 < K; k0 += 128) {
        __syncthreads();   // previous tile's LDS reads complete
#pragma unroll
        for (int i = 0; i < 8; ++i) {
            *(bf16x8*)&As[(size_t)(i * 256 + tid) * 8] = rA[i];
            *(bf16x8*)&Bs[(size_t)(i * 256 + tid) * 8] = rB[i];
        }
        if (k0 + 128 < K) {   // prefetch next tile; hides under MFMA phase
            int kn = k0 + 128;
#pragma unroll
            for (int i = 0; i < 8; ++i) {
                rA[i] = *(const bf16x8*)(A + (size_t)(bm + srow[i]) * K + kn + skc[i]);
                rB[i] = *(const bf16x8*)(Bt + (size_t)(bn + srow[i]) * K + kn + skc[i]);
            }
        }
        __syncthreads();   // ds_writes visible

#pragma unroll
        for (int kh = 0; kh < 4; ++kh) {
            bf16x8 av[4], bv[4];
            int cl = kh * 4 + (lane >> 4);
#pragma unroll
            for (int mi = 0; mi < 4; ++mi) {
                int r = wm * 64 + mi * 16 + (lane & 15);
                av[mi] = *(const bf16x8*)&As[r * 128 + cl * 8];
            }
#pragma unroll
            for (int nj = 0; nj < 4; ++nj) {
                int r = wn * 64 + nj * 16 + (lane & 15);
                bv[nj] = *(const bf16x8*)&Bs[r * 128 + cl * 8];
            }
#pragma unroll
            for (int mi = 0; mi < 4; ++mi)
#pragma unroll
                for (int nj = 0; nj < 4; ++nj)
                    acc[mi][nj] = __builtin_amdgcn_mfma_f32_16x16x32_bf16(
                        av[mi], bv[nj], acc[mi][nj], 0, 0, 0);
        }
    }

#pragma unroll
    for (int mi = 0; mi < 4; ++mi) {
#pragma unroll
        for (int nj = 0; nj < 4; ++nj) {
            int c = bn + wn * 64 + nj * 16 + (lane & 15);
            float bia = bias ? ldin(bias, c, f32w) : 0.f;
#pragma unroll
            for (int r = 0; r < 4; ++r) {
                int row = bm + wm * 64 + mi * 16 + (lane >> 4) * 4 + r;
                float v = acc[mi][nj][r] + bia;
                if (ACT == 1) v = 0.5f * v * (1.0f + erff(v * 0.70710678118654752f));
                if (OUTM == 0) {
                    storev(C + (size_t)row * N + c, v);
                } else {
                    int bb2 = row / CT, t = row % CT;
                    if (t >= CST) {
                        if (t < CST + CL)
                            storev(C0 + ((size_t)bb2 * CS + (size_t)seg * CL + (t - CST)) * CD + c, v);
                        else
                            storev(C1 + ((size_t)bb2 * CST + (t - CST - CL)) * CD + c, v);
                    }
                }
            }
        }
    }
}

// ---------------------------------------------------------------------------
// RoPE (in-place, bf16) on q and k + LDS-tiled transpose of v -> vt.
// PROVEN rounds 12-21 (separate pass beats all fused variants).
// ---------------------------------------------------------------------------
__global__ __launch_bounds__(256) void ropeV_kernel(
    bf16* __restrict__ q, bf16* __restrict__ k,
    const bf16* __restrict__ v, bf16* __restrict__ vt)
{
    int t0 = blockIdx.x * 64, hh = blockIdx.y, b = blockIdx.z;
    int tid = threadIdx.x;
    __shared__ short lt[64][72];
    int c = tid & 63;
    int r0 = tid >> 6;
    int ip = c >> 1;
    float inv = powf(10000.f, -(float)(2 * ip) / 64.f);
#pragma unroll
    for (int i = 0; i < 16; ++i) {
        int r = r0 + i * 4;
        int t = t0 + r;
        size_t idx = ((size_t)b * CT + t) * 512 + hh * 64 + c;
        float qv = tof(q[idx]);
        float kv = tof(k[idx]);
        float ang = (float)t * inv;
        float sn, cs;
        sincosf(ang, &sn, &cs);
        float qp = __shfl_xor(qv, 1);
        float kp = __shfl_xor(kv, 1);
        float rq, rk;
        if (c & 1) { rq = qp * sn + qv * cs; rk = kp * sn + kv * cs; }
        else       { rq = qv * cs - qp * sn; rk = kv * cs - kp * sn; }
        q[idx] = __float2bfloat16(rq);
        k[idx] = __float2bfloat16(rk);
        lt[r][c] = ((const short*)v)[idx];
    }
    __syncthreads();
#pragma unroll
    for (int i = 0; i < 16; ++i) {
        int c2 = r0 + i * 4;
        int r2 = c;
        ((short*)vt)[((size_t)(b * CH + hh) * 64 + c2) * CT + t0 + r2] = lt[r2][c2];
    }
}

// ---------------------------------------------------------------------------
// MFMA flash attention (core PROVEN rounds 12-21).
// FUSE=1: epilogue computes proj1 + RoPE -> q1/k1 head-major, v1t [d][T].
// ---------------------------------------------------------------------------
template <int FUSE>
__global__ __launch_bounds__(256) void attn_mfma(
    const bf16* __restrict__ q, const bf16* __restrict__ k, const bf16* __restrict__ vt,
    bf16* __restrict__ o,
    int qsb, int qsh, int qst,
    int ksb, int ksh, int kst,
    int ob, int oh, int ot,
    const bf16* __restrict__ Wq1t, const bf16* __restrict__ Wk1t, const bf16* __restrict__ Wv1t,
    bf16* __restrict__ q1o, bf16* __restrict__ k1o, bf16* __restrict__ v1to)
{
    const int tid = threadIdx.x;
    const int lane = tid & 63;
    const int wrow = tid >> 6;
    const int hh = blockIdx.y, b = blockIdx.z;
    const int qbase = ((int)gridDim.x - 1 - (int)blockIdx.x) * 64;

    __shared__ __align__(16) short Qs[64 * LP];
    __shared__ __align__(16) short Ks[64 * LP];
    __shared__ __align__(16) short Vs[64 * LP];
    __shared__ __align__(16) short Ps[64 * LP];

    const size_t qb0 = (size_t)b * qsb + (size_t)hh * qsh;
    const size_t kb0 = (size_t)b * ksb + (size_t)hh * ksh;
    const size_t vtb = (size_t)(b * CH + hh) * 64 * CT;

    int srow[2], skc[2], soff[2];
#pragma unroll
    for (int i = 0; i < 2; ++i) {
        int c = i * 256 + tid;
        srow[i] = c >> 3;
        skc[i] = c & 7;
        soff[i] = srow[i] * LP + skc[i] * 8;
    }

    bf16x8 rQ[2], rK[2], rV[2];
#pragma unroll
    for (int i = 0; i < 2; ++i) {
        rQ[i] = *(const bf16x8*)(q + qb0 + (size_t)(qbase + srow[i]) * qst + skc[i] * 8);
        rK[i] = *(const bf16x8*)(k + kb0 + (size_t)srow[i] * kst + skc[i] * 8);
        rV[i] = *(const bf16x8*)(vt + vtb + (size_t)srow[i] * CT + skc[i] * 8);
    }

    float mrow[4], lrow[4];
    f32x4 oacc[4];
#pragma unroll
    for (int r = 0; r < 4; ++r) { mrow[r] = -1e30f; lrow[r] = 0.f; }
#pragma unroll
    for (int nd = 0; nd < 4; ++nd) oacc[nd] = (f32x4){0.f, 0.f, 0.f, 0.f};

    const int ntiles = qbase / 64 + 1;
    for (int ti = 0; ti < ntiles; ++ti) {
        __syncthreads();
        if (ti == 0) {
#pragma unroll
            for (int i = 0; i < 2; ++i) *(bf16x8*)&Qs[soff[i]] = rQ[i];
        }
#pragma unroll
        for (int i = 0; i < 2; ++i) {
            *(bf16x8*)&Ks[soff[i]] = rK[i];
            *(bf16x8*)&Vs[soff[i]] = rV[i];
        }
        if (ti + 1 < ntiles) {
            int j1 = (ti + 1) * 64;
#pragma unroll
            for (int i = 0; i < 2; ++i) {
                rK[i] = *(const bf16x8*)(k + kb0 + (size_t)(j1 + srow[i]) * kst + skc[i] * 8);
                rV[i] = *(const bf16x8*)(vt + vtb + (size_t)srow[i] * CT + j1 + skc[i] * 8);
            }
        }
        __syncthreads();

        f32x4 sacc[4];
#pragma unroll
        for (int nj = 0; nj < 4; ++nj) sacc[nj] = (f32x4){0.f, 0.f, 0.f, 0.f};
#pragma unroll
        for (int kh = 0; kh < 2; ++kh) {
            int cl = kh * 4 + (lane >> 4);
            bf16x8 av = *(const bf16x8*)&Qs[(wrow * 16 + (lane & 15)) * LP + cl * 8];
#pragma unroll
            for (int nj = 0; nj < 4; ++nj) {
                bf16x8 bv = *(const bf16x8*)&Ks[(nj * 16 + (lane & 15)) * LP + cl * 8];
                sacc[nj] = __builtin_amdgcn_mfma_f32_16x16x32_bf16(av, bv, sacc[nj], 0, 0, 0);
            }
        }

        const bool diag = (ti == ntiles - 1);
        float pm[4] = {-1e30f, -1e30f, -1e30f, -1e30f};
#pragma unroll
        for (int nj = 0; nj < 4; ++nj) {
            int col_l = nj * 16 + (lane & 15);
#pragma unroll
            for (int r = 0; r < 4; ++r) {
                int row_l = wrow * 16 + ((lane >> 4) << 2) + r;
                float s = (diag && col_l > row_l) ? -1e30f : sacc[nj][r] * 0.125f;
                sacc[nj][r] = s;
                pm[r] = fmaxf(pm[r], s);
            }
        }
#pragma unroll
        for (int msk = 1; msk < 16; msk <<= 1)
#pragma unroll
            for (int r = 0; r < 4; ++r) pm[r] = fmaxf(pm[r], __shfl_xor(pm[r], msk));

        float corr[4], rs[4] = {0.f, 0.f, 0.f, 0.f};
#pragma unroll
        for (int r = 0; r < 4; ++r) {
            float mn = fmaxf(mrow[r], pm[r]);
            corr[r] = __expf(mrow[r] - mn);
            mrow[r] = mn;
        }
#pragma unroll
        for (int nj = 0; nj < 4; ++nj)
#pragma unroll
            for (int r = 0; r < 4; ++r) {
                float p = __expf(sacc[nj][r] - mrow[r]);
                sacc[nj][r] = p;
                rs[r] += p;
            }
#pragma unroll
        for (int msk = 1; msk < 16; msk <<= 1)
#pragma unroll
            for (int r = 0; r < 4; ++r) rs[r] += __shfl_xor(rs[r], msk);
#pragma unroll
        for (int r = 0; r < 4; ++r) lrow[r] = lrow[r] * corr[r] + rs[r];
#pragma unroll
        for (int nd = 0; nd < 4; ++nd)
#pragma unroll
            for (int r = 0; r < 4; ++r) oacc[nd][r] *= corr[r];

#pragma unroll
        for (int nj = 0; nj < 4; ++nj)
#pragma unroll
            for (int r = 0; r < 4; ++r) {
                bf16 pb = __float2bfloat16(sacc[nj][r]);
                Ps[(wrow * 16 + ((lane >> 4) << 2) + r) * LP + nj * 16 + (lane & 15)] =
                    *(short*)&pb;
            }

#pragma unroll
        for (int kh = 0; kh < 2; ++kh) {
            int cl = kh * 4 + (lane >> 4);
            bf16x8 pa = *(const bf16x8*)&Ps[(wrow * 16 + (lane & 15)) * LP + cl * 8];
#pragma unroll
            for (int nd = 0; nd < 4; ++nd) {
                bf16x8 bv = *(const bf16x8*)&Vs[(nd * 16 + (lane & 15)) * LP + cl * 8];
                oacc[nd] = __builtin_amdgcn_mfma_f32_16x16x32_bf16(pa, bv, oacc[nd], 0, 0, 0);
            }
        }
    }

    if (FUSE == 0) {
#pragma unroll
        for (int nd = 0; nd < 4; ++nd) {
#pragma unroll
            for (int r = 0; r < 4; ++r) {
                int row_g = qbase + wrow * 16 + ((lane >> 4) << 2) + r;
                int col = nd * 16 + (lane & 15);
                storev(&o[(size_t)b * ob + (size_t)hh * oh + (size_t)row_g * ot + col],
                       oacc[nd][r] / lrow[r]);
            }
        }
    } else {
#pragma unroll
        for (int nd = 0; nd < 4; ++nd)
#pragma unroll
            for (int r = 0; r < 4; ++r) {
                int row_l = wrow * 16 + ((lane >> 4) << 2) + r;
                bf16 ob16 = __float2bfloat16(oacc[nd][r] / lrow[r]);
                Qs[row_l * LP + nd * 16 + (lane & 15)] = *(short*)&ob16;
            }
        __syncthreads();

        const size_t whb = (size_t)hh * 4096;
        f32x4 qa[4], ka[4], va[4];
#pragma unroll
        for (int nj = 0; nj < 4; ++nj) {
            qa[nj] = (f32x4){0.f, 0.f, 0.f, 0.f};
            ka[nj] = (f32x4){0.f, 0.f, 0.f, 0.f};
            va[nj] = (f32x4){0.f, 0.f, 0.f, 0.f};
        }
#pragma unroll
        for (int kh = 0; kh < 2; ++kh) {
            int cl = kh * 4 + (lane >> 4);
            bf16x8 av = *(const bf16x8*)&Qs[(wrow * 16 + (lane & 15)) * LP + cl * 8];
#pragma unroll
            for (int nj = 0; nj < 4; ++nj) {
                int rowb = nj * 16 + (lane & 15);
                bf16x8 bq = *(const bf16x8*)(Wq1t + whb + (size_t)rowb * 64 + cl * 8);
                bf16x8 bk = *(const bf16x8*)(Wk1t + whb + (size_t)rowb * 64 + cl * 8);
                bf16x8 bw = *(const bf16x8*)(Wv1t + whb + (size_t)rowb * 64 + cl * 8);
                qa[nj] = __builtin_amdgcn_mfma_f32_16x16x32_bf16(av, bq, qa[nj], 0, 0, 0);
                ka[nj] = __builtin_amdgcn_mfma_f32_16x16x32_bf16(av, bk, ka[nj], 0, 0, 0);
                va[nj] = __builtin_amdgcn_mfma_f32_16x16x32_bf16(av, bw, va[nj], 0, 0, 0);
            }
        }
        const size_t bh = (size_t)(b * CH + hh);
#pragma unroll
        for (int nj = 0; nj < 4; ++nj) {
            int col = nj * 16 + (lane & 15);
            int ip = col >> 1;
            float inv = powf(10000.f, -(float)(2 * ip) / 64.f);
#pragma unroll
            for (int r = 0; r < 4; ++r) {
                int row_l = wrow * 16 + ((lane >> 4) << 2) + r;
                int t = qbase + row_l;
                float ang = (float)t * inv;
                float sn, cs;
                sincosf(ang, &sn, &cs);
                float aq = qa[nj][r], ak = ka[nj][r];
                float pq = __shfl_xor(aq, 1);
                float pk = __shfl_xor(ak, 1);
                float rq, rk;
                if (col & 1) { rq = pq * sn + aq * cs; rk = pk * sn + ak * cs; }
                else         { rq = aq * cs - pq * sn; rk = ak * cs - pk * sn; }
                size_t roff = (bh * CT + t) * 64 + col;
                q1o[roff] = __float2bfloat16(rq);
                k1o[roff] = __float2bfloat16(rk);
                v1to[(bh * 64 + col) * CT + t] = __float2bfloat16(va[nj][r]);
            }
        }
    }
}

// toks = concat([state, x_seg, state]) -> bf16 (PROVEN; separate pass wins)
__global__ __launch_bounds__(256) void build_toks_kernel(
    const void* __restrict__ x, const float* __restrict__ state, bf16* __restrict__ toks,
    int seg, const int* __restrict__ flag)
{
    const int f32w = flag[0];
    int idx = blockIdx.x * 256 + threadIdx.x;  // B*T*D
    int d = idx & (CD - 1);
    int t = (idx >> 10) % CT;
    int b = idx / (CT * CD);
    float v;
    if (t < CST) v = state[(b * CST + t) * CD + d];
    else if (t < CST + CL) v = ldin(x, ((size_t)b * CS + seg * CL + (t - CST)) * CD + d, f32w);
    else v = state[(b * CST + (t - CST - CL)) * CD + d];
    toks[idx] = __float2bfloat16(v);
}

__global__ __launch_bounds__(256) void init_state_kernel(
    const void* __restrict__ s0, float* __restrict__ state, const int* __restrict__ flag)
{
    const int f32w = flag[0];
    int idx = blockIdx.x * 256 + threadIdx.x;  // B*ST*D
    state[idx] = ldin(s0, idx % (CST * CD), f32w);
}

// LayerNorm(ra + x) * g + b.
__global__ __launch_bounds__(256) void ln_kernel(
    const float* __restrict__ ra, const void* __restrict__ x,
    const void* __restrict__ g, const void* __restrict__ bb,
    void* __restrict__ outp, int out_ext, const int* __restrict__ flag)
{
    const int f32w = flag[0];
    int row = blockIdx.x;
    int tid = threadIdx.x;
    __shared__ float buf[CD];
    __shared__ float red[4];

    float s = 0.f;
    for (int c = tid; c < CD; c += 256) {
        float v = ra[(size_t)row * CD + c] + ldin(x, (size_t)row * CD + c, f32w);
        buf[c] = v;
        s += v;
    }
#pragma unroll
    for (int off = 32; off; off >>= 1) s += __shfl_xor(s, off);
    if ((tid & 63) == 0) red[tid >> 6] = s;
    __syncthreads();
    float mu = (red[0] + red[1] + red[2] + red[3]) * (1.f / CD);
    __syncthreads();

    float vs = 0.f;
    for (int c = tid; c < CD; c += 256) {
        float d0 = buf[c] - mu;
        vs += d0 * d0;
    }
#pragma unroll
    for (int off = 32; off; off >>= 1) vs += __shfl_xor(vs, off);
    if ((tid & 63) == 0) red[tid >> 6] = vs;
    __syncthreads();
    float var = (red[0] + red[1] + red[2] + red[3]) * (1.f / CD);
    float rs = rsqrtf(var + 1e-5f);

    for (int c = tid; c < CD; c += 256) {
        float y = (buf[c] - mu) * rs * ldin(g, c, f32w) + ldin(bb, c, f32w);
        size_t idx = (size_t)row * CD + c;
        if (!out_ext) {
            ((bf16*)outp)[idx] = __float2bfloat16(y);
        } else if (f32w) {
            ((float*)outp)[idx] = y;
        } else {
            ((bf16*)outp)[idx] = __float2bfloat16(y);
        }
    }
}

extern "C" void kernel_launch(void* const* d_in, const int* in_sizes, int n_in,
                              void* d_out, int out_size, void* d_ws, size_t ws_size,
                              hipStream_t stream)
{
    const void* x      = d_in[0];
    const void* s0     = d_in[1];
    const void* Wq0    = d_in[2];
    const void* Wk0    = d_in[3];
    const void* Wv0    = d_in[4];
    const void* Wq1    = d_in[5];
    const void* Wk1    = d_in[6];
    const void* Wv1    = d_in[7];
    const void* Wo     = d_in[8];
    const void* bo     = d_in[9];
    const void* g_attn = d_in[10];
    const void* b_attn = d_in[11];
    const void* W1     = d_in[12];
    const void* b1     = d_in[13];
    const void* W2     = d_in[14];
    const void* b2     = d_in[15];
    const void* g_mlp  = d_in[16];
    const void* b_mlp  = d_in[17];

    // workspace slot layout BYTE-IDENTICAL to passing rounds 2/6-21 (~90.7 MB)
    int* flag = (int*)d_ws;
    float* f = (float*)((char*)d_ws + 16);
    float* toks_slot = f; f += (size_t)CB * CT * CD;       // bf16 toks
    float* q0_slot = f;  f += (size_t)CB * CH * CT * 64;   // bf16 q0 [1280][512]
    float* k0_slot = f;  f += (size_t)CB * CH * CT * 64;   // bf16 k0
    float* v0_slot = f;  f += (size_t)CB * CH * CT * 64;   // bf16 v0
    float* o0_slot = f;  f += (size_t)CB * CH * CT * 64;   // bf16 v0t
    float* q1_slot = f;  f += (size_t)CB * CH * CT * 64;   // bf16 q1
    float* k1_slot = f;  f += (size_t)CB * CH * CT * 64;   // bf16 k1
    float* v1_slot = f;  f += (size_t)CB * CH * CT * 64;   // bf16 v1t
    float* o1t_slot = f; f += (size_t)CB * CT * (CH * 64); // bf16 o1t [1280][512]
    float* seg_slot = f; f += (size_t)CB * CT * CD;        // (free during segments)
    float* state = f;   f += (size_t)CB * CST * CD;        // fp32 state
    float* a = f;       f += (size_t)CB * CS * CD;
    bf16* h = (bf16*)f;                                    // LN1 out [B*S, D] bf16
    bf16* tail = h + (size_t)CB * CS * CD;                 // 8.39 MB tail slot

    bf16* toks = (bf16*)toks_slot;
    bf16* q0b = (bf16*)q0_slot;
    bf16* k0b = (bf16*)k0_slot;
    bf16* v0b = (bf16*)v0_slot;
    bf16* v0t = (bf16*)o0_slot;
    bf16* q1b = (bf16*)q1_slot;
    bf16* k1b = (bf16*)k1_slot;
    bf16* v1t = (bf16*)v1_slot;
    bf16* o1t = (bf16*)o1t_slot;
    bf16* WtQ = h;                                         // h region dead until LN1
    bf16* WtK = WtQ + (size_t)512 * 1024;
    bf16* WtV = WtK + (size_t)512 * 1024;
    bf16* WtO = WtV + (size_t)512 * 1024;                  // [1024][512]
    bf16* WtQ1 = WtO + (size_t)1024 * 512;                 // per-head [8][64][64]
    bf16* WtK1 = WtQ1 + (size_t)8 * 4096;
    bf16* WtV1 = WtK1 + (size_t)8 * 4096;
    // MLP phase (seg region dead): g1 at region base, Wt1 after, Wt2 in tail.
    bf16* g1  = (bf16*)toks_slot;                          // [2048][4096] 16.78 MB
    bf16* Wt1 = g1 + (size_t)MCH * CDH;                    // [CDH][CD]    8.39 MB
    bf16* Wt2 = tail;                                      // [CD][CDH]    8.39 MB

    sniff_kernel<<<1, 64, 0, stream>>>(x, flag);
    init_state_kernel<<<(CB * CST * CD) / 256, 256, 0, stream>>>(s0, state, flag);

    // merged QKV weight transposes (PROVEN round 21)
    transpose3_kernel<<<dim3(8, 16, 3), 256, 0, stream>>>(
        Wq0, Wk0, Wv0, WtQ, WtK, WtV, flag);
    transpose_kernel<<<dim3(16, 8), 256, 0, stream>>>(Wo, WtO, 512, CD, flag);
    transposeH_kernel<<<24, 256, 0, stream>>>(Wq1, Wk1, Wv1, WtQ1, WtK1, WtV1, flag);

    for (int seg = 0; seg < NSEG; ++seg) {
        build_toks_kernel<<<(CB * CT * CD) / 256, 256, 0, stream>>>(x, state, toks, seg, flag);
        // QKV GEMM (BK=128), row-major bf16 outputs
        mfma_lds<bf16, 0, 0><<<dim3(10, 4, 3), 256, 0, stream>>>(
            toks, WtQ, WtK, WtV, q0b, k0b, v0b, nullptr, CB * CT, 512, CD, 0, flag);
        // RoPE q0,k0 in place + V transpose -> v0t (proven separate pass)
        ropeV_kernel<<<dim3(CT / 64, CH, CB), 256, 0, stream>>>(q0b, k0b, v0b, v0t);
        // attn1 (row-major Q/K + v0t) with FUSED proj1+RoPE epilogue
        attn_mfma<1><<<dim3(CT / 64, CH, CB), 256, 0, stream>>>(
            q0b, k0b, v0t, nullptr,
            CT * 512, 64, 512,
            CT * 512, 64, 512,
            0, 0, 0,
            WtQ1, WtK1, WtV1, q1b, k1b, v1t);
        // attn2 (head-major Q/K + v1t) -> o1t token-major bf16 [1280][512]
        attn_mfma<0><<<dim3(CT / 64, CH, CB), 256, 0, stream>>>(
            q1b, k1b, v1t, o1t,
            CH * CT * 64, CT * 64, 64,
            CH * CT * 64, CT * 64, 64,
            CT * 512, 64, 512,
            nullptr, nullptr, nullptr, nullptr, nullptr, nullptr);
        // Wo GEMM (BK=128) with fused epilogue split: L rows -> a, ST -> state
        mfma_lds<float, 0, 1><<<dim3(10, 8, 1), 256, 0, stream>>>(
            o1t, WtO, WtO, WtO, a, state, a, bo, CB * CT, CD, 512, seg, flag);
    }

    // h = LN(a + x) -> bf16 internal (overwrites WtQ..WtV1 — dead by now)
    ln_kernel<<<CB * CS, 256, 0, stream>>>(a, x, g_attn, b_attn, h, 0, flag);

    transpose_kernel<<<dim3(CDH / 64, CD / 64), 256, 0, stream>>>(W1, Wt1, CD, CDH, flag);
    transpose_kernel<<<dim3(CD / 64, CDH / 64), 256, 0, stream>>>(W2, Wt2, CDH, CD, flag);

    // MLP in M-chunks of 2048; both GEMMs (BK=128) plain stores
    for (int c = 0; c < (CB * CS) / MCH; ++c) {
        mfma_lds<bf16, 1, 0><<<dim3(MCH / 128, CDH / 128, 1), 256, 0, stream>>>(
            h + (size_t)c * MCH * CD, Wt1, Wt1, Wt1, g1, g1, g1, b1, MCH, CDH, CD, 0, flag);
        mfma_lds<float, 0, 0><<<dim3(MCH / 128, CD / 128, 1), 256, 0, stream>>>(
            g1, Wt2, Wt2, Wt2,
            a + (size_t)c * MCH * CD, a + (size_t)c * MCH * CD, a + (size_t)c * MCH * CD,
            b2, MCH, CD, CDH, 0, flag);
    }
    ln_kernel<<<CB * CS, 256, 0, stream>>>(a, x, g_mlp, b_mlp, d_out, 1, flag);
}

// Round 23
// 1310.757 us; speedup vs baseline: 1.2016x; 1.2016x over previous
//
#include <hip/hip_runtime.h>
#include <hip/hip_bf16.h>

typedef __hip_bfloat16 bf16;
typedef short bf16x8 __attribute__((ext_vector_type(8)));   // 8 bf16 = 4 VGPRs
typedef float f32x4 __attribute__((ext_vector_type(4)));

// Problem constants
#define CB 2
#define CS 4096
#define CD 1024
#define CL 512
#define CST 64
#define CH 8
#define CT 640      // 2*ST + L
#define CDH 4096
#define NSEG 8
#define MCH 2048    // MLP M-chunk rows
#define LP 80       // padded LDS row length (bf16) for attn tiles

__device__ __forceinline__ float tof(float x) { return x; }
__device__ __forceinline__ float tof(bf16 x) { return __bfloat162float(x); }
__device__ __forceinline__ void storev(float* p, float v) { *p = v; }
__device__ __forceinline__ void storev(bf16* p, float v) { *p = __float2bfloat16(v); }

__device__ __forceinline__ float ldin(const void* p, size_t i, int f32w) {
    if (f32w) return ((const float*)p)[i];
    return __bfloat162float(((const bf16*)p)[i]);
}

// ---------------------------------------------------------------------------
// Dtype sniffer (proven rounds 2/6-22; resolves flag=0 = bf16 here).
// ---------------------------------------------------------------------------
__global__ void sniff_kernel(const void* x, int* flag) {
    if (threadIdx.x == 0 && blockIdx.x == 0) {
        const bf16* hb = (const bf16*)x;
        int plaus = 0;
        for (int i = 0; i < 256; ++i) {
            float v = __bfloat162float(hb[2 * i]);
            float a = fabsf(v);
            if (v == 0.f || (a > 1e-4f && a < 100.f)) ++plaus;
        }
        flag[0] = (plaus < 128) ? 1 : 0;
    }
}

// ---------------------------------------------------------------------------
// bf16 transpose: out[C][R] = in[R][C], 64x64 tiles. PROVEN rounds 7-22.
// ---------------------------------------------------------------------------
__global__ __launch_bounds__(256) void transpose_kernel(
    const void* __restrict__ in, bf16* __restrict__ out, int R, int C,
    const int* __restrict__ flag)
{
    const int f32w = flag[0];
    __shared__ short t[64][72];
    int tid = threadIdx.x;
    int c0 = blockIdx.x * 64, r0 = blockIdx.y * 64;
    int cc = tid & 63, rr = tid >> 6;
#pragma unroll
    for (int i = 0; i < 16; ++i) {
        bf16 v = __float2bfloat16(ldin(in, (size_t)(r0 + rr + i * 4) * C + c0 + cc, f32w));
        t[rr + i * 4][cc] = *(short*)&v;
    }
    __syncthreads();
#pragma unroll
    for (int i = 0; i < 16; ++i)
        ((short*)out)[(size_t)(c0 + rr + i * 4) * R + r0 + cc] = t[cc][rr + i * 4];
}

// ---------------------------------------------------------------------------
// Merged QKV weight transpose (PROVEN round 21): 3 dispatches -> 1.
// ---------------------------------------------------------------------------
__global__ __launch_bounds__(256) void transpose3_kernel(
    const void* __restrict__ in0, const void* __restrict__ in1, const void* __restrict__ in2,
    bf16* __restrict__ out0, bf16* __restrict__ out1, bf16* __restrict__ out2,
    const int* __restrict__ flag)
{
    const int f32w = flag[0];
    const void* in = (blockIdx.z == 0) ? in0 : (blockIdx.z == 1 ? in1 : in2);
    bf16* out = (blockIdx.z == 0) ? out0 : (blockIdx.z == 1 ? out1 : out2);
    const int R = CD, C = 512;
    __shared__ short t[64][72];
    int tid = threadIdx.x;
    int c0 = blockIdx.x * 64, r0 = blockIdx.y * 64;
    int cc = tid & 63, rr = tid >> 6;
#pragma unroll
    for (int i = 0; i < 16; ++i) {
        bf16 v = __float2bfloat16(ldin(in, (size_t)(r0 + rr + i * 4) * C + c0 + cc, f32w));
        t[rr + i * 4][cc] = *(short*)&v;
    }
    __syncthreads();
#pragma unroll
    for (int i = 0; i < 16; ++i)
        ((short*)out)[(size_t)(c0 + rr + i * 4) * R + r0 + cc] = t[cc][rr + i * 4];
}

// ---------------------------------------------------------------------------
// Per-head 64x64 transpose of Wq1/Wk1/Wv1 (PROVEN rounds 15-22).
// ---------------------------------------------------------------------------
__global__ __launch_bounds__(256) void transposeH_kernel(
    const void* __restrict__ Wq1, const void* __restrict__ Wk1, const void* __restrict__ Wv1,
    bf16* __restrict__ oq, bf16* __restrict__ ok, bf16* __restrict__ ov,
    const int* __restrict__ flag)
{
    const int f32w = flag[0];
    int which = blockIdx.x >> 3, hh = blockIdx.x & 7;
    const void* in = (which == 0) ? Wq1 : (which == 1) ? Wk1 : Wv1;
    bf16* out = (which == 0) ? oq : (which == 1) ? ok : ov;
    __shared__ short t[64][72];
    int tid = threadIdx.x;
    int cc = tid & 63, rr = tid >> 6;
    size_t base = (size_t)hh * 4096;
#pragma unroll
    for (int i = 0; i < 16; ++i) {
        bf16 v = __float2bfloat16(ldin(in, base + (size_t)(rr + i * 4) * 64 + cc, f32w));
        t[rr + i * 4][cc] = *(short*)&v;
    }
    __syncthreads();
#pragma unroll
    for (int i = 0; i < 16; ++i)
        ((short*)out)[base + (size_t)(rr + i * 4) * 64 + cc] = t[cc][rr + i * 4];
}

// ---------------------------------------------------------------------------
// MFMA GEMM, register-staged linear LDS, BK=64, DEPTH-2 PREFETCH
// (PROVEN rounds 19/21 — the 1311us configuration; BK=128 regressed 2.3x
// bank conflicts in round 22 and is reverted).
// OUTM=1: Wo epilogue split (a / state / discard).
// ---------------------------------------------------------------------------
template <typename TC, int ACT, int OUTM>
__global__ __launch_bounds__(256) void mfma_lds(
    const bf16* __restrict__ A,
    const bf16* __restrict__ Bt0, const bf16* __restrict__ Bt1, const bf16* __restrict__ Bt2,
    TC* __restrict__ C0, TC* __restrict__ C1, TC* __restrict__ C2,
    const void* __restrict__ bias, int M, int N, int K, int seg,
    const int* __restrict__ flag)
{
    const int f32w = flag[0];
    const bf16* Bt = (blockIdx.z == 0) ? Bt0 : (blockIdx.z == 1 ? Bt1 : Bt2);
    TC* C = (blockIdx.z == 0) ? C0 : (blockIdx.z == 1 ? C1 : C2);

    __shared__ __align__(16) short As[128 * 64];
    __shared__ __align__(16) short Bs[128 * 64];

    const int tid = threadIdx.x;
    const int lane = tid & 63;
    const int w = tid >> 6;
    const int wm = w >> 1, wn = w & 1;
    const int bm = blockIdx.x * 128, bn = blockIdx.y * 128;

    f32x4 acc[4][4];
#pragma unroll
    for (int i = 0; i < 4; ++i)
#pragma unroll
        for (int j = 0; j < 4; ++j) acc[i][j] = (f32x4){0.f, 0.f, 0.f, 0.f};

    int srow[4], skc[4];
#pragma unroll
    for (int i = 0; i < 4; ++i) {
        int c = i * 256 + tid;
        srow[i] = c >> 3;
        skc[i] = (c & 7) * 8;
    }

    bf16x8 rA0[4], rB0[4], rA1[4], rB1[4];
#pragma unroll
    for (int i = 0; i < 4; ++i) {
        rA0[i] = *(const bf16x8*)(A + (size_t)(bm + srow[i]) * K + skc[i]);
        rB0[i] = *(const bf16x8*)(Bt + (size_t)(bn + srow[i]) * K + skc[i]);
        rA1[i] = *(const bf16x8*)(A + (size_t)(bm + srow[i]) * K + 64 + skc[i]);
        rB1[i] = *(const bf16x8*)(Bt + (size_t)(bn + srow[i]) * K + 64 + skc[i]);
    }

#define MFMA_PHASE                                                              \
    _Pragma("unroll")                                                           \
    for (int kh = 0; kh < 2; ++kh) {                                            \
        bf16x8 av[4], bv[4];                                                    \
        _Pragma("unroll")                                                       \
        for (int mi = 0; mi < 4; ++mi) {                                        \
            int r = wm * 64 + mi * 16 + (lane & 15);                            \
            int cl = kh * 4 + (lane >> 4);                                      \
            av[mi] = *(const bf16x8*)&As[r * 64 + cl * 8];                      \
        }                                                                       \
        _Pragma("unroll")                                                       \
        for (int nj = 0; nj < 4; ++nj) {                                        \
            int r = wn * 64 + nj * 16 + (lane & 15);                            \
            int cl = kh * 4 + (lane >> 4);                                      \
            bv[nj] = *(const bf16x8*)&Bs[r * 64 + cl * 8];                      \
        }                                                                       \
        _Pragma("unroll")                                                       \
        for (int mi = 0; mi < 4; ++mi)                                          \
            _Pragma("unroll")                                                   \
            for (int nj = 0; nj < 4; ++nj)                                      \
                acc[mi][nj] = __builtin_amdgcn_mfma_f32_16x16x32_bf16(          \
                    av[mi], bv[nj], acc[mi][nj], 0, 0, 0);                      \
    }

    for (int k0 = 0; k0 < K; k0 += 128) {
        // phase A: tile k0 (from set 0); prefetch k0+128 into set 0
        __syncthreads();
#pragma unroll
        for (int i = 0; i < 4; ++i) {
            *(bf16x8*)&As[(size_t)(i * 256 + tid) * 8] = rA0[i];
            *(bf16x8*)&Bs[(size_t)(i * 256 + tid) * 8] = rB0[i];
        }
        if (k0 + 128 < K) {
            int kn = k0 + 128;
#pragma unroll
            for (int i = 0; i < 4; ++i) {
                rA0[i] = *(const bf16x8*)(A + (size_t)(bm + srow[i]) * K + kn + skc[i]);
                rB0[i] = *(const bf16x8*)(Bt + (size_t)(bn + srow[i]) * K + kn + skc[i]);
            }
        }
        __syncthreads();
        MFMA_PHASE

        // phase B: tile k0+64 (from set 1); prefetch k0+192 into set 1
        __syncthreads();
#pragma unroll
        for (int i = 0; i < 4; ++i) {
            *(bf16x8*)&As[(size_t)(i * 256 + tid) * 8] = rA1[i];
            *(bf16x8*)&Bs[(size_t)(i * 256 + tid) * 8] = rB1[i];
        }
        if (k0 + 192 < K) {
            int kn = k0 + 192;
#pragma unroll
            for (int i = 0; i < 4; ++i) {
                rA1[i] = *(const bf16x8*)(A + (size_t)(bm + srow[i]) * K + kn + skc[i]);
                rB1[i] = *(const bf16x8*)(Bt + (size_t)(bn + srow[i]) * K + kn + skc[i]);
            }
        }
        __syncthreads();
        MFMA_PHASE
    }
#undef MFMA_PHASE

#pragma unroll
    for (int mi = 0; mi < 4; ++mi) {
#pragma unroll
        for (int nj = 0; nj < 4; ++nj) {
            int c = bn + wn * 64 + nj * 16 + (lane & 15);
            float bia = bias ? ldin(bias, c, f32w) : 0.f;
#pragma unroll
            for (int r = 0; r < 4; ++r) {
                int row = bm + wm * 64 + mi * 16 + (lane >> 4) * 4 + r;
                float v = acc[mi][nj][r] + bia;
                if (ACT == 1) v = 0.5f * v * (1.0f + erff(v * 0.70710678118654752f));
                if (OUTM == 0) {
                    storev(C + (size_t)row * N + c, v);
                } else {
                    int bb2 = row / CT, t = row % CT;
                    if (t >= CST) {
                        if (t < CST + CL)
                            storev(C0 + ((size_t)bb2 * CS + (size_t)seg * CL + (t - CST)) * CD + c, v);
                        else
                            storev(C1 + ((size_t)bb2 * CST + (t - CST - CL)) * CD + c, v);
                    }
                }
            }
        }
    }
}

// ---------------------------------------------------------------------------
// RoPE (in-place, bf16) on q and k + LDS-tiled transpose of v -> vt.
// PROVEN rounds 12-22 (separate pass beats all fused variants).
// ---------------------------------------------------------------------------
__global__ __launch_bounds__(256) void ropeV_kernel(
    bf16* __restrict__ q, bf16* __restrict__ k,
    const bf16* __restrict__ v, bf16* __restrict__ vt)
{
    int t0 = blockIdx.x * 64, hh = blockIdx.y, b = blockIdx.z;
    int tid = threadIdx.x;
    __shared__ short lt[64][72];
    int c = tid & 63;
    int r0 = tid >> 6;
    int ip = c >> 1;
    float inv = powf(10000.f, -(float)(2 * ip) / 64.f);
#pragma unroll
    for (int i = 0; i < 16; ++i) {
        int r = r0 + i * 4;
        int t = t0 + r;
        size_t idx = ((size_t)b * CT + t) * 512 + hh * 64 + c;
        float qv = tof(q[idx]);
        float kv = tof(k[idx]);
        float ang = (float)t * inv;
        float sn, cs;
        sincosf(ang, &sn, &cs);
        float qp = __shfl_xor(qv, 1);
        float kp = __shfl_xor(kv, 1);
        float rq, rk;
        if (c & 1) { rq = qp * sn + qv * cs; rk = kp * sn + kv * cs; }
        else       { rq = qv * cs - qp * sn; rk = kv * cs - kp * sn; }
        q[idx] = __float2bfloat16(rq);
        k[idx] = __float2bfloat16(rk);
        lt[r][c] = ((const short*)v)[idx];
    }
    __syncthreads();
#pragma unroll
    for (int i = 0; i < 16; ++i) {
        int c2 = r0 + i * 4;
        int r2 = c;
        ((short*)vt)[((size_t)(b * CH + hh) * 64 + c2) * CT + t0 + r2] = lt[r2][c2];
    }
}

// ---------------------------------------------------------------------------
// MFMA flash attention (core PROVEN rounds 12-22).
// FUSE=1: epilogue computes proj1 + RoPE -> q1/k1 head-major, v1t [d][T].
// ---------------------------------------------------------------------------
template <int FUSE>
__global__ __launch_bounds__(256) void attn_mfma(
    const bf16* __restrict__ q, const bf16* __restrict__ k, const bf16* __restrict__ vt,
    bf16* __restrict__ o,
    int qsb, int qsh, int qst,
    int ksb, int ksh, int kst,
    int ob, int oh, int ot,
    const bf16* __restrict__ Wq1t, const bf16* __restrict__ Wk1t, const bf16* __restrict__ Wv1t,
    bf16* __restrict__ q1o, bf16* __restrict__ k1o, bf16* __restrict__ v1to)
{
    const int tid = threadIdx.x;
    const int lane = tid & 63;
    const int wrow = tid >> 6;
    const int hh = blockIdx.y, b = blockIdx.z;
    const int qbase = ((int)gridDim.x - 1 - (int)blockIdx.x) * 64;

    __shared__ __align__(16) short Qs[64 * LP];
    __shared__ __align__(16) short Ks[64 * LP];
    __shared__ __align__(16) short Vs[64 * LP];
    __shared__ __align__(16) short Ps[64 * LP];

    const size_t qb0 = (size_t)b * qsb + (size_t)hh * qsh;
    const size_t kb0 = (size_t)b * ksb + (size_t)hh * ksh;
    const size_t vtb = (size_t)(b * CH + hh) * 64 * CT;

    int srow[2], skc[2], soff[2];
#pragma unroll
    for (int i = 0; i < 2; ++i) {
        int c = i * 256 + tid;
        srow[i] = c >> 3;
        skc[i] = c & 7;
        soff[i] = srow[i] * LP + skc[i] * 8;
    }

    bf16x8 rQ[2], rK[2], rV[2];
#pragma unroll
    for (int i = 0; i < 2; ++i) {
        rQ[i] = *(const bf16x8*)(q + qb0 + (size_t)(qbase + srow[i]) * qst + skc[i] * 8);
        rK[i] = *(const bf16x8*)(k + kb0 + (size_t)srow[i] * kst + skc[i] * 8);
        rV[i] = *(const bf16x8*)(vt + vtb + (size_t)srow[i] * CT + skc[i] * 8);
    }

    float mrow[4], lrow[4];
    f32x4 oacc[4];
#pragma unroll
    for (int r = 0; r < 4; ++r) { mrow[r] = -1e30f; lrow[r] = 0.f; }
#pragma unroll
    for (int nd = 0; nd < 4; ++nd) oacc[nd] = (f32x4){0.f, 0.f, 0.f, 0.f};

    const int ntiles = qbase / 64 + 1;
    for (int ti = 0; ti < ntiles; ++ti) {
        __syncthreads();
        if (ti == 0) {
#pragma unroll
            for (int i = 0; i < 2; ++i) *(bf16x8*)&Qs[soff[i]] = rQ[i];
        }
#pragma unroll
        for (int i = 0; i < 2; ++i) {
            *(bf16x8*)&Ks[soff[i]] = rK[i];
            *(bf16x8*)&Vs[soff[i]] = rV[i];
        }
        if (ti + 1 < ntiles) {
            int j1 = (ti + 1) * 64;
#pragma unroll
            for (int i = 0; i < 2; ++i) {
                rK[i] = *(const bf16x8*)(k + kb0 + (size_t)(j1 + srow[i]) * kst + skc[i] * 8);
                rV[i] = *(const bf16x8*)(vt + vtb + (size_t)srow[i] * CT + j1 + skc[i] * 8);
            }
        }
        __syncthreads();

        f32x4 sacc[4];
#pragma unroll
        for (int nj = 0; nj < 4; ++nj) sacc[nj] = (f32x4){0.f, 0.f, 0.f, 0.f};
#pragma unroll
        for (int kh = 0; kh < 2; ++kh) {
            int cl = kh * 4 + (lane >> 4);
            bf16x8 av = *(const bf16x8*)&Qs[(wrow * 16 + (lane & 15)) * LP + cl * 8];
#pragma unroll
            for (int nj = 0; nj < 4; ++nj) {
                bf16x8 bv = *(const bf16x8*)&Ks[(nj * 16 + (lane & 15)) * LP + cl * 8];
                sacc[nj] = __builtin_amdgcn_mfma_f32_16x16x32_bf16(av, bv, sacc[nj], 0, 0, 0);
            }
        }

        const bool diag = (ti == ntiles - 1);
        float pm[4] = {-1e30f, -1e30f, -1e30f, -1e30f};
#pragma unroll
        for (int nj = 0; nj < 4; ++nj) {
            int col_l = nj * 16 + (lane & 15);
#pragma unroll
            for (int r = 0; r < 4; ++r) {
                int row_l = wrow * 16 + ((lane >> 4) << 2) + r;
                float s = (diag && col_l > row_l) ? -1e30f : sacc[nj][r] * 0.125f;
                sacc[nj][r] = s;
                pm[r] = fmaxf(pm[r], s);
            }
        }
#pragma unroll
        for (int msk = 1; msk < 16; msk <<= 1)
#pragma unroll
            for (int r = 0; r < 4; ++r) pm[r] = fmaxf(pm[r], __shfl_xor(pm[r], msk));

        float corr[4], rs[4] = {0.f, 0.f, 0.f, 0.f};
#pragma unroll
        for (int r = 0; r < 4; ++r) {
            float mn = fmaxf(mrow[r], pm[r]);
            corr[r] = __expf(mrow[r] - mn);
            mrow[r] = mn;
        }
#pragma unroll
        for (int nj = 0; nj < 4; ++nj)
#pragma unroll
            for (int r = 0; r < 4; ++r) {
                float p = __expf(sacc[nj][r] - mrow[r]);
                sacc[nj][r] = p;
                rs[r] += p;
            }
#pragma unroll
        for (int msk = 1; msk < 16; msk <<= 1)
#pragma unroll
            for (int r = 0; r < 4; ++r) rs[r] += __shfl_xor(rs[r], msk);
#pragma unroll
        for (int r = 0; r < 4; ++r) lrow[r] = lrow[r] * corr[r] + rs[r];
#pragma unroll
        for (int nd = 0; nd < 4; ++nd)
#pragma unroll
            for (int r = 0; r < 4; ++r) oacc[nd][r] *= corr[r];

#pragma unroll
        for (int nj = 0; nj < 4; ++nj)
#pragma unroll
            for (int r = 0; r < 4; ++r) {
                bf16 pb = __float2bfloat16(sacc[nj][r]);
                Ps[(wrow * 16 + ((lane >> 4) << 2) + r) * LP + nj * 16 + (lane & 15)] =
                    *(short*)&pb;
            }

#pragma unroll
        for (int kh = 0; kh < 2; ++kh) {
            int cl = kh * 4 + (lane >> 4);
            bf16x8 pa = *(const bf16x8*)&Ps[(wrow * 16 + (lane & 15)) * LP + cl * 8];
#pragma unroll
            for (int nd = 0; nd < 4; ++nd) {
                bf16x8 bv = *(const bf16x8*)&Vs[(nd * 16 + (lane & 15)) * LP + cl * 8];
                oacc[nd] = __builtin_amdgcn_mfma_f32_16x16x32_bf16(pa, bv, oacc[nd], 0, 0, 0);
            }
        }
    }

    if (FUSE == 0) {
#pragma unroll
        for (int nd = 0; nd < 4; ++nd) {
#pragma unroll
            for (int r = 0; r < 4; ++r) {
                int row_g = qbase + wrow * 16 + ((lane >> 4) << 2) + r;
                int col = nd * 16 + (lane & 15);
                storev(&o[(size_t)b * ob + (size_t)hh * oh + (size_t)row_g * ot + col],
                       oacc[nd][r] / lrow[r]);
            }
        }
    } else {
#pragma unroll
        for (int nd = 0; nd < 4; ++nd)
#pragma unroll
            for (int r = 0; r < 4; ++r) {
                int row_l = wrow * 16 + ((lane >> 4) << 2) + r;
                bf16 ob16 = __float2bfloat16(oacc[nd][r] / lrow[r]);
                Qs[row_l * LP + nd * 16 + (lane & 15)] = *(short*)&ob16;
            }
        __syncthreads();

        const size_t whb = (size_t)hh * 4096;
        f32x4 qa[4], ka[4], va[4];
#pragma unroll
        for (int nj = 0; nj < 4; ++nj) {
            qa[nj] = (f32x4){0.f, 0.f, 0.f, 0.f};
            ka[nj] = (f32x4){0.f, 0.f, 0.f, 0.f};
            va[nj] = (f32x4){0.f, 0.f, 0.f, 0.f};
        }
#pragma unroll
        for (int kh = 0; kh < 2; ++kh) {
            int cl = kh * 4 + (lane >> 4);
            bf16x8 av = *(const bf16x8*)&Qs[(wrow * 16 + (lane & 15)) * LP + cl * 8];
#pragma unroll
            for (int nj = 0; nj < 4; ++nj) {
                int rowb = nj * 16 + (lane & 15);
                bf16x8 bq = *(const bf16x8*)(Wq1t + whb + (size_t)rowb * 64 + cl * 8);
                bf16x8 bk = *(const bf16x8*)(Wk1t + whb + (size_t)rowb * 64 + cl * 8);
                bf16x8 bw = *(const bf16x8*)(Wv1t + whb + (size_t)rowb * 64 + cl * 8);
                qa[nj] = __builtin_amdgcn_mfma_f32_16x16x32_bf16(av, bq, qa[nj], 0, 0, 0);
                ka[nj] = __builtin_amdgcn_mfma_f32_16x16x32_bf16(av, bk, ka[nj], 0, 0, 0);
                va[nj] = __builtin_amdgcn_mfma_f32_16x16x32_bf16(av, bw, va[nj], 0, 0, 0);
            }
        }
        const size_t bh = (size_t)(b * CH + hh);
#pragma unroll
        for (int nj = 0; nj < 4; ++nj) {
            int col = nj * 16 + (lane & 15);
            int ip = col >> 1;
            float inv = powf(10000.f, -(float)(2 * ip) / 64.f);
#pragma unroll
            for (int r = 0; r < 4; ++r) {
                int row_l = wrow * 16 + ((lane >> 4) << 2) + r;
                int t = qbase + row_l;
                float ang = (float)t * inv;
                float sn, cs;
                sincosf(ang, &sn, &cs);
                float aq = qa[nj][r], ak = ka[nj][r];
                float pq = __shfl_xor(aq, 1);
                float pk = __shfl_xor(ak, 1);
                float rq, rk;
                if (col & 1) { rq = pq * sn + aq * cs; rk = pk * sn + ak * cs; }
                else         { rq = aq * cs - pq * sn; rk = ak * cs - pk * sn; }
                size_t roff = (bh * CT + t) * 64 + col;
                q1o[roff] = __float2bfloat16(rq);
                k1o[roff] = __float2bfloat16(rk);
                v1to[(bh * 64 + col) * CT + t] = __float2bfloat16(va[nj][r]);
            }
        }
    }
}

// toks = concat([state, x_seg, state]) -> bf16 (PROVEN; separate pass wins)
__global__ __launch_bounds__(256) void build_toks_kernel(
    const void* __restrict__ x, const float* __restrict__ state, bf16* __restrict__ toks,
    int seg, const int* __restrict__ flag)
{
    const int f32w = flag[0];
    int idx = blockIdx.x * 256 + threadIdx.x;  // B*T*D
    int d = idx & (CD - 1);
    int t = (idx >> 10) % CT;
    int b = idx / (CT * CD);
    float v;
    if (t < CST) v = state[(b * CST + t) * CD + d];
    else if (t < CST + CL) v = ldin(x, ((size_t)b * CS + seg * CL + (t - CST)) * CD + d, f32w);
    else v = state[(b * CST + (t - CST - CL)) * CD + d];
    toks[idx] = __float2bfloat16(v);
}

__global__ __launch_bounds__(256) void init_state_kernel(
    const void* __restrict__ s0, float* __restrict__ state, const int* __restrict__ flag)
{
    const int f32w = flag[0];
    int idx = blockIdx.x * 256 + threadIdx.x;  // B*ST*D
    state[idx] = ldin(s0, idx % (CST * CD), f32w);
}

// LayerNorm(ra + x) * g + b.
__global__ __launch_bounds__(256) void ln_kernel(
    const float* __restrict__ ra, const void* __restrict__ x,
    const void* __restrict__ g, const void* __restrict__ bb,
    void* __restrict__ outp, int out_ext, const int* __restrict__ flag)
{
    const int f32w = flag[0];
    int row = blockIdx.x;
    int tid = threadIdx.x;
    __shared__ float buf[CD];
    __shared__ float red[4];

    float s = 0.f;
    for (int c = tid; c < CD; c += 256) {
        float v = ra[(size_t)row * CD + c] + ldin(x, (size_t)row * CD + c, f32w);
        buf[c] = v;
        s += v;
    }
#pragma unroll
    for (int off = 32; off; off >>= 1) s += __shfl_xor(s, off);
    if ((tid & 63) == 0) red[tid >> 6] = s;
    __syncthreads();
    float mu = (red[0] + red[1] + red[2] + red[3]) * (1.f / CD);
    __syncthreads();

    float vs = 0.f;
    for (int c = tid; c < CD; c += 256) {
        float d0 = buf[c] - mu;
        vs += d0 * d0;
    }
#pragma unroll
    for (int off = 32; off; off >>= 1) vs += __shfl_xor(vs, off);
    if ((tid & 63) == 0) red[tid >> 6] = vs;
    __syncthreads();
    float var = (red[0] + red[1] + red[2] + red[3]) * (1.f / CD);
    float rs = rsqrtf(var + 1e-5f);

    for (int c = tid; c < CD; c += 256) {
        float y = (buf[c] - mu) * rs * ldin(g, c, f32w) + ldin(bb, c, f32w);
        size_t idx = (size_t)row * CD + c;
        if (!out_ext) {
            ((bf16*)outp)[idx] = __float2bfloat16(y);
        } else if (f32w) {
            ((float*)outp)[idx] = y;
        } else {
            ((bf16*)outp)[idx] = __float2bfloat16(y);
        }
    }
}

extern "C" void kernel_launch(void* const* d_in, const int* in_sizes, int n_in,
                              void* d_out, int out_size, void* d_ws, size_t ws_size,
                              hipStream_t stream)
{
    const void* x      = d_in[0];
    const void* s0     = d_in[1];
    const void* Wq0    = d_in[2];
    const void* Wk0    = d_in[3];
    const void* Wv0    = d_in[4];
    const void* Wq1    = d_in[5];
    const void* Wk1    = d_in[6];
    const void* Wv1    = d_in[7];
    const void* Wo     = d_in[8];
    const void* bo     = d_in[9];
    const void* g_attn = d_in[10];
    const void* b_attn = d_in[11];
    const void* W1     = d_in[12];
    const void* b1     = d_in[13];
    const void* W2     = d_in[14];
    const void* b2     = d_in[15];
    const void* g_mlp  = d_in[16];
    const void* b_mlp  = d_in[17];

    // workspace slot layout BYTE-IDENTICAL to passing rounds 2/6-22 (~90.7 MB)
    int* flag = (int*)d_ws;
    float* f = (float*)((char*)d_ws + 16);
    float* toks_slot = f; f += (size_t)CB * CT * CD;       // bf16 toks
    float* q0_slot = f;  f += (size_t)CB * CH * CT * 64;   // bf16 q0 [1280][512]
    float* k0_slot = f;  f += (size_t)CB * CH * CT * 64;   // bf16 k0
    float* v0_slot = f;  f += (size_t)CB * CH * CT * 64;   // bf16 v0
    float* o0_slot = f;  f += (size_t)CB * CH * CT * 64;   // bf16 v0t
    float* q1_slot = f;  f += (size_t)CB * CH * CT * 64;   // bf16 q1
    float* k1_slot = f;  f += (size_t)CB * CH * CT * 64;   // bf16 k1
    float* v1_slot = f;  f += (size_t)CB * CH * CT * 64;   // bf16 v1t
    float* o1t_slot = f; f += (size_t)CB * CT * (CH * 64); // bf16 o1t [1280][512]
    float* seg_slot = f; f += (size_t)CB * CT * CD;        // (free during segments)
    float* state = f;   f += (size_t)CB * CST * CD;        // fp32 state
    float* a = f;       f += (size_t)CB * CS * CD;
    bf16* h = (bf16*)f;                                    // LN1 out [B*S, D] bf16
    bf16* tail = h + (size_t)CB * CS * CD;                 // 8.39 MB tail slot

    bf16* toks = (bf16*)toks_slot;
    bf16* q0b = (bf16*)q0_slot;
    bf16* k0b = (bf16*)k0_slot;
    bf16* v0b = (bf16*)v0_slot;
    bf16* v0t = (bf16*)o0_slot;
    bf16* q1b = (bf16*)q1_slot;
    bf16* k1b = (bf16*)k1_slot;
    bf16* v1t = (bf16*)v1_slot;
    bf16* o1t = (bf16*)o1t_slot;
    bf16* WtQ = h;                                         // h region dead until LN1
    bf16* WtK = WtQ + (size_t)512 * 1024;
    bf16* WtV = WtK + (size_t)512 * 1024;
    bf16* WtO = WtV + (size_t)512 * 1024;                  // [1024][512]
    bf16* WtQ1 = WtO + (size_t)1024 * 512;                 // per-head [8][64][64]
    bf16* WtK1 = WtQ1 + (size_t)8 * 4096;
    bf16* WtV1 = WtK1 + (size_t)8 * 4096;
    // MLP phase (seg region dead): g1 at region base, Wt1 after, Wt2 in tail.
    bf16* g1  = (bf16*)toks_slot;                          // [2048][4096] 16.78 MB
    bf16* Wt1 = g1 + (size_t)MCH * CDH;                    // [CDH][CD]    8.39 MB
    bf16* Wt2 = tail;                                      // [CD][CDH]    8.39 MB

    sniff_kernel<<<1, 64, 0, stream>>>(x, flag);
    init_state_kernel<<<(CB * CST * CD) / 256, 256, 0, stream>>>(s0, state, flag);

    // merged QKV weight transposes (PROVEN round 21)
    transpose3_kernel<<<dim3(8, 16, 3), 256, 0, stream>>>(
        Wq0, Wk0, Wv0, WtQ, WtK, WtV, flag);
    transpose_kernel<<<dim3(16, 8), 256, 0, stream>>>(Wo, WtO, 512, CD, flag);
    transposeH_kernel<<<24, 256, 0, stream>>>(Wq1, Wk1, Wv1, WtQ1, WtK1, WtV1, flag);

    for (int seg = 0; seg < NSEG; ++seg) {
        build_toks_kernel<<<(CB * CT * CD) / 256, 256, 0, stream>>>(x, state, toks, seg, flag);
        // QKV GEMM (proven path), row-major bf16 outputs
        mfma_lds<bf16, 0, 0><<<dim3(10, 4, 3), 256, 0, stream>>>(
            toks, WtQ, WtK, WtV, q0b, k0b, v0b, nullptr, CB * CT, 512, CD, 0, flag);
        // RoPE q0,k0 in place + V transpose -> v0t (proven separate pass)
        ropeV_kernel<<<dim3(CT / 64, CH, CB), 256, 0, stream>>>(q0b, k0b, v0b, v0t);
        // attn1 (row-major Q/K + v0t) with FUSED proj1+RoPE epilogue
        attn_mfma<1><<<dim3(CT / 64, CH, CB), 256, 0, stream>>>(
            q0b, k0b, v0t, nullptr,
            CT * 512, 64, 512,
            CT * 512, 64, 512,
            0, 0, 0,
            WtQ1, WtK1, WtV1, q1b, k1b, v1t);
        // attn2 (head-major Q/K + v1t) -> o1t token-major bf16 [1280][512]
        attn_mfma<0><<<dim3(CT / 64, CH, CB), 256, 0, stream>>>(
            q1b, k1b, v1t, o1t,
            CH * CT * 64, CT * 64, 64,
            CH * CT * 64, CT * 64, 64,
            CT * 512, 64, 512,
            nullptr, nullptr, nullptr, nullptr, nullptr, nullptr);
        // Wo GEMM with fused epilogue split: middle L rows -> a, last ST -> state
        mfma_lds<float, 0, 1><<<dim3(10, 8, 1), 256, 0, stream>>>(
            o1t, WtO, WtO, WtO, a, state, a, bo, CB * CT, CD, 512, seg, flag);
    }

    // h = LN(a + x) -> bf16 internal (overwrites WtQ..WtV1 — dead by now)
    ln_kernel<<<CB * CS, 256, 0, stream>>>(a, x, g_attn, b_attn, h, 0, flag);

    transpose_kernel<<<dim3(CDH / 64, CD / 64), 256, 0, stream>>>(W1, Wt1, CD, CDH, flag);
    transpose_kernel<<<dim3(CD / 64, CDH / 64), 256, 0, stream>>>(W2, Wt2, CDH, CD, flag);

    // MLP in M-chunks of 2048; both GEMMs plain stores (PROVEN config)
    for (int c = 0; c < (CB * CS) / MCH; ++c) {
        mfma_lds<bf16, 1, 0><<<dim3(MCH / 128, CDH / 128, 1), 256, 0, stream>>>(
            h + (size_t)c * MCH * CD, Wt1, Wt1, Wt1, g1, g1, g1, b1, MCH, CDH, CD, 0, flag);
        mfma_lds<float, 0, 0><<<dim3(MCH / 128, CD / 128, 1), 256, 0, stream>>>(
            g1, Wt2, Wt2, Wt2,
            a + (size_t)c * MCH * CD, a + (size_t)c * MCH * CD, a + (size_t)c * MCH * CD,
            b2, MCH, CD, CDH, 0, flag);
    }
    ln_kernel<<<CB * CS, 256, 0, stream>>>(a, x, g_mlp, b_mlp, d_out, 1, flag);
}

// Round 24
// 1214.422 us; speedup vs baseline: 1.2969x; 1.0793x over previous
//
#include <hip/hip_runtime.h>
#include <hip/hip_bf16.h>

typedef __hip_bfloat16 bf16;
typedef short bf16x8 __attribute__((ext_vector_type(8)));   // 8 bf16 = 4 VGPRs
typedef float f32x4 __attribute__((ext_vector_type(4)));

// Problem constants
#define CB 2
#define CS 4096
#define CD 1024
#define CL 512
#define CST 64
#define CH 8
#define CT 640      // 2*ST + L
#define CDH 4096
#define NSEG 8
#define LP 80       // padded LDS row length (bf16) for attn tiles

__device__ __forceinline__ float tof(float x) { return x; }
__device__ __forceinline__ float tof(bf16 x) { return __bfloat162float(x); }
__device__ __forceinline__ void storev(float* p, float v) { *p = v; }
__device__ __forceinline__ void storev(bf16* p, float v) { *p = __float2bfloat16(v); }

__device__ __forceinline__ float ldin(const void* p, size_t i, int f32w) {
    if (f32w) return ((const float*)p)[i];
    return __bfloat162float(((const bf16*)p)[i]);
}

// ---------------------------------------------------------------------------
// Dtype sniffer (proven rounds 2/6-23; resolves flag=0 = bf16 here).
// ---------------------------------------------------------------------------
__global__ void sniff_kernel(const void* x, int* flag) {
    if (threadIdx.x == 0 && blockIdx.x == 0) {
        const bf16* hb = (const bf16*)x;
        int plaus = 0;
        for (int i = 0; i < 256; ++i) {
            float v = __bfloat162float(hb[2 * i]);
            float a = fabsf(v);
            if (v == 0.f || (a > 1e-4f && a < 100.f)) ++plaus;
        }
        flag[0] = (plaus < 128) ? 1 : 0;
    }
}

// ---------------------------------------------------------------------------
// bf16 transpose: out[C][R] = in[R][C], 64x64 tiles. PROVEN rounds 7-23.
// ---------------------------------------------------------------------------
__global__ __launch_bounds__(256) void transpose_kernel(
    const void* __restrict__ in, bf16* __restrict__ out, int R, int C,
    const int* __restrict__ flag)
{
    const int f32w = flag[0];
    __shared__ short t[64][72];
    int tid = threadIdx.x;
    int c0 = blockIdx.x * 64, r0 = blockIdx.y * 64;
    int cc = tid & 63, rr = tid >> 6;
#pragma unroll
    for (int i = 0; i < 16; ++i) {
        bf16 v = __float2bfloat16(ldin(in, (size_t)(r0 + rr + i * 4) * C + c0 + cc, f32w));
        t[rr + i * 4][cc] = *(short*)&v;
    }
    __syncthreads();
#pragma unroll
    for (int i = 0; i < 16; ++i)
        ((short*)out)[(size_t)(c0 + rr + i * 4) * R + r0 + cc] = t[cc][rr + i * 4];
}

// ---------------------------------------------------------------------------
// Merged QKV weight transpose (PROVEN rounds 21-23): 3 dispatches -> 1.
// ---------------------------------------------------------------------------
__global__ __launch_bounds__(256) void transpose3_kernel(
    const void* __restrict__ in0, const void* __restrict__ in1, const void* __restrict__ in2,
    bf16* __restrict__ out0, bf16* __restrict__ out1, bf16* __restrict__ out2,
    const int* __restrict__ flag)
{
    const int f32w = flag[0];
    const void* in = (blockIdx.z == 0) ? in0 : (blockIdx.z == 1 ? in1 : in2);
    bf16* out = (blockIdx.z == 0) ? out0 : (blockIdx.z == 1 ? out1 : out2);
    const int R = CD, C = 512;
    __shared__ short t[64][72];
    int tid = threadIdx.x;
    int c0 = blockIdx.x * 64, r0 = blockIdx.y * 64;
    int cc = tid & 63, rr = tid >> 6;
#pragma unroll
    for (int i = 0; i < 16; ++i) {
        bf16 v = __float2bfloat16(ldin(in, (size_t)(r0 + rr + i * 4) * C + c0 + cc, f32w));
        t[rr + i * 4][cc] = *(short*)&v;
    }
    __syncthreads();
#pragma unroll
    for (int i = 0; i < 16; ++i)
        ((short*)out)[(size_t)(c0 + rr + i * 4) * R + r0 + cc] = t[cc][rr + i * 4];
}

// ---------------------------------------------------------------------------
// Per-head 64x64 transpose of Wq1/Wk1/Wv1 (PROVEN rounds 15-23).
// ---------------------------------------------------------------------------
__global__ __launch_bounds__(256) void transposeH_kernel(
    const void* __restrict__ Wq1, const void* __restrict__ Wk1, const void* __restrict__ Wv1,
    bf16* __restrict__ oq, bf16* __restrict__ ok, bf16* __restrict__ ov,
    const int* __restrict__ flag)
{
    const int f32w = flag[0];
    int which = blockIdx.x >> 3, hh = blockIdx.x & 7;
    const void* in = (which == 0) ? Wq1 : (which == 1) ? Wk1 : Wv1;
    bf16* out = (which == 0) ? oq : (which == 1) ? ok : ov;
    __shared__ short t[64][72];
    int tid = threadIdx.x;
    int cc = tid & 63, rr = tid >> 6;
    size_t base = (size_t)hh * 4096;
#pragma unroll
    for (int i = 0; i < 16; ++i) {
        bf16 v = __float2bfloat16(ldin(in, base + (size_t)(rr + i * 4) * 64 + cc, f32w));
        t[rr + i * 4][cc] = *(short*)&v;
    }
    __syncthreads();
#pragma unroll
    for (int i = 0; i < 16; ++i)
        ((short*)out)[base + (size_t)(rr + i * 4) * 64 + cc] = t[cc][rr + i * 4];
}

// ---------------------------------------------------------------------------
// MFMA GEMM, register-staged linear LDS, BK=64, DEPTH-2 PREFETCH
// (PROVEN rounds 19/21/23 — the 1311us configuration), now with lda/ldb
// strides, bias column offset boff, and ACCUM mode (epilogue adds previous C
// contents; round-15/16-proven sequential K-chunk accumulation, no atomics).
// Plain call sites pass lda=ldb=K, boff=0, ACCUM=0 (identical codegen).
// OUTM=1: Wo epilogue split (a / state / discard).
// ---------------------------------------------------------------------------
template <typename TC, int ACT, int OUTM, int ACCUM>
__global__ __launch_bounds__(256) void mfma_lds(
    const bf16* __restrict__ A,
    const bf16* __restrict__ Bt0, const bf16* __restrict__ Bt1, const bf16* __restrict__ Bt2,
    TC* __restrict__ C0, TC* __restrict__ C1, TC* __restrict__ C2,
    const void* __restrict__ bias, int boff,
    int M, int N, int K, int lda, int ldb, int seg,
    const int* __restrict__ flag)
{
    const int f32w = flag[0];
    const bf16* Bt = (blockIdx.z == 0) ? Bt0 : (blockIdx.z == 1 ? Bt1 : Bt2);
    TC* C = (blockIdx.z == 0) ? C0 : (blockIdx.z == 1 ? C1 : C2);

    __shared__ __align__(16) short As[128 * 64];
    __shared__ __align__(16) short Bs[128 * 64];

    const int tid = threadIdx.x;
    const int lane = tid & 63;
    const int w = tid >> 6;
    const int wm = w >> 1, wn = w & 1;
    const int bm = blockIdx.x * 128, bn = blockIdx.y * 128;

    f32x4 acc[4][4];
#pragma unroll
    for (int i = 0; i < 4; ++i)
#pragma unroll
        for (int j = 0; j < 4; ++j) acc[i][j] = (f32x4){0.f, 0.f, 0.f, 0.f};

    int srow[4], skc[4];
#pragma unroll
    for (int i = 0; i < 4; ++i) {
        int c = i * 256 + tid;
        srow[i] = c >> 3;
        skc[i] = (c & 7) * 8;
    }

    bf16x8 rA0[4], rB0[4], rA1[4], rB1[4];
#pragma unroll
    for (int i = 0; i < 4; ++i) {
        rA0[i] = *(const bf16x8*)(A + (size_t)(bm + srow[i]) * lda + skc[i]);
        rB0[i] = *(const bf16x8*)(Bt + (size_t)(bn + srow[i]) * ldb + skc[i]);
        rA1[i] = *(const bf16x8*)(A + (size_t)(bm + srow[i]) * lda + 64 + skc[i]);
        rB1[i] = *(const bf16x8*)(Bt + (size_t)(bn + srow[i]) * ldb + 64 + skc[i]);
    }

#define MFMA_PHASE                                                              \
    _Pragma("unroll")                                                           \
    for (int kh = 0; kh < 2; ++kh) {                                            \
        bf16x8 av[4], bv[4];                                                    \
        _Pragma("unroll")                                                       \
        for (int mi = 0; mi < 4; ++mi) {                                        \
            int r = wm * 64 + mi * 16 + (lane & 15);                            \
            int cl = kh * 4 + (lane >> 4);                                      \
            av[mi] = *(const bf16x8*)&As[r * 64 + cl * 8];                      \
        }                                                                       \
        _Pragma("unroll")                                                       \
        for (int nj = 0; nj < 4; ++nj) {                                        \
            int r = wn * 64 + nj * 16 + (lane & 15);                            \
            int cl = kh * 4 + (lane >> 4);                                      \
            bv[nj] = *(const bf16x8*)&Bs[r * 64 + cl * 8];                      \
        }                                                                       \
        _Pragma("unroll")                                                       \
        for (int mi = 0; mi < 4; ++mi)                                          \
            _Pragma("unroll")                                                   \
            for (int nj = 0; nj < 4; ++nj)                                      \
                acc[mi][nj] = __builtin_amdgcn_mfma_f32_16x16x32_bf16(          \
                    av[mi], bv[nj], acc[mi][nj], 0, 0, 0);                      \
    }

    for (int k0 = 0; k0 < K; k0 += 128) {
        // phase A: tile k0 (from set 0); prefetch k0+128 into set 0
        __syncthreads();
#pragma unroll
        for (int i = 0; i < 4; ++i) {
            *(bf16x8*)&As[(size_t)(i * 256 + tid) * 8] = rA0[i];
            *(bf16x8*)&Bs[(size_t)(i * 256 + tid) * 8] = rB0[i];
        }
        if (k0 + 128 < K) {
            int kn = k0 + 128;
#pragma unroll
            for (int i = 0; i < 4; ++i) {
                rA0[i] = *(const bf16x8*)(A + (size_t)(bm + srow[i]) * lda + kn + skc[i]);
                rB0[i] = *(const bf16x8*)(Bt + (size_t)(bn + srow[i]) * ldb + kn + skc[i]);
            }
        }
        __syncthreads();
        MFMA_PHASE

        // phase B: tile k0+64 (from set 1); prefetch k0+192 into set 1
        __syncthreads();
#pragma unroll
        for (int i = 0; i < 4; ++i) {
            *(bf16x8*)&As[(size_t)(i * 256 + tid) * 8] = rA1[i];
            *(bf16x8*)&Bs[(size_t)(i * 256 + tid) * 8] = rB1[i];
        }
        if (k0 + 192 < K) {
            int kn = k0 + 192;
#pragma unroll
            for (int i = 0; i < 4; ++i) {
                rA1[i] = *(const bf16x8*)(A + (size_t)(bm + srow[i]) * lda + kn + skc[i]);
                rB1[i] = *(const bf16x8*)(Bt + (size_t)(bn + srow[i]) * ldb + kn + skc[i]);
            }
        }
        __syncthreads();
        MFMA_PHASE
    }
#undef MFMA_PHASE

#pragma unroll
    for (int mi = 0; mi < 4; ++mi) {
#pragma unroll
        for (int nj = 0; nj < 4; ++nj) {
            int c = bn + wn * 64 + nj * 16 + (lane & 15);
            float bia = bias ? ldin(bias, boff + c, f32w) : 0.f;
#pragma unroll
            for (int r = 0; r < 4; ++r) {
                int row = bm + wm * 64 + mi * 16 + (lane >> 4) * 4 + r;
                float v = acc[mi][nj][r] + bia;
                if (ACT == 1) v = 0.5f * v * (1.0f + erff(v * 0.70710678118654752f));
                if (OUTM == 0) {
                    if (ACCUM) v += tof(C[(size_t)row * N + c]);
                    storev(C + (size_t)row * N + c, v);
                } else {
                    int bb2 = row / CT, t = row % CT;
                    if (t >= CST) {
                        if (t < CST + CL)
                            storev(C0 + ((size_t)bb2 * CS + (size_t)seg * CL + (t - CST)) * CD + c, v);
                        else
                            storev(C1 + ((size_t)bb2 * CST + (t - CST - CL)) * CD + c, v);
                    }
                }
            }
        }
    }
}

// ---------------------------------------------------------------------------
// RoPE (in-place, bf16) on q and k + LDS-tiled transpose of v -> vt.
// PROVEN rounds 12-23.
// ---------------------------------------------------------------------------
__global__ __launch_bounds__(256) void ropeV_kernel(
    bf16* __restrict__ q, bf16* __restrict__ k,
    const bf16* __restrict__ v, bf16* __restrict__ vt)
{
    int t0 = blockIdx.x * 64, hh = blockIdx.y, b = blockIdx.z;
    int tid = threadIdx.x;
    __shared__ short lt[64][72];
    int c = tid & 63;
    int r0 = tid >> 6;
    int ip = c >> 1;
    float inv = powf(10000.f, -(float)(2 * ip) / 64.f);
#pragma unroll
    for (int i = 0; i < 16; ++i) {
        int r = r0 + i * 4;
        int t = t0 + r;
        size_t idx = ((size_t)b * CT + t) * 512 + hh * 64 + c;
        float qv = tof(q[idx]);
        float kv = tof(k[idx]);
        float ang = (float)t * inv;
        float sn, cs;
        sincosf(ang, &sn, &cs);
        float qp = __shfl_xor(qv, 1);
        float kp = __shfl_xor(kv, 1);
        float rq, rk;
        if (c & 1) { rq = qp * sn + qv * cs; rk = kp * sn + kv * cs; }
        else       { rq = qv * cs - qp * sn; rk = kv * cs - kp * sn; }
        q[idx] = __float2bfloat16(rq);
        k[idx] = __float2bfloat16(rk);
        lt[r][c] = ((const short*)v)[idx];
    }
    __syncthreads();
#pragma unroll
    for (int i = 0; i < 16; ++i) {
        int c2 = r0 + i * 4;
        int r2 = c;
        ((short*)vt)[((size_t)(b * CH + hh) * 64 + c2) * CT + t0 + r2] = lt[r2][c2];
    }
}

// ---------------------------------------------------------------------------
// MFMA flash attention (core PROVEN rounds 12-23).
// FUSE=1: epilogue computes proj1 + RoPE -> q1/k1 head-major, v1t [d][T].
// ---------------------------------------------------------------------------
template <int FUSE>
__global__ __launch_bounds__(256) void attn_mfma(
    const bf16* __restrict__ q, const bf16* __restrict__ k, const bf16* __restrict__ vt,
    bf16* __restrict__ o,
    int qsb, int qsh, int qst,
    int ksb, int ksh, int kst,
    int ob, int oh, int ot,
    const bf16* __restrict__ Wq1t, const bf16* __restrict__ Wk1t, const bf16* __restrict__ Wv1t,
    bf16* __restrict__ q1o, bf16* __restrict__ k1o, bf16* __restrict__ v1to)
{
    const int tid = threadIdx.x;
    const int lane = tid & 63;
    const int wrow = tid >> 6;
    const int hh = blockIdx.y, b = blockIdx.z;
    const int qbase = ((int)gridDim.x - 1 - (int)blockIdx.x) * 64;

    __shared__ __align__(16) short Qs[64 * LP];
    __shared__ __align__(16) short Ks[64 * LP];
    __shared__ __align__(16) short Vs[64 * LP];
    __shared__ __align__(16) short Ps[64 * LP];

    const size_t qb0 = (size_t)b * qsb + (size_t)hh * qsh;
    const size_t kb0 = (size_t)b * ksb + (size_t)hh * ksh;
    const size_t vtb = (size_t)(b * CH + hh) * 64 * CT;

    int srow[2], skc[2], soff[2];
#pragma unroll
    for (int i = 0; i < 2; ++i) {
        int c = i * 256 + tid;
        srow[i] = c >> 3;
        skc[i] = c & 7;
        soff[i] = srow[i] * LP + skc[i] * 8;
    }

    bf16x8 rQ[2], rK[2], rV[2];
#pragma unroll
    for (int i = 0; i < 2; ++i) {
        rQ[i] = *(const bf16x8*)(q + qb0 + (size_t)(qbase + srow[i]) * qst + skc[i] * 8);
        rK[i] = *(const bf16x8*)(k + kb0 + (size_t)srow[i] * kst + skc[i] * 8);
        rV[i] = *(const bf16x8*)(vt + vtb + (size_t)srow[i] * CT + skc[i] * 8);
    }

    float mrow[4], lrow[4];
    f32x4 oacc[4];
#pragma unroll
    for (int r = 0; r < 4; ++r) { mrow[r] = -1e30f; lrow[r] = 0.f; }
#pragma unroll
    for (int nd = 0; nd < 4; ++nd) oacc[nd] = (f32x4){0.f, 0.f, 0.f, 0.f};

    const int ntiles = qbase / 64 + 1;
    for (int ti = 0; ti < ntiles; ++ti) {
        __syncthreads();
        if (ti == 0) {
#pragma unroll
            for (int i = 0; i < 2; ++i) *(bf16x8*)&Qs[soff[i]] = rQ[i];
        }
#pragma unroll
        for (int i = 0; i < 2; ++i) {
            *(bf16x8*)&Ks[soff[i]] = rK[i];
            *(bf16x8*)&Vs[soff[i]] = rV[i];
        }
        if (ti + 1 < ntiles) {
            int j1 = (ti + 1) * 64;
#pragma unroll
            for (int i = 0; i < 2; ++i) {
                rK[i] = *(const bf16x8*)(k + kb0 + (size_t)(j1 + srow[i]) * kst + skc[i] * 8);
                rV[i] = *(const bf16x8*)(vt + vtb + (size_t)srow[i] * CT + j1 + skc[i] * 8);
            }
        }
        __syncthreads();

        f32x4 sacc[4];
#pragma unroll
        for (int nj = 0; nj < 4; ++nj) sacc[nj] = (f32x4){0.f, 0.f, 0.f, 0.f};
#pragma unroll
        for (int kh = 0; kh < 2; ++kh) {
            int cl = kh * 4 + (lane >> 4);
            bf16x8 av = *(const bf16x8*)&Qs[(wrow * 16 + (lane & 15)) * LP + cl * 8];
#pragma unroll
            for (int nj = 0; nj < 4; ++nj) {
                bf16x8 bv = *(const bf16x8*)&Ks[(nj * 16 + (lane & 15)) * LP + cl * 8];
                sacc[nj] = __builtin_amdgcn_mfma_f32_16x16x32_bf16(av, bv, sacc[nj], 0, 0, 0);
            }
        }

        const bool diag = (ti == ntiles - 1);
        float pm[4] = {-1e30f, -1e30f, -1e30f, -1e30f};
#pragma unroll
        for (int nj = 0; nj < 4; ++nj) {
            int col_l = nj * 16 + (lane & 15);
#pragma unroll
            for (int r = 0; r < 4; ++r) {
                int row_l = wrow * 16 + ((lane >> 4) << 2) + r;
                float s = (diag && col_l > row_l) ? -1e30f : sacc[nj][r] * 0.125f;
                sacc[nj][r] = s;
                pm[r] = fmaxf(pm[r], s);
            }
        }
#pragma unroll
        for (int msk = 1; msk < 16; msk <<= 1)
#pragma unroll
            for (int r = 0; r < 4; ++r) pm[r] = fmaxf(pm[r], __shfl_xor(pm[r], msk));

        float corr[4], rs[4] = {0.f, 0.f, 0.f, 0.f};
#pragma unroll
        for (int r = 0; r < 4; ++r) {
            float mn = fmaxf(mrow[r], pm[r]);
            corr[r] = __expf(mrow[r] - mn);
            mrow[r] = mn;
        }
#pragma unroll
        for (int nj = 0; nj < 4; ++nj)
#pragma unroll
            for (int r = 0; r < 4; ++r) {
                float p = __expf(sacc[nj][r] - mrow[r]);
                sacc[nj][r] = p;
                rs[r] += p;
            }
#pragma unroll
        for (int msk = 1; msk < 16; msk <<= 1)
#pragma unroll
            for (int r = 0; r < 4; ++r) rs[r] += __shfl_xor(rs[r], msk);
#pragma unroll
        for (int r = 0; r < 4; ++r) lrow[r] = lrow[r] * corr[r] + rs[r];
#pragma unroll
        for (int nd = 0; nd < 4; ++nd)
#pragma unroll
            for (int r = 0; r < 4; ++r) oacc[nd][r] *= corr[r];

#pragma unroll
        for (int nj = 0; nj < 4; ++nj)
#pragma unroll
            for (int r = 0; r < 4; ++r) {
                bf16 pb = __float2bfloat16(sacc[nj][r]);
                Ps[(wrow * 16 + ((lane >> 4) << 2) + r) * LP + nj * 16 + (lane & 15)] =
                    *(short*)&pb;
            }

#pragma unroll
        for (int kh = 0; kh < 2; ++kh) {
            int cl = kh * 4 + (lane >> 4);
            bf16x8 pa = *(const bf16x8*)&Ps[(wrow * 16 + (lane & 15)) * LP + cl * 8];
#pragma unroll
            for (int nd = 0; nd < 4; ++nd) {
                bf16x8 bv = *(const bf16x8*)&Vs[(nd * 16 + (lane & 15)) * LP + cl * 8];
                oacc[nd] = __builtin_amdgcn_mfma_f32_16x16x32_bf16(pa, bv, oacc[nd], 0, 0, 0);
            }
        }
    }

    if (FUSE == 0) {
#pragma unroll
        for (int nd = 0; nd < 4; ++nd) {
#pragma unroll
            for (int r = 0; r < 4; ++r) {
                int row_g = qbase + wrow * 16 + ((lane >> 4) << 2) + r;
                int col = nd * 16 + (lane & 15);
                storev(&o[(size_t)b * ob + (size_t)hh * oh + (size_t)row_g * ot + col],
                       oacc[nd][r] / lrow[r]);
            }
        }
    } else {
#pragma unroll
        for (int nd = 0; nd < 4; ++nd)
#pragma unroll
            for (int r = 0; r < 4; ++r) {
                int row_l = wrow * 16 + ((lane >> 4) << 2) + r;
                bf16 ob16 = __float2bfloat16(oacc[nd][r] / lrow[r]);
                Qs[row_l * LP + nd * 16 + (lane & 15)] = *(short*)&ob16;
            }
        __syncthreads();

        const size_t whb = (size_t)hh * 4096;
        f32x4 qa[4], ka[4], va[4];
#pragma unroll
        for (int nj = 0; nj < 4; ++nj) {
            qa[nj] = (f32x4){0.f, 0.f, 0.f, 0.f};
            ka[nj] = (f32x4){0.f, 0.f, 0.f, 0.f};
            va[nj] = (f32x4){0.f, 0.f, 0.f, 0.f};
        }
#pragma unroll
        for (int kh = 0; kh < 2; ++kh) {
            int cl = kh * 4 + (lane >> 4);
            bf16x8 av = *(const bf16x8*)&Qs[(wrow * 16 + (lane & 15)) * LP + cl * 8];
#pragma unroll
            for (int nj = 0; nj < 4; ++nj) {
                int rowb = nj * 16 + (lane & 15);
                bf16x8 bq = *(const bf16x8*)(Wq1t + whb + (size_t)rowb * 64 + cl * 8);
                bf16x8 bk = *(const bf16x8*)(Wk1t + whb + (size_t)rowb * 64 + cl * 8);
                bf16x8 bw = *(const bf16x8*)(Wv1t + whb + (size_t)rowb * 64 + cl * 8);
                qa[nj] = __builtin_amdgcn_mfma_f32_16x16x32_bf16(av, bq, qa[nj], 0, 0, 0);
                ka[nj] = __builtin_amdgcn_mfma_f32_16x16x32_bf16(av, bk, ka[nj], 0, 0, 0);
                va[nj] = __builtin_amdgcn_mfma_f32_16x16x32_bf16(av, bw, va[nj], 0, 0, 0);
            }
        }
        const size_t bh = (size_t)(b * CH + hh);
#pragma unroll
        for (int nj = 0; nj < 4; ++nj) {
            int col = nj * 16 + (lane & 15);
            int ip = col >> 1;
            float inv = powf(10000.f, -(float)(2 * ip) / 64.f);
#pragma unroll
            for (int r = 0; r < 4; ++r) {
                int row_l = wrow * 16 + ((lane >> 4) << 2) + r;
                int t = qbase + row_l;
                float ang = (float)t * inv;
                float sn, cs;
                sincosf(ang, &sn, &cs);
                float aq = qa[nj][r], ak = ka[nj][r];
                float pq = __shfl_xor(aq, 1);
                float pk = __shfl_xor(ak, 1);
                float rq, rk;
                if (col & 1) { rq = pq * sn + aq * cs; rk = pk * sn + ak * cs; }
                else         { rq = aq * cs - pq * sn; rk = ak * cs - pk * sn; }
                size_t roff = (bh * CT + t) * 64 + col;
                q1o[roff] = __float2bfloat16(rq);
                k1o[roff] = __float2bfloat16(rk);
                v1to[(bh * 64 + col) * CT + t] = __float2bfloat16(va[nj][r]);
            }
        }
    }
}

// toks = concat([state, x_seg, state]) -> bf16 (PROVEN; separate pass wins)
__global__ __launch_bounds__(256) void build_toks_kernel(
    const void* __restrict__ x, const float* __restrict__ state, bf16* __restrict__ toks,
    int seg, const int* __restrict__ flag)
{
    const int f32w = flag[0];
    int idx = blockIdx.x * 256 + threadIdx.x;  // B*T*D
    int d = idx & (CD - 1);
    int t = (idx >> 10) % CT;
    int b = idx / (CT * CD);
    float v;
    if (t < CST) v = state[(b * CST + t) * CD + d];
    else if (t < CST + CL) v = ldin(x, ((size_t)b * CS + seg * CL + (t - CST)) * CD + d, f32w);
    else v = state[(b * CST + (t - CST - CL)) * CD + d];
    toks[idx] = __float2bfloat16(v);
}

__global__ __launch_bounds__(256) void init_state_kernel(
    const void* __restrict__ s0, float* __restrict__ state, const int* __restrict__ flag)
{
    const int f32w = flag[0];
    int idx = blockIdx.x * 256 + threadIdx.x;  // B*ST*D
    state[idx] = ldin(s0, idx % (CST * CD), f32w);
}

// LayerNorm(ra + x) * g + b.
__global__ __launch_bounds__(256) void ln_kernel(
    const float* __restrict__ ra, const void* __restrict__ x,
    const void* __restrict__ g, const void* __restrict__ bb,
    void* __restrict__ outp, int out_ext, const int* __restrict__ flag)
{
    const int f32w = flag[0];
    int row = blockIdx.x;
    int tid = threadIdx.x;
    __shared__ float buf[CD];
    __shared__ float red[4];

    float s = 0.f;
    for (int c = tid; c < CD; c += 256) {
        float v = ra[(size_t)row * CD + c] + ldin(x, (size_t)row * CD + c, f32w);
        buf[c] = v;
        s += v;
    }
#pragma unroll
    for (int off = 32; off; off >>= 1) s += __shfl_xor(s, off);
    if ((tid & 63) == 0) red[tid >> 6] = s;
    __syncthreads();
    float mu = (red[0] + red[1] + red[2] + red[3]) * (1.f / CD);
    __syncthreads();

    float vs = 0.f;
    for (int c = tid; c < CD; c += 256) {
        float d0 = buf[c] - mu;
        vs += d0 * d0;
    }
#pragma unroll
    for (int off = 32; off; off >>= 1) vs += __shfl_xor(vs, off);
    if ((tid & 63) == 0) red[tid >> 6] = vs;
    __syncthreads();
    float var = (red[0] + red[1] + red[2] + red[3]) * (1.f / CD);
    float rs = rsqrtf(var + 1e-5f);

    for (int c = tid; c < CD; c += 256) {
        float y = (buf[c] - mu) * rs * ldin(g, c, f32w) + ldin(bb, c, f32w);
        size_t idx = (size_t)row * CD + c;
        if (!out_ext) {
            ((bf16*)outp)[idx] = __float2bfloat16(y);
        } else if (f32w) {
            ((float*)outp)[idx] = y;
        } else {
            ((bf16*)outp)[idx] = __float2bfloat16(y);
        }
    }
}

extern "C" void kernel_launch(void* const* d_in, const int* in_sizes, int n_in,
                              void* d_out, int out_size, void* d_ws, size_t ws_size,
                              hipStream_t stream)
{
    const void* x      = d_in[0];
    const void* s0     = d_in[1];
    const void* Wq0    = d_in[2];
    const void* Wk0    = d_in[3];
    const void* Wv0    = d_in[4];
    const void* Wq1    = d_in[5];
    const void* Wk1    = d_in[6];
    const void* Wv1    = d_in[7];
    const void* Wo     = d_in[8];
    const void* bo     = d_in[9];
    const void* g_attn = d_in[10];
    const void* b_attn = d_in[11];
    const void* W1     = d_in[12];
    const void* b1     = d_in[13];
    const void* W2     = d_in[14];
    const void* b2     = d_in[15];
    const void* g_mlp  = d_in[16];
    const void* b_mlp  = d_in[17];

    // workspace slot layout BYTE-IDENTICAL to passing rounds 2/6-23 (~90.7 MB)
    int* flag = (int*)d_ws;
    float* f = (float*)((char*)d_ws + 16);
    float* toks_slot = f; f += (size_t)CB * CT * CD;       // bf16 toks
    float* q0_slot = f;  f += (size_t)CB * CH * CT * 64;   // bf16 q0 [1280][512]
    float* k0_slot = f;  f += (size_t)CB * CH * CT * 64;   // bf16 k0
    float* v0_slot = f;  f += (size_t)CB * CH * CT * 64;   // bf16 v0
    float* o0_slot = f;  f += (size_t)CB * CH * CT * 64;   // bf16 v0t
    float* q1_slot = f;  f += (size_t)CB * CH * CT * 64;   // bf16 q1
    float* k1_slot = f;  f += (size_t)CB * CH * CT * 64;   // bf16 k1
    float* v1_slot = f;  f += (size_t)CB * CH * CT * 64;   // bf16 v1t
    float* o1t_slot = f; f += (size_t)CB * CT * (CH * 64); // bf16 o1t [1280][512]
    float* seg_slot = f; f += (size_t)CB * CT * CD;        // (free during segments)
    float* state = f;   f += (size_t)CB * CST * CD;        // fp32 state
    float* a = f;       f += (size_t)CB * CS * CD;
    bf16* h = (bf16*)f;                                    // LN1 out [B*S, D] bf16
    bf16* tail = h + (size_t)CB * CS * CD;                 // 8.39 MB tail slot

    bf16* toks = (bf16*)toks_slot;
    bf16* q0b = (bf16*)q0_slot;
    bf16* k0b = (bf16*)k0_slot;
    bf16* v0b = (bf16*)v0_slot;
    bf16* v0t = (bf16*)o0_slot;
    bf16* q1b = (bf16*)q1_slot;
    bf16* k1b = (bf16*)k1_slot;
    bf16* v1t = (bf16*)v1_slot;
    bf16* o1t = (bf16*)o1t_slot;
    bf16* WtQ = h;                                         // h region dead until LN1
    bf16* WtK = WtQ + (size_t)512 * 1024;
    bf16* WtV = WtK + (size_t)512 * 1024;
    bf16* WtO = WtV + (size_t)512 * 1024;                  // [1024][512]
    bf16* WtQ1 = WtO + (size_t)1024 * 512;                 // per-head [8][64][64]
    bf16* WtK1 = WtQ1 + (size_t)8 * 4096;
    bf16* WtV1 = WtK1 + (size_t)8 * 4096;
    // MLP phase (seg region dead): g1 [8192][1024] bf16 at region base,
    // Wt1 after, Wt2 in tail. 16.78 + 8.39 = 25.17 MB (round-16-proven fit).
    bf16* g1  = (bf16*)toks_slot;                          // [8192][1024] 16.78 MB
    bf16* Wt1 = g1 + (size_t)CB * CS * CD;                 // [CDH][CD]    8.39 MB
    bf16* Wt2 = tail;                                      // [CD][CDH]    8.39 MB

    sniff_kernel<<<1, 64, 0, stream>>>(x, flag);
    init_state_kernel<<<(CB * CST * CD) / 256, 256, 0, stream>>>(s0, state, flag);

    // merged QKV weight transposes (PROVEN rounds 21-23)
    transpose3_kernel<<<dim3(8, 16, 3), 256, 0, stream>>>(
        Wq0, Wk0, Wv0, WtQ, WtK, WtV, flag);
    transpose_kernel<<<dim3(16, 8), 256, 0, stream>>>(Wo, WtO, 512, CD, flag);
    transposeH_kernel<<<24, 256, 0, stream>>>(Wq1, Wk1, Wv1, WtQ1, WtK1, WtV1, flag);

    for (int seg = 0; seg < NSEG; ++seg) {
        build_toks_kernel<<<(CB * CT * CD) / 256, 256, 0, stream>>>(x, state, toks, seg, flag);
        // QKV GEMM (proven path), row-major bf16 outputs
        mfma_lds<bf16, 0, 0, 0><<<dim3(10, 4, 3), 256, 0, stream>>>(
            toks, WtQ, WtK, WtV, q0b, k0b, v0b, nullptr, 0,
            CB * CT, 512, CD, CD, CD, 0, flag);
        // RoPE q0,k0 in place + V transpose -> v0t (proven separate pass)
        ropeV_kernel<<<dim3(CT / 64, CH, CB), 256, 0, stream>>>(q0b, k0b, v0b, v0t);
        // attn1 (row-major Q/K + v0t) with FUSED proj1+RoPE epilogue
        attn_mfma<1><<<dim3(CT / 64, CH, CB), 256, 0, stream>>>(
            q0b, k0b, v0t, nullptr,
            CT * 512, 64, 512,
            CT * 512, 64, 512,
            0, 0, 0,
            WtQ1, WtK1, WtV1, q1b, k1b, v1t);
        // attn2 (head-major Q/K + v1t) -> o1t token-major bf16 [1280][512]
        attn_mfma<0><<<dim3(CT / 64, CH, CB), 256, 0, stream>>>(
            q1b, k1b, v1t, o1t,
            CH * CT * 64, CT * 64, 64,
            CH * CT * 64, CT * 64, 64,
            CT * 512, 64, 512,
            nullptr, nullptr, nullptr, nullptr, nullptr, nullptr);
        // Wo GEMM with fused epilogue split: middle L rows -> a, last ST -> state
        mfma_lds<float, 0, 1, 0><<<dim3(10, 8, 1), 256, 0, stream>>>(
            o1t, WtO, WtO, WtO, a, state, a, bo, 0,
            CB * CT, CD, 512, 512, 512, seg, flag);
    }

    // h = LN(a + x) -> bf16 internal (overwrites WtQ..WtV1 — dead by now)
    ln_kernel<<<CB * CS, 256, 0, stream>>>(a, x, g_attn, b_attn, h, 0, flag);

    transpose_kernel<<<dim3(CDH / 64, CD / 64), 256, 0, stream>>>(W1, Wt1, CD, CDH, flag);
    transpose_kernel<<<dim3(CD / 64, CDH / 64), 256, 0, stream>>>(W2, Wt2, CDH, CD, flag);

    // MLP chunked over the hidden dim (round-16-proven correctness):
    // W1c: g1 = gelu(h @ Wt1[c-slice] + b1[c-slice])   grid 64x8 = 512 blocks
    // W2c: a (+)= g1 @ Wt2[:, c-slice] (+ b2 on c==0)  grid 64x8 = 512 blocks
    for (int c = 0; c < 4; ++c) {
        mfma_lds<bf16, 1, 0, 0><<<dim3(64, 8, 1), 256, 0, stream>>>(
            h, Wt1 + (size_t)c * 1024 * CD, Wt1, Wt1, g1, g1, g1,
            b1, c * 1024, CB * CS, 1024, CD, CD, CD, 0, flag);
        if (c == 0)
            mfma_lds<float, 0, 0, 0><<<dim3(64, 8, 1), 256, 0, stream>>>(
                g1, Wt2 + (size_t)c * 1024, Wt2, Wt2, a, a, a,
                b2, 0, CB * CS, CD, 1024, 1024, CDH, 0, flag);
        else
            mfma_lds<float, 0, 0, 1><<<dim3(64, 8, 1), 256, 0, stream>>>(
                g1, Wt2 + (size_t)c * 1024, Wt2, Wt2, a, a, a,
                nullptr, 0, CB * CS, CD, 1024, 1024, CDH, 0, flag);
    }
    ln_kernel<<<CB * CS, 256, 0, stream>>>(a, x, g_mlp, b_mlp, d_out, 1, flag);
}

// Round 26
// 1166.124 us; speedup vs baseline: 1.3506x; 1.0414x over previous
//
#include <hip/hip_runtime.h>
#include <hip/hip_bf16.h>

typedef __hip_bfloat16 bf16;
typedef short bf16x8 __attribute__((ext_vector_type(8)));   // 8 bf16 = 4 VGPRs
typedef float f32x4 __attribute__((ext_vector_type(4)));

// Problem constants
#define CB 2
#define CS 4096
#define CD 1024
#define CL 512
#define CST 64
#define CH 8
#define CT 640      // 2*ST + L
#define CDH 4096
#define NSEG 8
#define LP 80       // padded LDS row length (bf16) for attn tiles

__device__ __forceinline__ float tof(float x) { return x; }
__device__ __forceinline__ float tof(bf16 x) { return __bfloat162float(x); }
__device__ __forceinline__ void storev(float* p, float v) { *p = v; }
__device__ __forceinline__ void storev(bf16* p, float v) { *p = __float2bfloat16(v); }

__device__ __forceinline__ float ldin(const void* p, size_t i, int f32w) {
    if (f32w) return ((const float*)p)[i];
    return __bfloat162float(((const bf16*)p)[i]);
}

// ---------------------------------------------------------------------------
// Dtype sniffer (proven rounds 2/6-24; resolves flag=0 = bf16 here).
// ---------------------------------------------------------------------------
__global__ void sniff_kernel(const void* x, int* flag) {
    if (threadIdx.x == 0 && blockIdx.x == 0) {
        const bf16* hb = (const bf16*)x;
        int plaus = 0;
        for (int i = 0; i < 256; ++i) {
            float v = __bfloat162float(hb[2 * i]);
            float a = fabsf(v);
            if (v == 0.f || (a > 1e-4f && a < 100.f)) ++plaus;
        }
        flag[0] = (plaus < 128) ? 1 : 0;
    }
}

// ---------------------------------------------------------------------------
// bf16 transpose: out[C][R] = in[R][C], 64x64 tiles. PROVEN rounds 7-24.
// ---------------------------------------------------------------------------
__global__ __launch_bounds__(256) void transpose_kernel(
    const void* __restrict__ in, bf16* __restrict__ out, int R, int C,
    const int* __restrict__ flag)
{
    const int f32w = flag[0];
    __shared__ short t[64][72];
    int tid = threadIdx.x;
    int c0 = blockIdx.x * 64, r0 = blockIdx.y * 64;
    int cc = tid & 63, rr = tid >> 6;
#pragma unroll
    for (int i = 0; i < 16; ++i) {
        bf16 v = __float2bfloat16(ldin(in, (size_t)(r0 + rr + i * 4) * C + c0 + cc, f32w));
        t[rr + i * 4][cc] = *(short*)&v;
    }
    __syncthreads();
#pragma unroll
    for (int i = 0; i < 16; ++i)
        ((short*)out)[(size_t)(c0 + rr + i * 4) * R + r0 + cc] = t[cc][rr + i * 4];
}

// ---------------------------------------------------------------------------
// Merged QKV weight transpose (PROVEN rounds 21-24): 3 dispatches -> 1.
// ---------------------------------------------------------------------------
__global__ __launch_bounds__(256) void transpose3_kernel(
    const void* __restrict__ in0, const void* __restrict__ in1, const void* __restrict__ in2,
    bf16* __restrict__ out0, bf16* __restrict__ out1, bf16* __restrict__ out2,
    const int* __restrict__ flag)
{
    const int f32w = flag[0];
    const void* in = (blockIdx.z == 0) ? in0 : (blockIdx.z == 1 ? in1 : in2);
    bf16* out = (blockIdx.z == 0) ? out0 : (blockIdx.z == 1 ? out1 : out2);
    const int R = CD, C = 512;
    __shared__ short t[64][72];
    int tid = threadIdx.x;
    int c0 = blockIdx.x * 64, r0 = blockIdx.y * 64;
    int cc = tid & 63, rr = tid >> 6;
#pragma unroll
    for (int i = 0; i < 16; ++i) {
        bf16 v = __float2bfloat16(ldin(in, (size_t)(r0 + rr + i * 4) * C + c0 + cc, f32w));
        t[rr + i * 4][cc] = *(short*)&v;
    }
    __syncthreads();
#pragma unroll
    for (int i = 0; i < 16; ++i)
        ((short*)out)[(size_t)(c0 + rr + i * 4) * R + r0 + cc] = t[cc][rr + i * 4];
}

// ---------------------------------------------------------------------------
// Per-head 64x64 transpose of Wq1/Wk1/Wv1 (PROVEN rounds 15-24).
// ---------------------------------------------------------------------------
__global__ __launch_bounds__(256) void transposeH_kernel(
    const void* __restrict__ Wq1, const void* __restrict__ Wk1, const void* __restrict__ Wv1,
    bf16* __restrict__ oq, bf16* __restrict__ ok, bf16* __restrict__ ov,
    const int* __restrict__ flag)
{
    const int f32w = flag[0];
    int which = blockIdx.x >> 3, hh = blockIdx.x & 7;
    const void* in = (which == 0) ? Wq1 : (which == 1) ? Wk1 : Wv1;
    bf16* out = (which == 0) ? oq : (which == 1) ? ok : ov;
    __shared__ short t[64][72];
    int tid = threadIdx.x;
    int cc = tid & 63, rr = tid >> 6;
    size_t base = (size_t)hh * 4096;
#pragma unroll
    for (int i = 0; i < 16; ++i) {
        bf16 v = __float2bfloat16(ldin(in, base + (size_t)(rr + i * 4) * 64 + cc, f32w));
        t[rr + i * 4][cc] = *(short*)&v;
    }
    __syncthreads();
#pragma unroll
    for (int i = 0; i < 16; ++i)
        ((short*)out)[base + (size_t)(rr + i * 4) * 64 + cc] = t[cc][rr + i * 4];
}

// ---------------------------------------------------------------------------
// MFMA GEMM, register-staged linear LDS, BK=64, DEPTH-2 PREFETCH (PROVEN).
// OUTM=0: row-major C (+ACCUM). OUTM=2: state-only (small Wo; row -> state
// rows 0..127 directly). lda/ldb/boff proven round 24.
// ---------------------------------------------------------------------------
template <typename TC, int ACT, int OUTM, int ACCUM>
__global__ __launch_bounds__(256) void mfma_lds(
    const bf16* __restrict__ A,
    const bf16* __restrict__ Bt0, const bf16* __restrict__ Bt1, const bf16* __restrict__ Bt2,
    TC* __restrict__ C0, TC* __restrict__ C1, TC* __restrict__ C2,
    const void* __restrict__ bias, int boff,
    int M, int N, int K, int lda, int ldb, int seg,
    const int* __restrict__ flag)
{
    const int f32w = flag[0];
    const bf16* Bt = (blockIdx.z == 0) ? Bt0 : (blockIdx.z == 1 ? Bt1 : Bt2);
    TC* C = (blockIdx.z == 0) ? C0 : (blockIdx.z == 1 ? C1 : C2);

    __shared__ __align__(16) short As[128 * 64];
    __shared__ __align__(16) short Bs[128 * 64];

    const int tid = threadIdx.x;
    const int lane = tid & 63;
    const int w = tid >> 6;
    const int wm = w >> 1, wn = w & 1;
    const int bm = blockIdx.x * 128, bn = blockIdx.y * 128;

    f32x4 acc[4][4];
#pragma unroll
    for (int i = 0; i < 4; ++i)
#pragma unroll
        for (int j = 0; j < 4; ++j) acc[i][j] = (f32x4){0.f, 0.f, 0.f, 0.f};

    int srow[4], skc[4];
#pragma unroll
    for (int i = 0; i < 4; ++i) {
        int c = i * 256 + tid;
        srow[i] = c >> 3;
        skc[i] = (c & 7) * 8;
    }

    bf16x8 rA0[4], rB0[4], rA1[4], rB1[4];
#pragma unroll
    for (int i = 0; i < 4; ++i) {
        rA0[i] = *(const bf16x8*)(A + (size_t)(bm + srow[i]) * lda + skc[i]);
        rB0[i] = *(const bf16x8*)(Bt + (size_t)(bn + srow[i]) * ldb + skc[i]);
        rA1[i] = *(const bf16x8*)(A + (size_t)(bm + srow[i]) * lda + 64 + skc[i]);
        rB1[i] = *(const bf16x8*)(Bt + (size_t)(bn + srow[i]) * ldb + 64 + skc[i]);
    }

#define MFMA_PHASE                                                              \
    _Pragma("unroll")                                                           \
    for (int kh = 0; kh < 2; ++kh) {                                            \
        bf16x8 av[4], bv[4];                                                    \
        _Pragma("unroll")                                                       \
        for (int mi = 0; mi < 4; ++mi) {                                        \
            int r = wm * 64 + mi * 16 + (lane & 15);                            \
            int cl = kh * 4 + (lane >> 4);                                      \
            av[mi] = *(const bf16x8*)&As[r * 64 + cl * 8];                      \
        }                                                                       \
        _Pragma("unroll")                                                       \
        for (int nj = 0; nj < 4; ++nj) {                                        \
            int r = wn * 64 + nj * 16 + (lane & 15);                            \
            int cl = kh * 4 + (lane >> 4);                                      \
            bv[nj] = *(const bf16x8*)&Bs[r * 64 + cl * 8];                      \
        }                                                                       \
        _Pragma("unroll")                                                       \
        for (int mi = 0; mi < 4; ++mi)                                          \
            _Pragma("unroll")                                                   \
            for (int nj = 0; nj < 4; ++nj)                                      \
                acc[mi][nj] = __builtin_amdgcn_mfma_f32_16x16x32_bf16(          \
                    av[mi], bv[nj], acc[mi][nj], 0, 0, 0);                      \
    }

    for (int k0 = 0; k0 < K; k0 += 128) {
        __syncthreads();
#pragma unroll
        for (int i = 0; i < 4; ++i) {
            *(bf16x8*)&As[(size_t)(i * 256 + tid) * 8] = rA0[i];
            *(bf16x8*)&Bs[(size_t)(i * 256 + tid) * 8] = rB0[i];
        }
        if (k0 + 128 < K) {
            int kn = k0 + 128;
#pragma unroll
            for (int i = 0; i < 4; ++i) {
                rA0[i] = *(const bf16x8*)(A + (size_t)(bm + srow[i]) * lda + kn + skc[i]);
                rB0[i] = *(const bf16x8*)(Bt + (size_t)(bn + srow[i]) * ldb + kn + skc[i]);
            }
        }
        __syncthreads();
        MFMA_PHASE

        __syncthreads();
#pragma unroll
        for (int i = 0; i < 4; ++i) {
            *(bf16x8*)&As[(size_t)(i * 256 + tid) * 8] = rA1[i];
            *(bf16x8*)&Bs[(size_t)(i * 256 + tid) * 8] = rB1[i];
        }
        if (k0 + 192 < K) {
            int kn = k0 + 192;
#pragma unroll
            for (int i = 0; i < 4; ++i) {
                rA1[i] = *(const bf16x8*)(A + (size_t)(bm + srow[i]) * lda + kn + skc[i]);
                rB1[i] = *(const bf16x8*)(Bt + (size_t)(bn + srow[i]) * ldb + kn + skc[i]);
            }
        }
        __syncthreads();
        MFMA_PHASE
    }
#undef MFMA_PHASE

#pragma unroll
    for (int mi = 0; mi < 4; ++mi) {
#pragma unroll
        for (int nj = 0; nj < 4; ++nj) {
            int c = bn + wn * 64 + nj * 16 + (lane & 15);
            float bia = bias ? ldin(bias, boff + c, f32w) : 0.f;
#pragma unroll
            for (int r = 0; r < 4; ++r) {
                int row = bm + wm * 64 + mi * 16 + (lane >> 4) * 4 + r;
                float v = acc[mi][nj][r] + bia;
                if (ACT == 1) v = 0.5f * v * (1.0f + erff(v * 0.70710678118654752f));
                if (OUTM == 0) {
                    if (ACCUM) v += tof(C[(size_t)row * N + c]);
                    storev(C + (size_t)row * N + c, v);
                } else {  // OUTM == 2: small Wo -> state rows (row = b*64+t)
                    storev(C1 + (size_t)row * CD + c, v);
                }
            }
        }
    }
}

// ---------------------------------------------------------------------------
// RoPE (in-place, bf16) on q and k + LDS-tiled transpose of v -> vt.
// PROVEN rounds 12-24.
// ---------------------------------------------------------------------------
__global__ __launch_bounds__(256) void ropeV_kernel(
    bf16* __restrict__ q, bf16* __restrict__ k,
    const bf16* __restrict__ v, bf16* __restrict__ vt)
{
    int t0 = blockIdx.x * 64, hh = blockIdx.y, b = blockIdx.z;
    int tid = threadIdx.x;
    __shared__ short lt[64][72];
    int c = tid & 63;
    int r0 = tid >> 6;
    int ip = c >> 1;
    float inv = powf(10000.f, -(float)(2 * ip) / 64.f);
#pragma unroll
    for (int i = 0; i < 16; ++i) {
        int r = r0 + i * 4;
        int t = t0 + r;
        size_t idx = ((size_t)b * CT + t) * 512 + hh * 64 + c;
        float qv = tof(q[idx]);
        float kv = tof(k[idx]);
        float ang = (float)t * inv;
        float sn, cs;
        sincosf(ang, &sn, &cs);
        float qp = __shfl_xor(qv, 1);
        float kp = __shfl_xor(kv, 1);
        float rq, rk;
        if (c & 1) { rq = qp * sn + qv * cs; rk = kp * sn + kv * cs; }
        else       { rq = qv * cs - qp * sn; rk = kv * cs - kp * sn; }
        q[idx] = __float2bfloat16(rq);
        k[idx] = __float2bfloat16(rk);
        lt[r][c] = ((const short*)v)[idx];
    }
    __syncthreads();
#pragma unroll
    for (int i = 0; i < 16; ++i) {
        int c2 = r0 + i * 4;
        int r2 = c;
        ((short*)vt)[((size_t)(b * CH + hh) * 64 + c2) * CT + t0 + r2] = lt[r2][c2];
    }
}

// ---------------------------------------------------------------------------
// MFMA flash attention (core PROVEN rounds 12-24).
// FUSE=1: grid x=10 (qbase 0..576); epilogue proj1+RoPE -> q1/k1/v1t.
// FUSE=0: grid x=9  (qbase 64..576; tile-0 output discarded downstream);
//   tiles 1..8 rows -> o1mid[(b*8+seg)*512 + (t-64)][512] (batch-major, row
//   index == 'a' row index), tile-9 rows -> o1s[b*64 + (t-576)][512].
// ---------------------------------------------------------------------------
template <int FUSE>
__global__ __launch_bounds__(256) void attn_mfma(
    const bf16* __restrict__ q, const bf16* __restrict__ k, const bf16* __restrict__ vt,
    bf16* __restrict__ o,
    int qsb, int qsh, int qst,
    int ksb, int ksh, int kst,
    int seg,
    const bf16* __restrict__ Wq1t, const bf16* __restrict__ Wk1t, const bf16* __restrict__ Wv1t,
    bf16* __restrict__ q1o, bf16* __restrict__ k1o, bf16* __restrict__ v1to)
{
    const int tid = threadIdx.x;
    const int lane = tid & 63;
    const int wrow = tid >> 6;
    const int hh = blockIdx.y, b = blockIdx.z;
    const int qbase = (FUSE ? ((int)gridDim.x - 1 - (int)blockIdx.x)
                            : ((int)gridDim.x - (int)blockIdx.x)) * 64;

    __shared__ __align__(16) short Qs[64 * LP];
    __shared__ __align__(16) short Ks[64 * LP];
    __shared__ __align__(16) short Vs[64 * LP];
    __shared__ __align__(16) short Ps[64 * LP];

    const size_t qb0 = (size_t)b * qsb + (size_t)hh * qsh;
    const size_t kb0 = (size_t)b * ksb + (size_t)hh * ksh;
    const size_t vtb = (size_t)(b * CH + hh) * 64 * CT;

    int srow[2], skc[2], soff[2];
#pragma unroll
    for (int i = 0; i < 2; ++i) {
        int c = i * 256 + tid;
        srow[i] = c >> 3;
        skc[i] = c & 7;
        soff[i] = srow[i] * LP + skc[i] * 8;
    }

    bf16x8 rQ[2], rK[2], rV[2];
#pragma unroll
    for (int i = 0; i < 2; ++i) {
        rQ[i] = *(const bf16x8*)(q + qb0 + (size_t)(qbase + srow[i]) * qst + skc[i] * 8);
        rK[i] = *(const bf16x8*)(k + kb0 + (size_t)srow[i] * kst + skc[i] * 8);
        rV[i] = *(const bf16x8*)(vt + vtb + (size_t)srow[i] * CT + skc[i] * 8);
    }

    float mrow[4], lrow[4];
    f32x4 oacc[4];
#pragma unroll
    for (int r = 0; r < 4; ++r) { mrow[r] = -1e30f; lrow[r] = 0.f; }
#pragma unroll
    for (int nd = 0; nd < 4; ++nd) oacc[nd] = (f32x4){0.f, 0.f, 0.f, 0.f};

    const int ntiles = qbase / 64 + 1;
    for (int ti = 0; ti < ntiles; ++ti) {
        __syncthreads();
        if (ti == 0) {
#pragma unroll
            for (int i = 0; i < 2; ++i) *(bf16x8*)&Qs[soff[i]] = rQ[i];
        }
#pragma unroll
        for (int i = 0; i < 2; ++i) {
            *(bf16x8*)&Ks[soff[i]] = rK[i];
            *(bf16x8*)&Vs[soff[i]] = rV[i];
        }
        if (ti + 1 < ntiles) {
            int j1 = (ti + 1) * 64;
#pragma unroll
            for (int i = 0; i < 2; ++i) {
                rK[i] = *(const bf16x8*)(k + kb0 + (size_t)(j1 + srow[i]) * kst + skc[i] * 8);
                rV[i] = *(const bf16x8*)(vt + vtb + (size_t)srow[i] * CT + j1 + skc[i] * 8);
            }
        }
        __syncthreads();

        f32x4 sacc[4];
#pragma unroll
        for (int nj = 0; nj < 4; ++nj) sacc[nj] = (f32x4){0.f, 0.f, 0.f, 0.f};
#pragma unroll
        for (int kh = 0; kh < 2; ++kh) {
            int cl = kh * 4 + (lane >> 4);
            bf16x8 av = *(const bf16x8*)&Qs[(wrow * 16 + (lane & 15)) * LP + cl * 8];
#pragma unroll
            for (int nj = 0; nj < 4; ++nj) {
                bf16x8 bv = *(const bf16x8*)&Ks[(nj * 16 + (lane & 15)) * LP + cl * 8];
                sacc[nj] = __builtin_amdgcn_mfma_f32_16x16x32_bf16(av, bv, sacc[nj], 0, 0, 0);
            }
        }

        const bool diag = (ti == ntiles - 1);
        float pm[4] = {-1e30f, -1e30f, -1e30f, -1e30f};
#pragma unroll
        for (int nj = 0; nj < 4; ++nj) {
            int col_l = nj * 16 + (lane & 15);
#pragma unroll
            for (int r = 0; r < 4; ++r) {
                int row_l = wrow * 16 + ((lane >> 4) << 2) + r;
                float s = (diag && col_l > row_l) ? -1e30f : sacc[nj][r] * 0.125f;
                sacc[nj][r] = s;
                pm[r] = fmaxf(pm[r], s);
            }
        }
#pragma unroll
        for (int msk = 1; msk < 16; msk <<= 1)
#pragma unroll
            for (int r = 0; r < 4; ++r) pm[r] = fmaxf(pm[r], __shfl_xor(pm[r], msk));

        float corr[4], rs[4] = {0.f, 0.f, 0.f, 0.f};
#pragma unroll
        for (int r = 0; r < 4; ++r) {
            float mn = fmaxf(mrow[r], pm[r]);
            corr[r] = __expf(mrow[r] - mn);
            mrow[r] = mn;
        }
#pragma unroll
        for (int nj = 0; nj < 4; ++nj)
#pragma unroll
            for (int r = 0; r < 4; ++r) {
                float p = __expf(sacc[nj][r] - mrow[r]);
                sacc[nj][r] = p;
                rs[r] += p;
            }
#pragma unroll
        for (int msk = 1; msk < 16; msk <<= 1)
#pragma unroll
            for (int r = 0; r < 4; ++r) rs[r] += __shfl_xor(rs[r], msk);
#pragma unroll
        for (int r = 0; r < 4; ++r) lrow[r] = lrow[r] * corr[r] + rs[r];
#pragma unroll
        for (int nd = 0; nd < 4; ++nd)
#pragma unroll
            for (int r = 0; r < 4; ++r) oacc[nd][r] *= corr[r];

#pragma unroll
        for (int nj = 0; nj < 4; ++nj)
#pragma unroll
            for (int r = 0; r < 4; ++r) {
                bf16 pb = __float2bfloat16(sacc[nj][r]);
                Ps[(wrow * 16 + ((lane >> 4) << 2) + r) * LP + nj * 16 + (lane & 15)] =
                    *(short*)&pb;
            }

#pragma unroll
        for (int kh = 0; kh < 2; ++kh) {
            int cl = kh * 4 + (lane >> 4);
            bf16x8 pa = *(const bf16x8*)&Ps[(wrow * 16 + (lane & 15)) * LP + cl * 8];
#pragma unroll
            for (int nd = 0; nd < 4; ++nd) {
                bf16x8 bv = *(const bf16x8*)&Vs[(nd * 16 + (lane & 15)) * LP + cl * 8];
                oacc[nd] = __builtin_amdgcn_mfma_f32_16x16x32_bf16(pa, bv, oacc[nd], 0, 0, 0);
            }
        }
    }

    if (FUSE == 0) {
        // per-block-uniform destination select (tile granularity == 64)
        bf16* dst;
        int rbase;
        if (qbase == 576) { dst = q1o; rbase = b * 64 - 576; }          // o1s
        else              { dst = o;   rbase = (b * 8 + seg) * 512 - 64; }  // o1mid
#pragma unroll
        for (int nd = 0; nd < 4; ++nd) {
#pragma unroll
            for (int r = 0; r < 4; ++r) {
                int row_g = qbase + wrow * 16 + ((lane >> 4) << 2) + r;
                int col = nd * 16 + (lane & 15);
                dst[(size_t)(rbase + row_g) * 512 + hh * 64 + col] =
                    __float2bfloat16(oacc[nd][r] / lrow[r]);
            }
        }
    } else {
#pragma unroll
        for (int nd = 0; nd < 4; ++nd)
#pragma unroll
            for (int r = 0; r < 4; ++r) {
                int row_l = wrow * 16 + ((lane >> 4) << 2) + r;
                bf16 ob16 = __float2bfloat16(oacc[nd][r] / lrow[r]);
                Qs[row_l * LP + nd * 16 + (lane & 15)] = *(short*)&ob16;
            }
        __syncthreads();

        const size_t whb = (size_t)hh * 4096;
        f32x4 qa[4], ka[4], va[4];
#pragma unroll
        for (int nj = 0; nj < 4; ++nj) {
            qa[nj] = (f32x4){0.f, 0.f, 0.f, 0.f};
            ka[nj] = (f32x4){0.f, 0.f, 0.f, 0.f};
            va[nj] = (f32x4){0.f, 0.f, 0.f, 0.f};
        }
#pragma unroll
        for (int kh = 0; kh < 2; ++kh) {
            int cl = kh * 4 + (lane >> 4);
            bf16x8 av = *(const bf16x8*)&Qs[(wrow * 16 + (lane & 15)) * LP + cl * 8];
#pragma unroll
            for (int nj = 0; nj < 4; ++nj) {
                int rowb = nj * 16 + (lane & 15);
                bf16x8 bq = *(const bf16x8*)(Wq1t + whb + (size_t)rowb * 64 + cl * 8);
                bf16x8 bk = *(const bf16x8*)(Wk1t + whb + (size_t)rowb * 64 + cl * 8);
                bf16x8 bw = *(const bf16x8*)(Wv1t + whb + (size_t)rowb * 64 + cl * 8);
                qa[nj] = __builtin_amdgcn_mfma_f32_16x16x32_bf16(av, bq, qa[nj], 0, 0, 0);
                ka[nj] = __builtin_amdgcn_mfma_f32_16x16x32_bf16(av, bk, ka[nj], 0, 0, 0);
                va[nj] = __builtin_amdgcn_mfma_f32_16x16x32_bf16(av, bw, va[nj], 0, 0, 0);
            }
        }
        const size_t bh = (size_t)(b * CH + hh);
#pragma unroll
        for (int nj = 0; nj < 4; ++nj) {
            int col = nj * 16 + (lane & 15);
            int ip = col >> 1;
            float inv = powf(10000.f, -(float)(2 * ip) / 64.f);
#pragma unroll
            for (int r = 0; r < 4; ++r) {
                int row_l = wrow * 16 + ((lane >> 4) << 2) + r;
                int t = qbase + row_l;
                float ang = (float)t * inv;
                float sn, cs;
                sincosf(ang, &sn, &cs);
                float aq = qa[nj][r], ak = ka[nj][r];
                float pq = __shfl_xor(aq, 1);
                float pk = __shfl_xor(ak, 1);
                float rq, rk;
                if (col & 1) { rq = pq * sn + aq * cs; rk = pk * sn + ak * cs; }
                else         { rq = aq * cs - pq * sn; rk = ak * cs - pk * sn; }
                size_t roff = (bh * CT + t) * 64 + col;
                q1o[roff] = __float2bfloat16(rq);
                k1o[roff] = __float2bfloat16(rk);
                v1to[(bh * 64 + col) * CT + t] = __float2bfloat16(va[nj][r]);
            }
        }
    }
}

// toks = concat([state, x_seg, state]) -> bf16 (PROVEN; separate pass wins)
__global__ __launch_bounds__(256) void build_toks_kernel(
    const void* __restrict__ x, const float* __restrict__ state, bf16* __restrict__ toks,
    int seg, const int* __restrict__ flag)
{
    const int f32w = flag[0];
    int idx = blockIdx.x * 256 + threadIdx.x;  // B*T*D
    int d = idx & (CD - 1);
    int t = (idx >> 10) % CT;
    int b = idx / (CT * CD);
    float v;
    if (t < CST) v = state[(b * CST + t) * CD + d];
    else if (t < CST + CL) v = ldin(x, ((size_t)b * CS + seg * CL + (t - CST)) * CD + d, f32w);
    else v = state[(b * CST + (t - CST - CL)) * CD + d];
    toks[idx] = __float2bfloat16(v);
}

__global__ __launch_bounds__(256) void init_state_kernel(
    const void* __restrict__ s0, float* __restrict__ state, const int* __restrict__ flag)
{
    const int f32w = flag[0];
    int idx = blockIdx.x * 256 + threadIdx.x;  // B*ST*D
    state[idx] = ldin(s0, idx % (CST * CD), f32w);
}

// LayerNorm(ra + x) * g + b.
__global__ __launch_bounds__(256) void ln_kernel(
    const float* __restrict__ ra, const void* __restrict__ x,
    const void* __restrict__ g, const void* __restrict__ bb,
    void* __restrict__ outp, int out_ext, const int* __restrict__ flag)
{
    const int f32w = flag[0];
    int row = blockIdx.x;
    int tid = threadIdx.x;
    __shared__ float buf[CD];
    __shared__ float red[4];

    float s = 0.f;
    for (int c = tid; c < CD; c += 256) {
        float v = ra[(size_t)row * CD + c] + ldin(x, (size_t)row * CD + c, f32w);
        buf[c] = v;
        s += v;
    }
#pragma unroll
    for (int off = 32; off; off >>= 1) s += __shfl_xor(s, off);
    if ((tid & 63) == 0) red[tid >> 6] = s;
    __syncthreads();
    float mu = (red[0] + red[1] + red[2] + red[3]) * (1.f / CD);
    __syncthreads();

    float vs = 0.f;
    for (int c = tid; c < CD; c += 256) {
        float d0 = buf[c] - mu;
        vs += d0 * d0;
    }
#pragma unroll
    for (int off = 32; off; off >>= 1) vs += __shfl_xor(vs, off);
    if ((tid & 63) == 0) red[tid >> 6] = vs;
    __syncthreads();
    float var = (red[0] + red[1] + red[2] + red[3]) * (1.f / CD);
    float rs = rsqrtf(var + 1e-5f);

    for (int c = tid; c < CD; c += 256) {
        float y = (buf[c] - mu) * rs * ldin(g, c, f32w) + ldin(bb, c, f32w);
        size_t idx = (size_t)row * CD + c;
        if (!out_ext) {
            ((bf16*)outp)[idx] = __float2bfloat16(y);
        } else if (f32w) {
            ((float*)outp)[idx] = y;
        } else {
            ((bf16*)outp)[idx] = __float2bfloat16(y);
        }
    }
}

extern "C" void kernel_launch(void* const* d_in, const int* in_sizes, int n_in,
                              void* d_out, int out_size, void* d_ws, size_t ws_size,
                              hipStream_t stream)
{
    const void* x      = d_in[0];
    const void* s0     = d_in[1];
    const void* Wq0    = d_in[2];
    const void* Wk0    = d_in[3];
    const void* Wv0    = d_in[4];
    const void* Wq1    = d_in[5];
    const void* Wk1    = d_in[6];
    const void* Wv1    = d_in[7];
    const void* Wo     = d_in[8];
    const void* bo     = d_in[9];
    const void* g_attn = d_in[10];
    const void* b_attn = d_in[11];
    const void* W1     = d_in[12];
    const void* b1     = d_in[13];
    const void* W2     = d_in[14];
    const void* b2     = d_in[15];
    const void* g_mlp  = d_in[16];
    const void* b_mlp  = d_in[17];

    // workspace slot layout BYTE-IDENTICAL to passing rounds 2/6-24 (~90.7 MB)
    int* flag = (int*)d_ws;
    float* f = (float*)((char*)d_ws + 16);
    float* toks_slot = f; f += (size_t)CB * CT * CD;       // bf16 toks
    float* q0_slot = f;  f += (size_t)CB * CH * CT * 64;   // bf16 q0 [1280][512]
    float* k0_slot = f;  f += (size_t)CB * CH * CT * 64;   // bf16 k0
    float* v0_slot = f;  f += (size_t)CB * CH * CT * 64;   // bf16 v0
    float* o0_slot = f;  f += (size_t)CB * CH * CT * 64;   // bf16 v0t
    float* q1_slot = f;  f += (size_t)CB * CH * CT * 64;   // bf16 q1
    float* k1_slot = f;  f += (size_t)CB * CH * CT * 64;   // bf16 k1
    float* v1_slot = f;  f += (size_t)CB * CH * CT * 64;   // bf16 v1t
    float* o1t_slot = f; f += (size_t)CB * CT * (CH * 64); // (unused during segments now)
    float* seg_slot = f; f += (size_t)CB * CT * CD;        // (unused during segments)
    float* state = f;   f += (size_t)CB * CST * CD;        // fp32 state
    float* a = f;       f += (size_t)CB * CS * CD;
    bf16* h = (bf16*)f;                                    // LN1 out [B*S, D] bf16
    bf16* tail = h + (size_t)CB * CS * CD;                 // 8.39 MB tail slot

    bf16* toks = (bf16*)toks_slot;
    bf16* q0b = (bf16*)q0_slot;
    bf16* k0b = (bf16*)k0_slot;
    bf16* v0b = (bf16*)v0_slot;
    bf16* v0t = (bf16*)o0_slot;
    bf16* q1b = (bf16*)q1_slot;
    bf16* k1b = (bf16*)k1_slot;
    bf16* v1t = (bf16*)v1_slot;
    bf16* WtQ = h;                                         // h region dead until LN1
    bf16* WtK = WtQ + (size_t)512 * 1024;
    bf16* WtV = WtK + (size_t)512 * 1024;
    bf16* WtO = WtV + (size_t)512 * 1024;                  // [1024][512]
    bf16* WtQ1 = WtO + (size_t)1024 * 512;                 // per-head [8][64][64]
    bf16* WtK1 = WtQ1 + (size_t)8 * 4096;
    bf16* WtV1 = WtK1 + (size_t)8 * 4096;
    // o1mid/o1s AFTER the transposed weights in the h region (fix for round
    // 25's overflow: old placement overran into the state slot). Usage:
    // 4.19 MB weights + 8.39 MB o1mid + 0.13 MB o1s = 12.71 MB < 16.78 MB.
    // Lifetime: written during segment loop, consumed by big Wo, then LN1
    // overwrites the h region — safe ordering.
    bf16* o1mid = WtV1 + (size_t)8 * 4096;                 // [B*NSEG*512][512]
    bf16* o1s = o1mid + (size_t)CB * NSEG * 512 * 512;     // [128][512]
    // MLP phase (toks..q1 region dead): g1 at region base, Wt1 after, Wt2 tail.
    bf16* g1  = (bf16*)toks_slot;                          // [8192][1024] 16.78 MB
    bf16* Wt1 = g1 + (size_t)CB * CS * CD;                 // [CDH][CD]    8.39 MB
    bf16* Wt2 = tail;                                      // [CD][CDH]    8.39 MB

    sniff_kernel<<<1, 64, 0, stream>>>(x, flag);
    init_state_kernel<<<(CB * CST * CD) / 256, 256, 0, stream>>>(s0, state, flag);

    transpose3_kernel<<<dim3(8, 16, 3), 256, 0, stream>>>(
        Wq0, Wk0, Wv0, WtQ, WtK, WtV, flag);
    transpose_kernel<<<dim3(16, 8), 256, 0, stream>>>(Wo, WtO, 512, CD, flag);
    transposeH_kernel<<<24, 256, 0, stream>>>(Wq1, Wk1, Wv1, WtQ1, WtK1, WtV1, flag);

    for (int seg = 0; seg < NSEG; ++seg) {
        build_toks_kernel<<<(CB * CT * CD) / 256, 256, 0, stream>>>(x, state, toks, seg, flag);
        // QKV GEMM (proven path), row-major bf16 outputs
        mfma_lds<bf16, 0, 0, 0><<<dim3(10, 4, 3), 256, 0, stream>>>(
            toks, WtQ, WtK, WtV, q0b, k0b, v0b, nullptr, 0,
            CB * CT, 512, CD, CD, CD, 0, flag);
        // RoPE q0,k0 in place + V transpose -> v0t (proven separate pass)
        ropeV_kernel<<<dim3(CT / 64, CH, CB), 256, 0, stream>>>(q0b, k0b, v0b, v0t);
        // attn1 (row-major Q/K + v0t) with FUSED proj1+RoPE epilogue (grid 10)
        attn_mfma<1><<<dim3(CT / 64, CH, CB), 256, 0, stream>>>(
            q0b, k0b, v0t, nullptr,
            CT * 512, 64, 512,
            CT * 512, 64, 512,
            seg,
            WtQ1, WtK1, WtV1, q1b, k1b, v1t);
        // attn2 (head-major Q/K + v1t), grid 9: middle rows -> o1mid, tile9 -> o1s
        attn_mfma<0><<<dim3(9, CH, CB), 256, 0, stream>>>(
            q1b, k1b, v1t, o1mid,
            CH * CT * 64, CT * 64, 64,
            CH * CT * 64, CT * 64, 64,
            seg,
            nullptr, nullptr, nullptr, o1s, nullptr, nullptr);
        // small Wo: state rows only (M=128, 8 blocks) -> state (fp32)
        mfma_lds<float, 0, 2, 0><<<dim3(1, 8, 1), 256, 0, stream>>>(
            o1s, WtO, WtO, WtO, a, state, a, bo, 0,
            128, CD, 512, 512, 512, seg, flag);
    }

    // big Wo: all middle rows at once (M=8192, grid 64x8=512 blocks) -> a + bo
    mfma_lds<float, 0, 0, 0><<<dim3(64, 8, 1), 256, 0, stream>>>(
        o1mid, WtO, WtO, WtO, a, a, a, bo, 0,
        CB * CS, CD, 512, 512, 512, 0, flag);

    // h = LN(a + x) -> bf16 internal (overwrites WtQ..o1s — all dead by now)
    ln_kernel<<<CB * CS, 256, 0, stream>>>(a, x, g_attn, b_attn, h, 0, flag);

    transpose_kernel<<<dim3(CDH / 64, CD / 64), 256, 0, stream>>>(W1, Wt1, CD, CDH, flag);
    transpose_kernel<<<dim3(CD / 64, CDH / 64), 256, 0, stream>>>(W2, Wt2, CDH, CD, flag);

    // MLP chunked over the hidden dim (PROVEN round 24)
    for (int c = 0; c < 4; ++c) {
        mfma_lds<bf16, 1, 0, 0><<<dim3(64, 8, 1), 256, 0, stream>>>(
            h, Wt1 + (size_t)c * 1024 * CD, Wt1, Wt1, g1, g1, g1,
            b1, c * 1024, CB * CS, 1024, CD, CD, CD, 0, flag);
        if (c == 0)
            mfma_lds<float, 0, 0, 0><<<dim3(64, 8, 1), 256, 0, stream>>>(
                g1, Wt2 + (size_t)c * 1024, Wt2, Wt2, a, a, a,
                b2, 0, CB * CS, CD, 1024, 1024, CDH, 0, flag);
        else
            mfma_lds<float, 0, 0, 1><<<dim3(64, 8, 1), 256, 0, stream>>>(
                g1, Wt2 + (size_t)c * 1024, Wt2, Wt2, a, a, a,
                nullptr, 0, CB * CS, CD, 1024, 1024, CDH, 0, flag);
    }
    ln_kernel<<<CB * CS, 256, 0, stream>>>(a, x, g_mlp, b_mlp, d_out, 1, flag);
}

// Round 27
// 1150.117 us; speedup vs baseline: 1.3694x; 1.0139x over previous
//
#include <hip/hip_runtime.h>
#include <hip/hip_bf16.h>

typedef __hip_bfloat16 bf16;
typedef short bf16x8 __attribute__((ext_vector_type(8)));   // 8 bf16 = 4 VGPRs
typedef float f32x4 __attribute__((ext_vector_type(4)));

// Problem constants
#define CB 2
#define CS 4096
#define CD 1024
#define CL 512
#define CST 64
#define CH 8
#define CT 640      // 2*ST + L
#define CDH 4096
#define NSEG 8
#define LP 80       // padded LDS row length (bf16) for attn tiles

__device__ __forceinline__ float tof(float x) { return x; }
__device__ __forceinline__ float tof(bf16 x) { return __bfloat162float(x); }
__device__ __forceinline__ void storev(float* p, float v) { *p = v; }
__device__ __forceinline__ void storev(bf16* p, float v) { *p = __float2bfloat16(v); }

__device__ __forceinline__ float ldin(const void* p, size_t i, int f32w) {
    if (f32w) return ((const float*)p)[i];
    return __bfloat162float(((const bf16*)p)[i]);
}

// ---------------------------------------------------------------------------
// Dtype sniffer (proven rounds 2/6-26; resolves flag=0 = bf16 here).
// ---------------------------------------------------------------------------
__global__ void sniff_kernel(const void* x, int* flag) {
    if (threadIdx.x == 0 && blockIdx.x == 0) {
        const bf16* hb = (const bf16*)x;
        int plaus = 0;
        for (int i = 0; i < 256; ++i) {
            float v = __bfloat162float(hb[2 * i]);
            float a = fabsf(v);
            if (v == 0.f || (a > 1e-4f && a < 100.f)) ++plaus;
        }
        flag[0] = (plaus < 128) ? 1 : 0;
    }
}

// ---------------------------------------------------------------------------
// bf16 transpose: out[C][R] = in[R][C], 64x64 tiles. PROVEN rounds 7-26.
// ---------------------------------------------------------------------------
__global__ __launch_bounds__(256) void transpose_kernel(
    const void* __restrict__ in, bf16* __restrict__ out, int R, int C,
    const int* __restrict__ flag)
{
    const int f32w = flag[0];
    __shared__ short t[64][72];
    int tid = threadIdx.x;
    int c0 = blockIdx.x * 64, r0 = blockIdx.y * 64;
    int cc = tid & 63, rr = tid >> 6;
#pragma unroll
    for (int i = 0; i < 16; ++i) {
        bf16 v = __float2bfloat16(ldin(in, (size_t)(r0 + rr + i * 4) * C + c0 + cc, f32w));
        t[rr + i * 4][cc] = *(short*)&v;
    }
    __syncthreads();
#pragma unroll
    for (int i = 0; i < 16; ++i)
        ((short*)out)[(size_t)(c0 + rr + i * 4) * R + r0 + cc] = t[cc][rr + i * 4];
}

// ---------------------------------------------------------------------------
// Merged QKV weight transpose (PROVEN rounds 21-26): 3 dispatches -> 1.
// ---------------------------------------------------------------------------
__global__ __launch_bounds__(256) void transpose3_kernel(
    const void* __restrict__ in0, const void* __restrict__ in1, const void* __restrict__ in2,
    bf16* __restrict__ out0, bf16* __restrict__ out1, bf16* __restrict__ out2,
    const int* __restrict__ flag)
{
    const int f32w = flag[0];
    const void* in = (blockIdx.z == 0) ? in0 : (blockIdx.z == 1 ? in1 : in2);
    bf16* out = (blockIdx.z == 0) ? out0 : (blockIdx.z == 1 ? out1 : out2);
    const int R = CD, C = 512;
    __shared__ short t[64][72];
    int tid = threadIdx.x;
    int c0 = blockIdx.x * 64, r0 = blockIdx.y * 64;
    int cc = tid & 63, rr = tid >> 6;
#pragma unroll
    for (int i = 0; i < 16; ++i) {
        bf16 v = __float2bfloat16(ldin(in, (size_t)(r0 + rr + i * 4) * C + c0 + cc, f32w));
        t[rr + i * 4][cc] = *(short*)&v;
    }
    __syncthreads();
#pragma unroll
    for (int i = 0; i < 16; ++i)
        ((short*)out)[(size_t)(c0 + rr + i * 4) * R + r0 + cc] = t[cc][rr + i * 4];
}

// ---------------------------------------------------------------------------
// Per-head 64x64 transpose of Wq1/Wk1/Wv1 (PROVEN rounds 15-26).
// ---------------------------------------------------------------------------
__global__ __launch_bounds__(256) void transposeH_kernel(
    const void* __restrict__ Wq1, const void* __restrict__ Wk1, const void* __restrict__ Wv1,
    bf16* __restrict__ oq, bf16* __restrict__ ok, bf16* __restrict__ ov,
    const int* __restrict__ flag)
{
    const int f32w = flag[0];
    int which = blockIdx.x >> 3, hh = blockIdx.x & 7;
    const void* in = (which == 0) ? Wq1 : (which == 1) ? Wk1 : Wv1;
    bf16* out = (which == 0) ? oq : (which == 1) ? ok : ov;
    __shared__ short t[64][72];
    int tid = threadIdx.x;
    int cc = tid & 63, rr = tid >> 6;
    size_t base = (size_t)hh * 4096;
#pragma unroll
    for (int i = 0; i < 16; ++i) {
        bf16 v = __float2bfloat16(ldin(in, base + (size_t)(rr + i * 4) * 64 + cc, f32w));
        t[rr + i * 4][cc] = *(short*)&v;
    }
    __syncthreads();
#pragma unroll
    for (int i = 0; i < 16; ++i)
        ((short*)out)[base + (size_t)(rr + i * 4) * 64 + cc] = t[cc][rr + i * 4];
}

// ---------------------------------------------------------------------------
// MFMA GEMM, register-staged linear LDS, BK=64, DEPTH-2 PREFETCH (PROVEN).
// OUTM=0: row-major C (+ACCUM reads prior C via tof, works for bf16/f32).
// OUTM=2: state-only (small Wo; row -> fp32 state rows 0..127 via ST ptr).
// ---------------------------------------------------------------------------
template <typename TC, int ACT, int OUTM, int ACCUM>
__global__ __launch_bounds__(256) void mfma_lds(
    const bf16* __restrict__ A,
    const bf16* __restrict__ Bt0, const bf16* __restrict__ Bt1, const bf16* __restrict__ Bt2,
    TC* __restrict__ C0, TC* __restrict__ C1, TC* __restrict__ C2,
    float* __restrict__ ST,
    const void* __restrict__ bias, int boff,
    int M, int N, int K, int lda, int ldb, int seg,
    const int* __restrict__ flag)
{
    const int f32w = flag[0];
    const bf16* Bt = (blockIdx.z == 0) ? Bt0 : (blockIdx.z == 1 ? Bt1 : Bt2);
    TC* C = (blockIdx.z == 0) ? C0 : (blockIdx.z == 1 ? C1 : C2);

    __shared__ __align__(16) short As[128 * 64];
    __shared__ __align__(16) short Bs[128 * 64];

    const int tid = threadIdx.x;
    const int lane = tid & 63;
    const int w = tid >> 6;
    const int wm = w >> 1, wn = w & 1;
    const int bm = blockIdx.x * 128, bn = blockIdx.y * 128;

    f32x4 acc[4][4];
#pragma unroll
    for (int i = 0; i < 4; ++i)
#pragma unroll
        for (int j = 0; j < 4; ++j) acc[i][j] = (f32x4){0.f, 0.f, 0.f, 0.f};

    int srow[4], skc[4];
#pragma unroll
    for (int i = 0; i < 4; ++i) {
        int c = i * 256 + tid;
        srow[i] = c >> 3;
        skc[i] = (c & 7) * 8;
    }

    bf16x8 rA0[4], rB0[4], rA1[4], rB1[4];
#pragma unroll
    for (int i = 0; i < 4; ++i) {
        rA0[i] = *(const bf16x8*)(A + (size_t)(bm + srow[i]) * lda + skc[i]);
        rB0[i] = *(const bf16x8*)(Bt + (size_t)(bn + srow[i]) * ldb + skc[i]);
        rA1[i] = *(const bf16x8*)(A + (size_t)(bm + srow[i]) * lda + 64 + skc[i]);
        rB1[i] = *(const bf16x8*)(Bt + (size_t)(bn + srow[i]) * ldb + 64 + skc[i]);
    }

#define MFMA_PHASE                                                              \
    _Pragma("unroll")                                                           \
    for (int kh = 0; kh < 2; ++kh) {                                            \
        bf16x8 av[4], bv[4];                                                    \
        _Pragma("unroll")                                                       \
        for (int mi = 0; mi < 4; ++mi) {                                        \
            int r = wm * 64 + mi * 16 + (lane & 15);                            \
            int cl = kh * 4 + (lane >> 4);                                      \
            av[mi] = *(const bf16x8*)&As[r * 64 + cl * 8];                      \
        }                                                                       \
        _Pragma("unroll")                                                       \
        for (int nj = 0; nj < 4; ++nj) {                                        \
            int r = wn * 64 + nj * 16 + (lane & 15);                            \
            int cl = kh * 4 + (lane >> 4);                                      \
            bv[nj] = *(const bf16x8*)&Bs[r * 64 + cl * 8];                      \
        }                                                                       \
        _Pragma("unroll")                                                       \
        for (int mi = 0; mi < 4; ++mi)                                          \
            _Pragma("unroll")                                                   \
            for (int nj = 0; nj < 4; ++nj)                                      \
                acc[mi][nj] = __builtin_amdgcn_mfma_f32_16x16x32_bf16(          \
                    av[mi], bv[nj], acc[mi][nj], 0, 0, 0);                      \
    }

    for (int k0 = 0; k0 < K; k0 += 128) {
        __syncthreads();
#pragma unroll
        for (int i = 0; i < 4; ++i) {
            *(bf16x8*)&As[(size_t)(i * 256 + tid) * 8] = rA0[i];
            *(bf16x8*)&Bs[(size_t)(i * 256 + tid) * 8] = rB0[i];
        }
        if (k0 + 128 < K) {
            int kn = k0 + 128;
#pragma unroll
            for (int i = 0; i < 4; ++i) {
                rA0[i] = *(const bf16x8*)(A + (size_t)(bm + srow[i]) * lda + kn + skc[i]);
                rB0[i] = *(const bf16x8*)(Bt + (size_t)(bn + srow[i]) * ldb + kn + skc[i]);
            }
        }
        __syncthreads();
        MFMA_PHASE

        __syncthreads();
#pragma unroll
        for (int i = 0; i < 4; ++i) {
            *(bf16x8*)&As[(size_t)(i * 256 + tid) * 8] = rA1[i];
            *(bf16x8*)&Bs[(size_t)(i * 256 + tid) * 8] = rB1[i];
        }
        if (k0 + 192 < K) {
            int kn = k0 + 192;
#pragma unroll
            for (int i = 0; i < 4; ++i) {
                rA1[i] = *(const bf16x8*)(A + (size_t)(bm + srow[i]) * lda + kn + skc[i]);
                rB1[i] = *(const bf16x8*)(Bt + (size_t)(bn + srow[i]) * ldb + kn + skc[i]);
            }
        }
        __syncthreads();
        MFMA_PHASE
    }
#undef MFMA_PHASE

#pragma unroll
    for (int mi = 0; mi < 4; ++mi) {
#pragma unroll
        for (int nj = 0; nj < 4; ++nj) {
            int c = bn + wn * 64 + nj * 16 + (lane & 15);
            float bia = bias ? ldin(bias, boff + c, f32w) : 0.f;
#pragma unroll
            for (int r = 0; r < 4; ++r) {
                int row = bm + wm * 64 + mi * 16 + (lane >> 4) * 4 + r;
                float v = acc[mi][nj][r] + bia;
                if (ACT == 1) v = 0.5f * v * (1.0f + erff(v * 0.70710678118654752f));
                if (OUTM == 0) {
                    if (ACCUM) v += tof(C[(size_t)row * N + c]);
                    storev(C + (size_t)row * N + c, v);
                } else {  // OUTM == 2: small Wo -> fp32 state rows (row = b*64+t)
                    ST[(size_t)row * CD + c] = v;
                }
            }
        }
    }
}

// ---------------------------------------------------------------------------
// RoPE (in-place, bf16) on q and k + LDS-tiled transpose of v -> vt.
// PROVEN rounds 12-26.
// ---------------------------------------------------------------------------
__global__ __launch_bounds__(256) void ropeV_kernel(
    bf16* __restrict__ q, bf16* __restrict__ k,
    const bf16* __restrict__ v, bf16* __restrict__ vt)
{
    int t0 = blockIdx.x * 64, hh = blockIdx.y, b = blockIdx.z;
    int tid = threadIdx.x;
    __shared__ short lt[64][72];
    int c = tid & 63;
    int r0 = tid >> 6;
    int ip = c >> 1;
    float inv = powf(10000.f, -(float)(2 * ip) / 64.f);
#pragma unroll
    for (int i = 0; i < 16; ++i) {
        int r = r0 + i * 4;
        int t = t0 + r;
        size_t idx = ((size_t)b * CT + t) * 512 + hh * 64 + c;
        float qv = tof(q[idx]);
        float kv = tof(k[idx]);
        float ang = (float)t * inv;
        float sn, cs;
        sincosf(ang, &sn, &cs);
        float qp = __shfl_xor(qv, 1);
        float kp = __shfl_xor(kv, 1);
        float rq, rk;
        if (c & 1) { rq = qp * sn + qv * cs; rk = kp * sn + kv * cs; }
        else       { rq = qv * cs - qp * sn; rk = kv * cs - kp * sn; }
        q[idx] = __float2bfloat16(rq);
        k[idx] = __float2bfloat16(rk);
        lt[r][c] = ((const short*)v)[idx];
    }
    __syncthreads();
#pragma unroll
    for (int i = 0; i < 16; ++i) {
        int c2 = r0 + i * 4;
        int r2 = c;
        ((short*)vt)[((size_t)(b * CH + hh) * 64 + c2) * CT + t0 + r2] = lt[r2][c2];
    }
}

// ---------------------------------------------------------------------------
// MFMA flash attention (core PROVEN rounds 12-26).
// FUSE=1: grid x=10; epilogue proj1+RoPE -> q1/k1/v1t.
// FUSE=0: grid x=9; tiles 1..8 -> o1mid (batch-major), tile-9 -> o1s.
// ---------------------------------------------------------------------------
template <int FUSE>
__global__ __launch_bounds__(256) void attn_mfma(
    const bf16* __restrict__ q, const bf16* __restrict__ k, const bf16* __restrict__ vt,
    bf16* __restrict__ o,
    int qsb, int qsh, int qst,
    int ksb, int ksh, int kst,
    int seg,
    const bf16* __restrict__ Wq1t, const bf16* __restrict__ Wk1t, const bf16* __restrict__ Wv1t,
    bf16* __restrict__ q1o, bf16* __restrict__ k1o, bf16* __restrict__ v1to)
{
    const int tid = threadIdx.x;
    const int lane = tid & 63;
    const int wrow = tid >> 6;
    const int hh = blockIdx.y, b = blockIdx.z;
    const int qbase = (FUSE ? ((int)gridDim.x - 1 - (int)blockIdx.x)
                            : ((int)gridDim.x - (int)blockIdx.x)) * 64;

    __shared__ __align__(16) short Qs[64 * LP];
    __shared__ __align__(16) short Ks[64 * LP];
    __shared__ __align__(16) short Vs[64 * LP];
    __shared__ __align__(16) short Ps[64 * LP];

    const size_t qb0 = (size_t)b * qsb + (size_t)hh * qsh;
    const size_t kb0 = (size_t)b * ksb + (size_t)hh * ksh;
    const size_t vtb = (size_t)(b * CH + hh) * 64 * CT;

    int srow[2], skc[2], soff[2];
#pragma unroll
    for (int i = 0; i < 2; ++i) {
        int c = i * 256 + tid;
        srow[i] = c >> 3;
        skc[i] = c & 7;
        soff[i] = srow[i] * LP + skc[i] * 8;
    }

    bf16x8 rQ[2], rK[2], rV[2];
#pragma unroll
    for (int i = 0; i < 2; ++i) {
        rQ[i] = *(const bf16x8*)(q + qb0 + (size_t)(qbase + srow[i]) * qst + skc[i] * 8);
        rK[i] = *(const bf16x8*)(k + kb0 + (size_t)srow[i] * kst + skc[i] * 8);
        rV[i] = *(const bf16x8*)(vt + vtb + (size_t)srow[i] * CT + skc[i] * 8);
    }

    float mrow[4], lrow[4];
    f32x4 oacc[4];
#pragma unroll
    for (int r = 0; r < 4; ++r) { mrow[r] = -1e30f; lrow[r] = 0.f; }
#pragma unroll
    for (int nd = 0; nd < 4; ++nd) oacc[nd] = (f32x4){0.f, 0.f, 0.f, 0.f};

    const int ntiles = qbase / 64 + 1;
    for (int ti = 0; ti < ntiles; ++ti) {
        __syncthreads();
        if (ti == 0) {
#pragma unroll
            for (int i = 0; i < 2; ++i) *(bf16x8*)&Qs[soff[i]] = rQ[i];
        }
#pragma unroll
        for (int i = 0; i < 2; ++i) {
            *(bf16x8*)&Ks[soff[i]] = rK[i];
            *(bf16x8*)&Vs[soff[i]] = rV[i];
        }
        if (ti + 1 < ntiles) {
            int j1 = (ti + 1) * 64;
#pragma unroll
            for (int i = 0; i < 2; ++i) {
                rK[i] = *(const bf16x8*)(k + kb0 + (size_t)(j1 + srow[i]) * kst + skc[i] * 8);
                rV[i] = *(const bf16x8*)(vt + vtb + (size_t)srow[i] * CT + j1 + skc[i] * 8);
            }
        }
        __syncthreads();

        f32x4 sacc[4];
#pragma unroll
        for (int nj = 0; nj < 4; ++nj) sacc[nj] = (f32x4){0.f, 0.f, 0.f, 0.f};
#pragma unroll
        for (int kh = 0; kh < 2; ++kh) {
            int cl = kh * 4 + (lane >> 4);
            bf16x8 av = *(const bf16x8*)&Qs[(wrow * 16 + (lane & 15)) * LP + cl * 8];
#pragma unroll
            for (int nj = 0; nj < 4; ++nj) {
                bf16x8 bv = *(const bf16x8*)&Ks[(nj * 16 + (lane & 15)) * LP + cl * 8];
                sacc[nj] = __builtin_amdgcn_mfma_f32_16x16x32_bf16(av, bv, sacc[nj], 0, 0, 0);
            }
        }

        const bool diag = (ti == ntiles - 1);
        float pm[4] = {-1e30f, -1e30f, -1e30f, -1e30f};
#pragma unroll
        for (int nj = 0; nj < 4; ++nj) {
            int col_l = nj * 16 + (lane & 15);
#pragma unroll
            for (int r = 0; r < 4; ++r) {
                int row_l = wrow * 16 + ((lane >> 4) << 2) + r;
                float s = (diag && col_l > row_l) ? -1e30f : sacc[nj][r] * 0.125f;
                sacc[nj][r] = s;
                pm[r] = fmaxf(pm[r], s);
            }
        }
#pragma unroll
        for (int msk = 1; msk < 16; msk <<= 1)
#pragma unroll
            for (int r = 0; r < 4; ++r) pm[r] = fmaxf(pm[r], __shfl_xor(pm[r], msk));

        float corr[4], rs[4] = {0.f, 0.f, 0.f, 0.f};
#pragma unroll
        for (int r = 0; r < 4; ++r) {
            float mn = fmaxf(mrow[r], pm[r]);
            corr[r] = __expf(mrow[r] - mn);
            mrow[r] = mn;
        }
#pragma unroll
        for (int nj = 0; nj < 4; ++nj)
#pragma unroll
            for (int r = 0; r < 4; ++r) {
                float p = __expf(sacc[nj][r] - mrow[r]);
                sacc[nj][r] = p;
                rs[r] += p;
            }
#pragma unroll
        for (int msk = 1; msk < 16; msk <<= 1)
#pragma unroll
            for (int r = 0; r < 4; ++r) rs[r] += __shfl_xor(rs[r], msk);
#pragma unroll
        for (int r = 0; r < 4; ++r) lrow[r] = lrow[r] * corr[r] + rs[r];
#pragma unroll
        for (int nd = 0; nd < 4; ++nd)
#pragma unroll
            for (int r = 0; r < 4; ++r) oacc[nd][r] *= corr[r];

#pragma unroll
        for (int nj = 0; nj < 4; ++nj)
#pragma unroll
            for (int r = 0; r < 4; ++r) {
                bf16 pb = __float2bfloat16(sacc[nj][r]);
                Ps[(wrow * 16 + ((lane >> 4) << 2) + r) * LP + nj * 16 + (lane & 15)] =
                    *(short*)&pb;
            }

#pragma unroll
        for (int kh = 0; kh < 2; ++kh) {
            int cl = kh * 4 + (lane >> 4);
            bf16x8 pa = *(const bf16x8*)&Ps[(wrow * 16 + (lane & 15)) * LP + cl * 8];
#pragma unroll
            for (int nd = 0; nd < 4; ++nd) {
                bf16x8 bv = *(const bf16x8*)&Vs[(nd * 16 + (lane & 15)) * LP + cl * 8];
                oacc[nd] = __builtin_amdgcn_mfma_f32_16x16x32_bf16(pa, bv, oacc[nd], 0, 0, 0);
            }
        }
    }

    if (FUSE == 0) {
        // per-block-uniform destination select (tile granularity == 64)
        bf16* dst;
        int rbase;
        if (qbase == 576) { dst = q1o; rbase = b * 64 - 576; }          // o1s
        else              { dst = o;   rbase = (b * 8 + seg) * 512 - 64; }  // o1mid
#pragma unroll
        for (int nd = 0; nd < 4; ++nd) {
#pragma unroll
            for (int r = 0; r < 4; ++r) {
                int row_g = qbase + wrow * 16 + ((lane >> 4) << 2) + r;
                int col = nd * 16 + (lane & 15);
                dst[(size_t)(rbase + row_g) * 512 + hh * 64 + col] =
                    __float2bfloat16(oacc[nd][r] / lrow[r]);
            }
        }
    } else {
#pragma unroll
        for (int nd = 0; nd < 4; ++nd)
#pragma unroll
            for (int r = 0; r < 4; ++r) {
                int row_l = wrow * 16 + ((lane >> 4) << 2) + r;
                bf16 ob16 = __float2bfloat16(oacc[nd][r] / lrow[r]);
                Qs[row_l * LP + nd * 16 + (lane & 15)] = *(short*)&ob16;
            }
        __syncthreads();

        const size_t whb = (size_t)hh * 4096;
        f32x4 qa[4], ka[4], va[4];
#pragma unroll
        for (int nj = 0; nj < 4; ++nj) {
            qa[nj] = (f32x4){0.f, 0.f, 0.f, 0.f};
            ka[nj] = (f32x4){0.f, 0.f, 0.f, 0.f};
            va[nj] = (f32x4){0.f, 0.f, 0.f, 0.f};
        }
#pragma unroll
        for (int kh = 0; kh < 2; ++kh) {
            int cl = kh * 4 + (lane >> 4);
            bf16x8 av = *(const bf16x8*)&Qs[(wrow * 16 + (lane & 15)) * LP + cl * 8];
#pragma unroll
            for (int nj = 0; nj < 4; ++nj) {
                int rowb = nj * 16 + (lane & 15);
                bf16x8 bq = *(const bf16x8*)(Wq1t + whb + (size_t)rowb * 64 + cl * 8);
                bf16x8 bk = *(const bf16x8*)(Wk1t + whb + (size_t)rowb * 64 + cl * 8);
                bf16x8 bw = *(const bf16x8*)(Wv1t + whb + (size_t)rowb * 64 + cl * 8);
                qa[nj] = __builtin_amdgcn_mfma_f32_16x16x32_bf16(av, bq, qa[nj], 0, 0, 0);
                ka[nj] = __builtin_amdgcn_mfma_f32_16x16x32_bf16(av, bk, ka[nj], 0, 0, 0);
                va[nj] = __builtin_amdgcn_mfma_f32_16x16x32_bf16(av, bw, va[nj], 0, 0, 0);
            }
        }
        const size_t bh = (size_t)(b * CH + hh);
#pragma unroll
        for (int nj = 0; nj < 4; ++nj) {
            int col = nj * 16 + (lane & 15);
            int ip = col >> 1;
            float inv = powf(10000.f, -(float)(2 * ip) / 64.f);
#pragma unroll
            for (int r = 0; r < 4; ++r) {
                int row_l = wrow * 16 + ((lane >> 4) << 2) + r;
                int t = qbase + row_l;
                float ang = (float)t * inv;
                float sn, cs;
                sincosf(ang, &sn, &cs);
                float aq = qa[nj][r], ak = ka[nj][r];
                float pq = __shfl_xor(aq, 1);
                float pk = __shfl_xor(ak, 1);
                float rq, rk;
                if (col & 1) { rq = pq * sn + aq * cs; rk = pk * sn + ak * cs; }
                else         { rq = aq * cs - pq * sn; rk = ak * cs - pk * sn; }
                size_t roff = (bh * CT + t) * 64 + col;
                q1o[roff] = __float2bfloat16(rq);
                k1o[roff] = __float2bfloat16(rk);
                v1to[(bh * 64 + col) * CT + t] = __float2bfloat16(va[nj][r]);
            }
        }
    }
}

// toks = concat([state, x_seg, state]) -> bf16 (PROVEN; separate pass wins)
__global__ __launch_bounds__(256) void build_toks_kernel(
    const void* __restrict__ x, const float* __restrict__ state, bf16* __restrict__ toks,
    int seg, const int* __restrict__ flag)
{
    const int f32w = flag[0];
    int idx = blockIdx.x * 256 + threadIdx.x;  // B*T*D
    int d = idx & (CD - 1);
    int t = (idx >> 10) % CT;
    int b = idx / (CT * CD);
    float v;
    if (t < CST) v = state[(b * CST + t) * CD + d];
    else if (t < CST + CL) v = ldin(x, ((size_t)b * CS + seg * CL + (t - CST)) * CD + d, f32w);
    else v = state[(b * CST + (t - CST - CL)) * CD + d];
    toks[idx] = __float2bfloat16(v);
}

__global__ __launch_bounds__(256) void init_state_kernel(
    const void* __restrict__ s0, float* __restrict__ state, const int* __restrict__ flag)
{
    const int f32w = flag[0];
    int idx = blockIdx.x * 256 + threadIdx.x;  // B*ST*D
    state[idx] = ldin(s0, idx % (CST * CD), f32w);
}

// LayerNorm(ra + x) * g + b.  ra is now bf16 (this round's change).
__global__ __launch_bounds__(256) void ln_kernel(
    const bf16* __restrict__ ra, const void* __restrict__ x,
    const void* __restrict__ g, const void* __restrict__ bb,
    void* __restrict__ outp, int out_ext, const int* __restrict__ flag)
{
    const int f32w = flag[0];
    int row = blockIdx.x;
    int tid = threadIdx.x;
    __shared__ float buf[CD];
    __shared__ float red[4];

    float s = 0.f;
    for (int c = tid; c < CD; c += 256) {
        float v = tof(ra[(size_t)row * CD + c]) + ldin(x, (size_t)row * CD + c, f32w);
        buf[c] = v;
        s += v;
    }
#pragma unroll
    for (int off = 32; off; off >>= 1) s += __shfl_xor(s, off);
    if ((tid & 63) == 0) red[tid >> 6] = s;
    __syncthreads();
    float mu = (red[0] + red[1] + red[2] + red[3]) * (1.f / CD);
    __syncthreads();

    float vs = 0.f;
    for (int c = tid; c < CD; c += 256) {
        float d0 = buf[c] - mu;
        vs += d0 * d0;
    }
#pragma unroll
    for (int off = 32; off; off >>= 1) vs += __shfl_xor(vs, off);
    if ((tid & 63) == 0) red[tid >> 6] = vs;
    __syncthreads();
    float var = (red[0] + red[1] + red[2] + red[3]) * (1.f / CD);
    float rs = rsqrtf(var + 1e-5f);

    for (int c = tid; c < CD; c += 256) {
        float y = (buf[c] - mu) * rs * ldin(g, c, f32w) + ldin(bb, c, f32w);
        size_t idx = (size_t)row * CD + c;
        if (!out_ext) {
            ((bf16*)outp)[idx] = __float2bfloat16(y);
        } else if (f32w) {
            ((float*)outp)[idx] = y;
        } else {
            ((bf16*)outp)[idx] = __float2bfloat16(y);
        }
    }
}

extern "C" void kernel_launch(void* const* d_in, const int* in_sizes, int n_in,
                              void* d_out, int out_size, void* d_ws, size_t ws_size,
                              hipStream_t stream)
{
    const void* x      = d_in[0];
    const void* s0     = d_in[1];
    const void* Wq0    = d_in[2];
    const void* Wk0    = d_in[3];
    const void* Wv0    = d_in[4];
    const void* Wq1    = d_in[5];
    const void* Wk1    = d_in[6];
    const void* Wv1    = d_in[7];
    const void* Wo     = d_in[8];
    const void* bo     = d_in[9];
    const void* g_attn = d_in[10];
    const void* b_attn = d_in[11];
    const void* W1     = d_in[12];
    const void* b1     = d_in[13];
    const void* W2     = d_in[14];
    const void* b2     = d_in[15];
    const void* g_mlp  = d_in[16];
    const void* b_mlp  = d_in[17];

    // workspace slot layout BYTE-IDENTICAL to passing rounds 2/6-26 (~90.7 MB)
    int* flag = (int*)d_ws;
    float* f = (float*)((char*)d_ws + 16);
    float* toks_slot = f; f += (size_t)CB * CT * CD;       // bf16 toks
    float* q0_slot = f;  f += (size_t)CB * CH * CT * 64;   // bf16 q0 [1280][512]
    float* k0_slot = f;  f += (size_t)CB * CH * CT * 64;   // bf16 k0
    float* v0_slot = f;  f += (size_t)CB * CH * CT * 64;   // bf16 v0
    float* o0_slot = f;  f += (size_t)CB * CH * CT * 64;   // bf16 v0t
    float* q1_slot = f;  f += (size_t)CB * CH * CT * 64;   // bf16 q1
    float* k1_slot = f;  f += (size_t)CB * CH * CT * 64;   // bf16 k1
    float* v1_slot = f;  f += (size_t)CB * CH * CT * 64;   // bf16 v1t
    float* o1t_slot = f; f += (size_t)CB * CT * (CH * 64); // (unused during segments)
    float* seg_slot = f; f += (size_t)CB * CT * CD;        // (unused during segments)
    float* state = f;   f += (size_t)CB * CST * CD;        // fp32 state
    float* a_slot = f;  f += (size_t)CB * CS * CD;         // bf16 a (half used)
    bf16* h = (bf16*)f;                                    // LN1 out [B*S, D] bf16
    bf16* tail = h + (size_t)CB * CS * CD;                 // 8.39 MB tail slot

    bf16* toks = (bf16*)toks_slot;
    bf16* q0b = (bf16*)q0_slot;
    bf16* k0b = (bf16*)k0_slot;
    bf16* v0b = (bf16*)v0_slot;
    bf16* v0t = (bf16*)o0_slot;
    bf16* q1b = (bf16*)q1_slot;
    bf16* k1b = (bf16*)k1_slot;
    bf16* v1t = (bf16*)v1_slot;
    bf16* ab  = (bf16*)a_slot;                             // [8192][1024] bf16
    bf16* WtQ = h;                                         // h region dead until LN1
    bf16* WtK = WtQ + (size_t)512 * 1024;
    bf16* WtV = WtK + (size_t)512 * 1024;
    bf16* WtO = WtV + (size_t)512 * 1024;                  // [1024][512]
    bf16* WtQ1 = WtO + (size_t)1024 * 512;                 // per-head [8][64][64]
    bf16* WtK1 = WtQ1 + (size_t)8 * 4096;
    bf16* WtV1 = WtK1 + (size_t)8 * 4096;
    // o1mid/o1s after transposed weights in h region (round-26-proven fit:
    // 4.19 + 8.39 + 0.13 = 12.71 MB < 16.78 MB).
    bf16* o1mid = WtV1 + (size_t)8 * 4096;                 // [B*NSEG*512][512]
    bf16* o1s = o1mid + (size_t)CB * NSEG * 512 * 512;     // [128][512]
    // MLP phase (toks..q1 region dead): g1 at region base, Wt1 after, Wt2 tail.
    bf16* g1  = (bf16*)toks_slot;                          // [8192][1024] 16.78 MB
    bf16* Wt1 = g1 + (size_t)CB * CS * CD;                 // [CDH][CD]    8.39 MB
    bf16* Wt2 = tail;                                      // [CD][CDH]    8.39 MB

    sniff_kernel<<<1, 64, 0, stream>>>(x, flag);
    init_state_kernel<<<(CB * CST * CD) / 256, 256, 0, stream>>>(s0, state, flag);

    transpose3_kernel<<<dim3(8, 16, 3), 256, 0, stream>>>(
        Wq0, Wk0, Wv0, WtQ, WtK, WtV, flag);
    transpose_kernel<<<dim3(16, 8), 256, 0, stream>>>(Wo, WtO, 512, CD, flag);
    transposeH_kernel<<<24, 256, 0, stream>>>(Wq1, Wk1, Wv1, WtQ1, WtK1, WtV1, flag);

    for (int seg = 0; seg < NSEG; ++seg) {
        build_toks_kernel<<<(CB * CT * CD) / 256, 256, 0, stream>>>(x, state, toks, seg, flag);
        // QKV GEMM (proven path), row-major bf16 outputs
        mfma_lds<bf16, 0, 0, 0><<<dim3(10, 4, 3), 256, 0, stream>>>(
            toks, WtQ, WtK, WtV, q0b, k0b, v0b, nullptr, nullptr, 0,
            CB * CT, 512, CD, CD, CD, 0, flag);
        // RoPE q0,k0 in place + V transpose -> v0t (proven separate pass)
        ropeV_kernel<<<dim3(CT / 64, CH, CB), 256, 0, stream>>>(q0b, k0b, v0b, v0t);
        // attn1 (row-major Q/K + v0t) with FUSED proj1+RoPE epilogue (grid 10)
        attn_mfma<1><<<dim3(CT / 64, CH, CB), 256, 0, stream>>>(
            q0b, k0b, v0t, nullptr,
            CT * 512, 64, 512,
            CT * 512, 64, 512,
            seg,
            WtQ1, WtK1, WtV1, q1b, k1b, v1t);
        // attn2 (head-major Q/K + v1t), grid 9: middle -> o1mid, tile9 -> o1s
        attn_mfma<0><<<dim3(9, CH, CB), 256, 0, stream>>>(
            q1b, k1b, v1t, o1mid,
            CH * CT * 64, CT * 64, 64,
            CH * CT * 64, CT * 64, 64,
            seg,
            nullptr, nullptr, nullptr, o1s, nullptr, nullptr);
        // small Wo: state rows only (M=128, 8 blocks) -> fp32 state
        mfma_lds<bf16, 0, 2, 0><<<dim3(1, 8, 1), 256, 0, stream>>>(
            o1s, WtO, WtO, WtO, ab, ab, ab, state, bo, 0,
            128, CD, 512, 512, 512, seg, flag);
    }

    // big Wo: all middle rows (M=8192, grid 64x8=512 blocks) -> ab (bf16) + bo
    mfma_lds<bf16, 0, 0, 0><<<dim3(64, 8, 1), 256, 0, stream>>>(
        o1mid, WtO, WtO, WtO, ab, ab, ab, nullptr, bo, 0,
        CB * CS, CD, 512, 512, 512, 0, flag);

    // h = LN(ab + x) -> bf16 internal (overwrites WtQ..o1s — dead by now)
    ln_kernel<<<CB * CS, 256, 0, stream>>>(ab, x, g_attn, b_attn, h, 0, flag);

    transpose_kernel<<<dim3(CDH / 64, CD / 64), 256, 0, stream>>>(W1, Wt1, CD, CDH, flag);
    transpose_kernel<<<dim3(CD / 64, CDH / 64), 256, 0, stream>>>(W2, Wt2, CDH, CD, flag);

    // MLP chunked over the hidden dim (PROVEN round 24/26); ab is bf16 now
    for (int c = 0; c < 4; ++c) {
        mfma_lds<bf16, 1, 0, 0><<<dim3(64, 8, 1), 256, 0, stream>>>(
            h, Wt1 + (size_t)c * 1024 * CD, Wt1, Wt1, g1, g1, g1, nullptr,
            b1, c * 1024, CB * CS, 1024, CD, CD, CD, 0, flag);
        if (c == 0)
            mfma_lds<bf16, 0, 0, 0><<<dim3(64, 8, 1), 256, 0, stream>>>(
                g1, Wt2 + (size_t)c * 1024, Wt2, Wt2, ab, ab, ab, nullptr,
                b2, 0, CB * CS, CD, 1024, 1024, CDH, 0, flag);
        else
            mfma_lds<bf16, 0, 0, 1><<<dim3(64, 8, 1), 256, 0, stream>>>(
                g1, Wt2 + (size_t)c * 1024, Wt2, Wt2, ab, ab, ab, nullptr,
                nullptr, 0, CB * CS, CD, 1024, 1024, CDH, 0, flag);
    }
    ln_kernel<<<CB * CS, 256, 0, stream>>>(ab, x, g_mlp, b_mlp, d_out, 1, flag);
}

// Round 28
// 1149.603 us; speedup vs baseline: 1.3700x; 1.0004x over previous
//
#include <hip/hip_runtime.h>
#include <hip/hip_bf16.h>

typedef __hip_bfloat16 bf16;
typedef short bf16x8 __attribute__((ext_vector_type(8)));   // 8 bf16 = 4 VGPRs
typedef float f32x4 __attribute__((ext_vector_type(4)));

// Problem constants
#define CB 2
#define CS 4096
#define CD 1024
#define CL 512
#define CST 64
#define CH 8
#define CT 640      // 2*ST + L
#define CDH 4096
#define NSEG 8
#define LP 80       // padded LDS row length (bf16) for attn tiles

__device__ __forceinline__ float tof(float x) { return x; }
__device__ __forceinline__ float tof(bf16 x) { return __bfloat162float(x); }
__device__ __forceinline__ void storev(float* p, float v) { *p = v; }
__device__ __forceinline__ void storev(bf16* p, float v) { *p = __float2bfloat16(v); }

__device__ __forceinline__ float ldin(const void* p, size_t i, int f32w) {
    if (f32w) return ((const float*)p)[i];
    return __bfloat162float(((const bf16*)p)[i]);
}

// ---------------------------------------------------------------------------
// Dtype sniffer (proven rounds 2/6-27; resolves flag=0 = bf16 here).
// ---------------------------------------------------------------------------
__global__ void sniff_kernel(const void* x, int* flag) {
    if (threadIdx.x == 0 && blockIdx.x == 0) {
        const bf16* hb = (const bf16*)x;
        int plaus = 0;
        for (int i = 0; i < 256; ++i) {
            float v = __bfloat162float(hb[2 * i]);
            float a = fabsf(v);
            if (v == 0.f || (a > 1e-4f && a < 100.f)) ++plaus;
        }
        flag[0] = (plaus < 128) ? 1 : 0;
    }
}

// ---------------------------------------------------------------------------
// bf16 transpose: out[C][R] = in[R][C], 64x64 tiles. PROVEN rounds 7-27.
// ---------------------------------------------------------------------------
__global__ __launch_bounds__(256) void transpose_kernel(
    const void* __restrict__ in, bf16* __restrict__ out, int R, int C,
    const int* __restrict__ flag)
{
    const int f32w = flag[0];
    __shared__ short t[64][72];
    int tid = threadIdx.x;
    int c0 = blockIdx.x * 64, r0 = blockIdx.y * 64;
    int cc = tid & 63, rr = tid >> 6;
#pragma unroll
    for (int i = 0; i < 16; ++i) {
        bf16 v = __float2bfloat16(ldin(in, (size_t)(r0 + rr + i * 4) * C + c0 + cc, f32w));
        t[rr + i * 4][cc] = *(short*)&v;
    }
    __syncthreads();
#pragma unroll
    for (int i = 0; i < 16; ++i)
        ((short*)out)[(size_t)(c0 + rr + i * 4) * R + r0 + cc] = t[cc][rr + i * 4];
}

// ---------------------------------------------------------------------------
// Merged QKV weight transpose (PROVEN rounds 21-27): 3 dispatches -> 1.
// ---------------------------------------------------------------------------
__global__ __launch_bounds__(256) void transpose3_kernel(
    const void* __restrict__ in0, const void* __restrict__ in1, const void* __restrict__ in2,
    bf16* __restrict__ out0, bf16* __restrict__ out1, bf16* __restrict__ out2,
    const int* __restrict__ flag)
{
    const int f32w = flag[0];
    const void* in = (blockIdx.z == 0) ? in0 : (blockIdx.z == 1 ? in1 : in2);
    bf16* out = (blockIdx.z == 0) ? out0 : (blockIdx.z == 1 ? out1 : out2);
    const int R = CD, C = 512;
    __shared__ short t[64][72];
    int tid = threadIdx.x;
    int c0 = blockIdx.x * 64, r0 = blockIdx.y * 64;
    int cc = tid & 63, rr = tid >> 6;
#pragma unroll
    for (int i = 0; i < 16; ++i) {
        bf16 v = __float2bfloat16(ldin(in, (size_t)(r0 + rr + i * 4) * C + c0 + cc, f32w));
        t[rr + i * 4][cc] = *(short*)&v;
    }
    __syncthreads();
#pragma unroll
    for (int i = 0; i < 16; ++i)
        ((short*)out)[(size_t)(c0 + rr + i * 4) * R + r0 + cc] = t[cc][rr + i * 4];
}

// ---------------------------------------------------------------------------
// Per-head 64x64 transpose of Wq1/Wk1/Wv1 (PROVEN rounds 15-27).
// ---------------------------------------------------------------------------
__global__ __launch_bounds__(256) void transposeH_kernel(
    const void* __restrict__ Wq1, const void* __restrict__ Wk1, const void* __restrict__ Wv1,
    bf16* __restrict__ oq, bf16* __restrict__ ok, bf16* __restrict__ ov,
    const int* __restrict__ flag)
{
    const int f32w = flag[0];
    int which = blockIdx.x >> 3, hh = blockIdx.x & 7;
    const void* in = (which == 0) ? Wq1 : (which == 1) ? Wk1 : Wv1;
    bf16* out = (which == 0) ? oq : (which == 1) ? ok : ov;
    __shared__ short t[64][72];
    int tid = threadIdx.x;
    int cc = tid & 63, rr = tid >> 6;
    size_t base = (size_t)hh * 4096;
#pragma unroll
    for (int i = 0; i < 16; ++i) {
        bf16 v = __float2bfloat16(ldin(in, base + (size_t)(rr + i * 4) * 64 + cc, f32w));
        t[rr + i * 4][cc] = *(short*)&v;
    }
    __syncthreads();
#pragma unroll
    for (int i = 0; i < 16; ++i)
        ((short*)out)[base + (size_t)(rr + i * 4) * 64 + cc] = t[cc][rr + i * 4];
}

// ---------------------------------------------------------------------------
// MFMA GEMM, register-staged linear LDS, BK=64, DEPTH-2 PREFETCH (PROVEN).
// OUTM=0: row-major C (+ACCUM reads prior C via tof, works for bf16/f32).
// OUTM=2: state-only (small Wo; row -> fp32 state rows 0..127 via ST ptr).
// ---------------------------------------------------------------------------
template <typename TC, int ACT, int OUTM, int ACCUM>
__global__ __launch_bounds__(256) void mfma_lds(
    const bf16* __restrict__ A,
    const bf16* __restrict__ Bt0, const bf16* __restrict__ Bt1, const bf16* __restrict__ Bt2,
    TC* __restrict__ C0, TC* __restrict__ C1, TC* __restrict__ C2,
    float* __restrict__ ST,
    const void* __restrict__ bias, int boff,
    int M, int N, int K, int lda, int ldb, int seg,
    const int* __restrict__ flag)
{
    const int f32w = flag[0];
    const bf16* Bt = (blockIdx.z == 0) ? Bt0 : (blockIdx.z == 1 ? Bt1 : Bt2);
    TC* C = (blockIdx.z == 0) ? C0 : (blockIdx.z == 1 ? C1 : C2);

    __shared__ __align__(16) short As[128 * 64];
    __shared__ __align__(16) short Bs[128 * 64];

    const int tid = threadIdx.x;
    const int lane = tid & 63;
    const int w = tid >> 6;
    const int wm = w >> 1, wn = w & 1;
    const int bm = blockIdx.x * 128, bn = blockIdx.y * 128;

    f32x4 acc[4][4];
#pragma unroll
    for (int i = 0; i < 4; ++i)
#pragma unroll
        for (int j = 0; j < 4; ++j) acc[i][j] = (f32x4){0.f, 0.f, 0.f, 0.f};

    int srow[4], skc[4];
#pragma unroll
    for (int i = 0; i < 4; ++i) {
        int c = i * 256 + tid;
        srow[i] = c >> 3;
        skc[i] = (c & 7) * 8;
    }

    bf16x8 rA0[4], rB0[4], rA1[4], rB1[4];
#pragma unroll
    for (int i = 0; i < 4; ++i) {
        rA0[i] = *(const bf16x8*)(A + (size_t)(bm + srow[i]) * lda + skc[i]);
        rB0[i] = *(const bf16x8*)(Bt + (size_t)(bn + srow[i]) * ldb + skc[i]);
        rA1[i] = *(const bf16x8*)(A + (size_t)(bm + srow[i]) * lda + 64 + skc[i]);
        rB1[i] = *(const bf16x8*)(Bt + (size_t)(bn + srow[i]) * ldb + 64 + skc[i]);
    }

#define MFMA_PHASE                                                              \
    _Pragma("unroll")                                                           \
    for (int kh = 0; kh < 2; ++kh) {                                            \
        bf16x8 av[4], bv[4];                                                    \
        _Pragma("unroll")                                                       \
        for (int mi = 0; mi < 4; ++mi) {                                        \
            int r = wm * 64 + mi * 16 + (lane & 15);                            \
            int cl = kh * 4 + (lane >> 4);                                      \
            av[mi] = *(const bf16x8*)&As[r * 64 + cl * 8];                      \
        }                                                                       \
        _Pragma("unroll")                                                       \
        for (int nj = 0; nj < 4; ++nj) {                                        \
            int r = wn * 64 + nj * 16 + (lane & 15);                            \
            int cl = kh * 4 + (lane >> 4);                                      \
            bv[nj] = *(const bf16x8*)&Bs[r * 64 + cl * 8];                      \
        }                                                                       \
        _Pragma("unroll")                                                       \
        for (int mi = 0; mi < 4; ++mi)                                          \
            _Pragma("unroll")                                                   \
            for (int nj = 0; nj < 4; ++nj)                                      \
                acc[mi][nj] = __builtin_amdgcn_mfma_f32_16x16x32_bf16(          \
                    av[mi], bv[nj], acc[mi][nj], 0, 0, 0);                      \
    }

    for (int k0 = 0; k0 < K; k0 += 128) {
        __syncthreads();
#pragma unroll
        for (int i = 0; i < 4; ++i) {
            *(bf16x8*)&As[(size_t)(i * 256 + tid) * 8] = rA0[i];
            *(bf16x8*)&Bs[(size_t)(i * 256 + tid) * 8] = rB0[i];
        }
        if (k0 + 128 < K) {
            int kn = k0 + 128;
#pragma unroll
            for (int i = 0; i < 4; ++i) {
                rA0[i] = *(const bf16x8*)(A + (size_t)(bm + srow[i]) * lda + kn + skc[i]);
                rB0[i] = *(const bf16x8*)(Bt + (size_t)(bn + srow[i]) * ldb + kn + skc[i]);
            }
        }
        __syncthreads();
        MFMA_PHASE

        __syncthreads();
#pragma unroll
        for (int i = 0; i < 4; ++i) {
            *(bf16x8*)&As[(size_t)(i * 256 + tid) * 8] = rA1[i];
            *(bf16x8*)&Bs[(size_t)(i * 256 + tid) * 8] = rB1[i];
        }
        if (k0 + 192 < K) {
            int kn = k0 + 192;
#pragma unroll
            for (int i = 0; i < 4; ++i) {
                rA1[i] = *(const bf16x8*)(A + (size_t)(bm + srow[i]) * lda + kn + skc[i]);
                rB1[i] = *(const bf16x8*)(Bt + (size_t)(bn + srow[i]) * ldb + kn + skc[i]);
            }
        }
        __syncthreads();
        MFMA_PHASE
    }
#undef MFMA_PHASE

#pragma unroll
    for (int mi = 0; mi < 4; ++mi) {
#pragma unroll
        for (int nj = 0; nj < 4; ++nj) {
            int c = bn + wn * 64 + nj * 16 + (lane & 15);
            float bia = bias ? ldin(bias, boff + c, f32w) : 0.f;
#pragma unroll
            for (int r = 0; r < 4; ++r) {
                int row = bm + wm * 64 + mi * 16 + (lane >> 4) * 4 + r;
                float v = acc[mi][nj][r] + bia;
                if (ACT == 1) v = 0.5f * v * (1.0f + erff(v * 0.70710678118654752f));
                if (OUTM == 0) {
                    if (ACCUM) v += tof(C[(size_t)row * N + c]);
                    storev(C + (size_t)row * N + c, v);
                } else {  // OUTM == 2: small Wo -> fp32 state rows (row = b*64+t)
                    ST[(size_t)row * CD + c] = v;
                }
            }
        }
    }
}

// ---------------------------------------------------------------------------
// RoPE (in-place, bf16) on q and k + LDS-tiled transpose of v -> vt.
// PROVEN rounds 12-27.
// ---------------------------------------------------------------------------
__global__ __launch_bounds__(256) void ropeV_kernel(
    bf16* __restrict__ q, bf16* __restrict__ k,
    const bf16* __restrict__ v, bf16* __restrict__ vt)
{
    int t0 = blockIdx.x * 64, hh = blockIdx.y, b = blockIdx.z;
    int tid = threadIdx.x;
    __shared__ short lt[64][72];
    int c = tid & 63;
    int r0 = tid >> 6;
    int ip = c >> 1;
    float inv = powf(10000.f, -(float)(2 * ip) / 64.f);
#pragma unroll
    for (int i = 0; i < 16; ++i) {
        int r = r0 + i * 4;
        int t = t0 + r;
        size_t idx = ((size_t)b * CT + t) * 512 + hh * 64 + c;
        float qv = tof(q[idx]);
        float kv = tof(k[idx]);
        float ang = (float)t * inv;
        float sn, cs;
        sincosf(ang, &sn, &cs);
        float qp = __shfl_xor(qv, 1);
        float kp = __shfl_xor(kv, 1);
        float rq, rk;
        if (c & 1) { rq = qp * sn + qv * cs; rk = kp * sn + kv * cs; }
        else       { rq = qv * cs - qp * sn; rk = kv * cs - kp * sn; }
        q[idx] = __float2bfloat16(rq);
        k[idx] = __float2bfloat16(rk);
        lt[r][c] = ((const short*)v)[idx];
    }
    __syncthreads();
#pragma unroll
    for (int i = 0; i < 16; ++i) {
        int c2 = r0 + i * 4;
        int r2 = c;
        ((short*)vt)[((size_t)(b * CH + hh) * 64 + c2) * CT + t0 + r2] = lt[r2][c2];
    }
}

// ---------------------------------------------------------------------------
// MFMA flash attention (core PROVEN rounds 12-27).
// FUSE=1: grid x=10; epilogue proj1+RoPE -> q1/k1/v1t.
// FUSE=0: grid x=9; tiles 1..8 -> o1mid (batch-major), tile-9 -> o1s.
// ---------------------------------------------------------------------------
template <int FUSE>
__global__ __launch_bounds__(256) void attn_mfma(
    const bf16* __restrict__ q, const bf16* __restrict__ k, const bf16* __restrict__ vt,
    bf16* __restrict__ o,
    int qsb, int qsh, int qst,
    int ksb, int ksh, int kst,
    int seg,
    const bf16* __restrict__ Wq1t, const bf16* __restrict__ Wk1t, const bf16* __restrict__ Wv1t,
    bf16* __restrict__ q1o, bf16* __restrict__ k1o, bf16* __restrict__ v1to)
{
    const int tid = threadIdx.x;
    const int lane = tid & 63;
    const int wrow = tid >> 6;
    const int hh = blockIdx.y, b = blockIdx.z;
    const int qbase = (FUSE ? ((int)gridDim.x - 1 - (int)blockIdx.x)
                            : ((int)gridDim.x - (int)blockIdx.x)) * 64;

    __shared__ __align__(16) short Qs[64 * LP];
    __shared__ __align__(16) short Ks[64 * LP];
    __shared__ __align__(16) short Vs[64 * LP];
    __shared__ __align__(16) short Ps[64 * LP];

    const size_t qb0 = (size_t)b * qsb + (size_t)hh * qsh;
    const size_t kb0 = (size_t)b * ksb + (size_t)hh * ksh;
    const size_t vtb = (size_t)(b * CH + hh) * 64 * CT;

    int srow[2], skc[2], soff[2];
#pragma unroll
    for (int i = 0; i < 2; ++i) {
        int c = i * 256 + tid;
        srow[i] = c >> 3;
        skc[i] = c & 7;
        soff[i] = srow[i] * LP + skc[i] * 8;
    }

    bf16x8 rQ[2], rK[2], rV[2];
#pragma unroll
    for (int i = 0; i < 2; ++i) {
        rQ[i] = *(const bf16x8*)(q + qb0 + (size_t)(qbase + srow[i]) * qst + skc[i] * 8);
        rK[i] = *(const bf16x8*)(k + kb0 + (size_t)srow[i] * kst + skc[i] * 8);
        rV[i] = *(const bf16x8*)(vt + vtb + (size_t)srow[i] * CT + skc[i] * 8);
    }

    float mrow[4], lrow[4];
    f32x4 oacc[4];
#pragma unroll
    for (int r = 0; r < 4; ++r) { mrow[r] = -1e30f; lrow[r] = 0.f; }
#pragma unroll
    for (int nd = 0; nd < 4; ++nd) oacc[nd] = (f32x4){0.f, 0.f, 0.f, 0.f};

    const int ntiles = qbase / 64 + 1;
    for (int ti = 0; ti < ntiles; ++ti) {
        __syncthreads();
        if (ti == 0) {
#pragma unroll
            for (int i = 0; i < 2; ++i) *(bf16x8*)&Qs[soff[i]] = rQ[i];
        }
#pragma unroll
        for (int i = 0; i < 2; ++i) {
            *(bf16x8*)&Ks[soff[i]] = rK[i];
            *(bf16x8*)&Vs[soff[i]] = rV[i];
        }
        if (ti + 1 < ntiles) {
            int j1 = (ti + 1) * 64;
#pragma unroll
            for (int i = 0; i < 2; ++i) {
                rK[i] = *(const bf16x8*)(k + kb0 + (size_t)(j1 + srow[i]) * kst + skc[i] * 8);
                rV[i] = *(const bf16x8*)(vt + vtb + (size_t)srow[i] * CT + j1 + skc[i] * 8);
            }
        }
        __syncthreads();

        f32x4 sacc[4];
#pragma unroll
        for (int nj = 0; nj < 4; ++nj) sacc[nj] = (f32x4){0.f, 0.f, 0.f, 0.f};
#pragma unroll
        for (int kh = 0; kh < 2; ++kh) {
            int cl = kh * 4 + (lane >> 4);
            bf16x8 av = *(const bf16x8*)&Qs[(wrow * 16 + (lane & 15)) * LP + cl * 8];
#pragma unroll
            for (int nj = 0; nj < 4; ++nj) {
                bf16x8 bv = *(const bf16x8*)&Ks[(nj * 16 + (lane & 15)) * LP + cl * 8];
                sacc[nj] = __builtin_amdgcn_mfma_f32_16x16x32_bf16(av, bv, sacc[nj], 0, 0, 0);
            }
        }

        const bool diag = (ti == ntiles - 1);
        float pm[4] = {-1e30f, -1e30f, -1e30f, -1e30f};
#pragma unroll
        for (int nj = 0; nj < 4; ++nj) {
            int col_l = nj * 16 + (lane & 15);
#pragma unroll
            for (int r = 0; r < 4; ++r) {
                int row_l = wrow * 16 + ((lane >> 4) << 2) + r;
                float s = (diag && col_l > row_l) ? -1e30f : sacc[nj][r] * 0.125f;
                sacc[nj][r] = s;
                pm[r] = fmaxf(pm[r], s);
            }
        }
#pragma unroll
        for (int msk = 1; msk < 16; msk <<= 1)
#pragma unroll
            for (int r = 0; r < 4; ++r) pm[r] = fmaxf(pm[r], __shfl_xor(pm[r], msk));

        float corr[4], rs[4] = {0.f, 0.f, 0.f, 0.f};
#pragma unroll
        for (int r = 0; r < 4; ++r) {
            float mn = fmaxf(mrow[r], pm[r]);
            corr[r] = __expf(mrow[r] - mn);
            mrow[r] = mn;
        }
#pragma unroll
        for (int nj = 0; nj < 4; ++nj)
#pragma unroll
            for (int r = 0; r < 4; ++r) {
                float p = __expf(sacc[nj][r] - mrow[r]);
                sacc[nj][r] = p;
                rs[r] += p;
            }
#pragma unroll
        for (int msk = 1; msk < 16; msk <<= 1)
#pragma unroll
            for (int r = 0; r < 4; ++r) rs[r] += __shfl_xor(rs[r], msk);
#pragma unroll
        for (int r = 0; r < 4; ++r) lrow[r] = lrow[r] * corr[r] + rs[r];
#pragma unroll
        for (int nd = 0; nd < 4; ++nd)
#pragma unroll
            for (int r = 0; r < 4; ++r) oacc[nd][r] *= corr[r];

#pragma unroll
        for (int nj = 0; nj < 4; ++nj)
#pragma unroll
            for (int r = 0; r < 4; ++r) {
                bf16 pb = __float2bfloat16(sacc[nj][r]);
                Ps[(wrow * 16 + ((lane >> 4) << 2) + r) * LP + nj * 16 + (lane & 15)] =
                    *(short*)&pb;
            }

#pragma unroll
        for (int kh = 0; kh < 2; ++kh) {
            int cl = kh * 4 + (lane >> 4);
            bf16x8 pa = *(const bf16x8*)&Ps[(wrow * 16 + (lane & 15)) * LP + cl * 8];
#pragma unroll
            for (int nd = 0; nd < 4; ++nd) {
                bf16x8 bv = *(const bf16x8*)&Vs[(nd * 16 + (lane & 15)) * LP + cl * 8];
                oacc[nd] = __builtin_amdgcn_mfma_f32_16x16x32_bf16(pa, bv, oacc[nd], 0, 0, 0);
            }
        }
    }

    if (FUSE == 0) {
        // per-block-uniform destination select (tile granularity == 64)
        bf16* dst;
        int rbase;
        if (qbase == 576) { dst = q1o; rbase = b * 64 - 576; }          // o1s
        else              { dst = o;   rbase = (b * 8 + seg) * 512 - 64; }  // o1mid
#pragma unroll
        for (int nd = 0; nd < 4; ++nd) {
#pragma unroll
            for (int r = 0; r < 4; ++r) {
                int row_g = qbase + wrow * 16 + ((lane >> 4) << 2) + r;
                int col = nd * 16 + (lane & 15);
                dst[(size_t)(rbase + row_g) * 512 + hh * 64 + col] =
                    __float2bfloat16(oacc[nd][r] / lrow[r]);
            }
        }
    } else {
#pragma unroll
        for (int nd = 0; nd < 4; ++nd)
#pragma unroll
            for (int r = 0; r < 4; ++r) {
                int row_l = wrow * 16 + ((lane >> 4) << 2) + r;
                bf16 ob16 = __float2bfloat16(oacc[nd][r] / lrow[r]);
                Qs[row_l * LP + nd * 16 + (lane & 15)] = *(short*)&ob16;
            }
        __syncthreads();

        const size_t whb = (size_t)hh * 4096;
        f32x4 qa[4], ka[4], va[4];
#pragma unroll
        for (int nj = 0; nj < 4; ++nj) {
            qa[nj] = (f32x4){0.f, 0.f, 0.f, 0.f};
            ka[nj] = (f32x4){0.f, 0.f, 0.f, 0.f};
            va[nj] = (f32x4){0.f, 0.f, 0.f, 0.f};
        }
#pragma unroll
        for (int kh = 0; kh < 2; ++kh) {
            int cl = kh * 4 + (lane >> 4);
            bf16x8 av = *(const bf16x8*)&Qs[(wrow * 16 + (lane & 15)) * LP + cl * 8];
#pragma unroll
            for (int nj = 0; nj < 4; ++nj) {
                int rowb = nj * 16 + (lane & 15);
                bf16x8 bq = *(const bf16x8*)(Wq1t + whb + (size_t)rowb * 64 + cl * 8);
                bf16x8 bk = *(const bf16x8*)(Wk1t + whb + (size_t)rowb * 64 + cl * 8);
                bf16x8 bw = *(const bf16x8*)(Wv1t + whb + (size_t)rowb * 64 + cl * 8);
                qa[nj] = __builtin_amdgcn_mfma_f32_16x16x32_bf16(av, bq, qa[nj], 0, 0, 0);
                ka[nj] = __builtin_amdgcn_mfma_f32_16x16x32_bf16(av, bk, ka[nj], 0, 0, 0);
                va[nj] = __builtin_amdgcn_mfma_f32_16x16x32_bf16(av, bw, va[nj], 0, 0, 0);
            }
        }
        const size_t bh = (size_t)(b * CH + hh);
#pragma unroll
        for (int nj = 0; nj < 4; ++nj) {
            int col = nj * 16 + (lane & 15);
            int ip = col >> 1;
            float inv = powf(10000.f, -(float)(2 * ip) / 64.f);
#pragma unroll
            for (int r = 0; r < 4; ++r) {
                int row_l = wrow * 16 + ((lane >> 4) << 2) + r;
                int t = qbase + row_l;
                float ang = (float)t * inv;
                float sn, cs;
                sincosf(ang, &sn, &cs);
                float aq = qa[nj][r], ak = ka[nj][r];
                float pq = __shfl_xor(aq, 1);
                float pk = __shfl_xor(ak, 1);
                float rq, rk;
                if (col & 1) { rq = pq * sn + aq * cs; rk = pk * sn + ak * cs; }
                else         { rq = aq * cs - pq * sn; rk = ak * cs - pk * sn; }
                size_t roff = (bh * CT + t) * 64 + col;
                q1o[roff] = __float2bfloat16(rq);
                k1o[roff] = __float2bfloat16(rk);
                v1to[(bh * 64 + col) * CT + t] = __float2bfloat16(va[nj][r]);
            }
        }
    }
}

// toks = concat([state, x_seg, state]) -> bf16 (PROVEN; separate pass wins)
__global__ __launch_bounds__(256) void build_toks_kernel(
    const void* __restrict__ x, const float* __restrict__ state, bf16* __restrict__ toks,
    int seg, const int* __restrict__ flag)
{
    const int f32w = flag[0];
    int idx = blockIdx.x * 256 + threadIdx.x;  // B*T*D
    int d = idx & (CD - 1);
    int t = (idx >> 10) % CT;
    int b = idx / (CT * CD);
    float v;
    if (t < CST) v = state[(b * CST + t) * CD + d];
    else if (t < CST + CL) v = ldin(x, ((size_t)b * CS + seg * CL + (t - CST)) * CD + d, f32w);
    else v = state[(b * CST + (t - CST - CL)) * CD + d];
    toks[idx] = __float2bfloat16(v);
}

__global__ __launch_bounds__(256) void init_state_kernel(
    const void* __restrict__ s0, float* __restrict__ state, const int* __restrict__ flag)
{
    const int f32w = flag[0];
    int idx = blockIdx.x * 256 + threadIdx.x;  // B*ST*D
    state[idx] = ldin(s0, idx % (CST * CD), f32w);
}

// LayerNorm(ra + x) * g + b.  ra bf16 (PROVEN round 27).
__global__ __launch_bounds__(256) void ln_kernel(
    const bf16* __restrict__ ra, const void* __restrict__ x,
    const void* __restrict__ g, const void* __restrict__ bb,
    void* __restrict__ outp, int out_ext, const int* __restrict__ flag)
{
    const int f32w = flag[0];
    int row = blockIdx.x;
    int tid = threadIdx.x;
    __shared__ float buf[CD];
    __shared__ float red[4];

    float s = 0.f;
    for (int c = tid; c < CD; c += 256) {
        float v = tof(ra[(size_t)row * CD + c]) + ldin(x, (size_t)row * CD + c, f32w);
        buf[c] = v;
        s += v;
    }
#pragma unroll
    for (int off = 32; off; off >>= 1) s += __shfl_xor(s, off);
    if ((tid & 63) == 0) red[tid >> 6] = s;
    __syncthreads();
    float mu = (red[0] + red[1] + red[2] + red[3]) * (1.f / CD);
    __syncthreads();

    float vs = 0.f;
    for (int c = tid; c < CD; c += 256) {
        float d0 = buf[c] - mu;
        vs += d0 * d0;
    }
#pragma unroll
    for (int off = 32; off; off >>= 1) vs += __shfl_xor(vs, off);
    if ((tid & 63) == 0) red[tid >> 6] = vs;
    __syncthreads();
    float var = (red[0] + red[1] + red[2] + red[3]) * (1.f / CD);
    float rs = rsqrtf(var + 1e-5f);

    for (int c = tid; c < CD; c += 256) {
        float y = (buf[c] - mu) * rs * ldin(g, c, f32w) + ldin(bb, c, f32w);
        size_t idx = (size_t)row * CD + c;
        if (!out_ext) {
            ((bf16*)outp)[idx] = __float2bfloat16(y);
        } else if (f32w) {
            ((float*)outp)[idx] = y;
        } else {
            ((bf16*)outp)[idx] = __float2bfloat16(y);
        }
    }
}

extern "C" void kernel_launch(void* const* d_in, const int* in_sizes, int n_in,
                              void* d_out, int out_size, void* d_ws, size_t ws_size,
                              hipStream_t stream)
{
    const void* x      = d_in[0];
    const void* s0     = d_in[1];
    const void* Wq0    = d_in[2];
    const void* Wk0    = d_in[3];
    const void* Wv0    = d_in[4];
    const void* Wq1    = d_in[5];
    const void* Wk1    = d_in[6];
    const void* Wv1    = d_in[7];
    const void* Wo     = d_in[8];
    const void* bo     = d_in[9];
    const void* g_attn = d_in[10];
    const void* b_attn = d_in[11];
    const void* W1     = d_in[12];
    const void* b1     = d_in[13];
    const void* W2     = d_in[14];
    const void* b2     = d_in[15];
    const void* g_mlp  = d_in[16];
    const void* b_mlp  = d_in[17];

    // workspace slot layout BYTE-IDENTICAL to passing rounds 2/6-27 (~90.7 MB)
    int* flag = (int*)d_ws;
    float* f = (float*)((char*)d_ws + 16);
    float* toks_slot = f; f += (size_t)CB * CT * CD;       // bf16 toks
    float* q0_slot = f;  f += (size_t)CB * CH * CT * 64;   // bf16 q0 [1280][512]
    float* k0_slot = f;  f += (size_t)CB * CH * CT * 64;   // bf16 k0
    float* v0_slot = f;  f += (size_t)CB * CH * CT * 64;   // bf16 v0
    float* o0_slot = f;  f += (size_t)CB * CH * CT * 64;   // bf16 v0t
    float* q1_slot = f;  f += (size_t)CB * CH * CT * 64;   // bf16 q1
    float* k1_slot = f;  f += (size_t)CB * CH * CT * 64;   // bf16 k1
    float* v1_slot = f;  f += (size_t)CB * CH * CT * 64;   // bf16 v1t
    float* o1t_slot = f; f += (size_t)CB * CT * (CH * 64); // (unused during segments)
    float* seg_slot = f; f += (size_t)CB * CT * CD;        // (unused during segments)
    float* state = f;   f += (size_t)CB * CST * CD;        // fp32 state
    float* a_slot = f;  f += (size_t)CB * CS * CD;         // bf16 a (half used)
    bf16* h = (bf16*)f;                                    // LN1 out [B*S, D] bf16
    bf16* tail = h + (size_t)CB * CS * CD;                 // 8.39 MB tail slot

    bf16* toks = (bf16*)toks_slot;
    bf16* q0b = (bf16*)q0_slot;
    bf16* k0b = (bf16*)k0_slot;
    bf16* v0b = (bf16*)v0_slot;
    bf16* v0t = (bf16*)o0_slot;
    bf16* q1b = (bf16*)q1_slot;
    bf16* k1b = (bf16*)k1_slot;
    bf16* v1t = (bf16*)v1_slot;
    bf16* ab  = (bf16*)a_slot;                             // [8192][1024] bf16
    bf16* WtQ = h;                                         // h region dead until LN1
    bf16* WtK = WtQ + (size_t)512 * 1024;
    bf16* WtV = WtK + (size_t)512 * 1024;
    bf16* WtO = WtV + (size_t)512 * 1024;                  // [1024][512]
    bf16* WtQ1 = WtO + (size_t)1024 * 512;                 // per-head [8][64][64]
    bf16* WtK1 = WtQ1 + (size_t)8 * 4096;
    bf16* WtV1 = WtK1 + (size_t)8 * 4096;
    // o1mid/o1s after transposed weights in h region (round-26/27-proven fit).
    bf16* o1mid = WtV1 + (size_t)8 * 4096;                 // [B*NSEG*512][512]
    bf16* o1s = o1mid + (size_t)CB * NSEG * 512 * 512;     // [128][512]
    // MLP phase (toks..q1 region dead): g1 at region base, Wt1 after, Wt2 tail.
    bf16* g1  = (bf16*)toks_slot;                          // [8192][1024] 16.78 MB
    bf16* Wt1 = g1 + (size_t)CB * CS * CD;                 // [CDH][CD]    8.39 MB
    bf16* Wt2 = tail;                                      // [CD][CDH]    8.39 MB

    sniff_kernel<<<1, 64, 0, stream>>>(x, flag);
    init_state_kernel<<<(CB * CST * CD) / 256, 256, 0, stream>>>(s0, state, flag);

    transpose3_kernel<<<dim3(8, 16, 3), 256, 0, stream>>>(
        Wq0, Wk0, Wv0, WtQ, WtK, WtV, flag);
    transpose_kernel<<<dim3(16, 8), 256, 0, stream>>>(Wo, WtO, 512, CD, flag);
    transposeH_kernel<<<24, 256, 0, stream>>>(Wq1, Wk1, Wv1, WtQ1, WtK1, WtV1, flag);
    // W2 transpose HOISTED to startup (this round's change): tail slot is
    // untouched until the MLP, so this overlaps the segment loop instead of
    // sitting on the LN1->MLP critical path. W1 stays post-LN1 (its dest
    // overlaps the toks region, live during segments).
    transpose_kernel<<<dim3(CD / 64, CDH / 64), 256, 0, stream>>>(W2, Wt2, CDH, CD, flag);

    for (int seg = 0; seg < NSEG; ++seg) {
        build_toks_kernel<<<(CB * CT * CD) / 256, 256, 0, stream>>>(x, state, toks, seg, flag);
        // QKV GEMM (proven path), row-major bf16 outputs
        mfma_lds<bf16, 0, 0, 0><<<dim3(10, 4, 3), 256, 0, stream>>>(
            toks, WtQ, WtK, WtV, q0b, k0b, v0b, nullptr, nullptr, 0,
            CB * CT, 512, CD, CD, CD, 0, flag);
        // RoPE q0,k0 in place + V transpose -> v0t (proven separate pass)
        ropeV_kernel<<<dim3(CT / 64, CH, CB), 256, 0, stream>>>(q0b, k0b, v0b, v0t);
        // attn1 (row-major Q/K + v0t) with FUSED proj1+RoPE epilogue (grid 10)
        attn_mfma<1><<<dim3(CT / 64, CH, CB), 256, 0, stream>>>(
            q0b, k0b, v0t, nullptr,
            CT * 512, 64, 512,
            CT * 512, 64, 512,
            seg,
            WtQ1, WtK1, WtV1, q1b, k1b, v1t);
        // attn2 (head-major Q/K + v1t), grid 9: middle -> o1mid, tile9 -> o1s
        attn_mfma<0><<<dim3(9, CH, CB), 256, 0, stream>>>(
            q1b, k1b, v1t, o1mid,
            CH * CT * 64, CT * 64, 64,
            CH * CT * 64, CT * 64, 64,
            seg,
            nullptr, nullptr, nullptr, o1s, nullptr, nullptr);
        // small Wo: state rows only (M=128, 8 blocks) -> fp32 state
        mfma_lds<bf16, 0, 2, 0><<<dim3(1, 8, 1), 256, 0, stream>>>(
            o1s, WtO, WtO, WtO, ab, ab, ab, state, bo, 0,
            128, CD, 512, 512, 512, seg, flag);
    }

    // big Wo: all middle rows (M=8192, grid 64x8=512 blocks) -> ab (bf16) + bo
    mfma_lds<bf16, 0, 0, 0><<<dim3(64, 8, 1), 256, 0, stream>>>(
        o1mid, WtO, WtO, WtO, ab, ab, ab, nullptr, bo, 0,
        CB * CS, CD, 512, 512, 512, 0, flag);

    // h = LN(ab + x) -> bf16 internal (overwrites WtQ..o1s — dead by now)
    ln_kernel<<<CB * CS, 256, 0, stream>>>(ab, x, g_attn, b_attn, h, 0, flag);

    transpose_kernel<<<dim3(CDH / 64, CD / 64), 256, 0, stream>>>(W1, Wt1, CD, CDH, flag);

    // MLP chunked over the hidden dim (PROVEN rounds 24-27); ab is bf16
    for (int c = 0; c < 4; ++c) {
        mfma_lds<bf16, 1, 0, 0><<<dim3(64, 8, 1), 256, 0, stream>>>(
            h, Wt1 + (size_t)c * 1024 * CD, Wt1, Wt1, g1, g1, g1, nullptr,
            b1, c * 1024, CB * CS, 1024, CD, CD, CD, 0, flag);
        if (c == 0)
            mfma_lds<bf16, 0, 0, 0><<<dim3(64, 8, 1), 256, 0, stream>>>(
                g1, Wt2 + (size_t)c * 1024, Wt2, Wt2, ab, ab, ab, nullptr,
                b2, 0, CB * CS, CD, 1024, 1024, CDH, 0, flag);
        else
            mfma_lds<bf16, 0, 0, 1><<<dim3(64, 8, 1), 256, 0, stream>>>(
                g1, Wt2 + (size_t)c * 1024, Wt2, Wt2, ab, ab, ab, nullptr,
                nullptr, 0, CB * CS, CD, 1024, 1024, CDH, 0, flag);
    }
    ln_kernel<<<CB * CS, 256, 0, stream>>>(ab, x, g_mlp, b_mlp, d_out, 1, flag);
}

// Round 29
// 1083.940 us; speedup vs baseline: 1.4530x; 1.0606x over previous
//
#include <hip/hip_runtime.h>
#include <hip/hip_bf16.h>

typedef __hip_bfloat16 bf16;
typedef short bf16x8 __attribute__((ext_vector_type(8)));   // 8 bf16 = 4 VGPRs
typedef float f32x4 __attribute__((ext_vector_type(4)));

// Problem constants
#define CB 2
#define CS 4096
#define CD 1024
#define CL 512
#define CST 64
#define CH 8
#define CT 640      // 2*ST + L
#define CDH 4096
#define NSEG 8
#define LP 80       // padded LDS row length (bf16) for attn tiles
#define GP 72       // padded LDS row length (shorts) for GEMM tiles (this round:
                    // breaks the 128B-row-stride 16-way bank conflict, G4)

__device__ __forceinline__ float tof(float x) { return x; }
__device__ __forceinline__ float tof(bf16 x) { return __bfloat162float(x); }
__device__ __forceinline__ void storev(float* p, float v) { *p = v; }
__device__ __forceinline__ void storev(bf16* p, float v) { *p = __float2bfloat16(v); }

__device__ __forceinline__ float ldin(const void* p, size_t i, int f32w) {
    if (f32w) return ((const float*)p)[i];
    return __bfloat162float(((const bf16*)p)[i]);
}

// ---------------------------------------------------------------------------
// Dtype sniffer (proven rounds 2/6-28; resolves flag=0 = bf16 here).
// ---------------------------------------------------------------------------
__global__ void sniff_kernel(const void* x, int* flag) {
    if (threadIdx.x == 0 && blockIdx.x == 0) {
        const bf16* hb = (const bf16*)x;
        int plaus = 0;
        for (int i = 0; i < 256; ++i) {
            float v = __bfloat162float(hb[2 * i]);
            float a = fabsf(v);
            if (v == 0.f || (a > 1e-4f && a < 100.f)) ++plaus;
        }
        flag[0] = (plaus < 128) ? 1 : 0;
    }
}

// ---------------------------------------------------------------------------
// bf16 transpose: out[C][R] = in[R][C], 64x64 tiles. PROVEN rounds 7-28.
// ---------------------------------------------------------------------------
__global__ __launch_bounds__(256) void transpose_kernel(
    const void* __restrict__ in, bf16* __restrict__ out, int R, int C,
    const int* __restrict__ flag)
{
    const int f32w = flag[0];
    __shared__ short t[64][72];
    int tid = threadIdx.x;
    int c0 = blockIdx.x * 64, r0 = blockIdx.y * 64;
    int cc = tid & 63, rr = tid >> 6;
#pragma unroll
    for (int i = 0; i < 16; ++i) {
        bf16 v = __float2bfloat16(ldin(in, (size_t)(r0 + rr + i * 4) * C + c0 + cc, f32w));
        t[rr + i * 4][cc] = *(short*)&v;
    }
    __syncthreads();
#pragma unroll
    for (int i = 0; i < 16; ++i)
        ((short*)out)[(size_t)(c0 + rr + i * 4) * R + r0 + cc] = t[cc][rr + i * 4];
}

// ---------------------------------------------------------------------------
// Merged QKV weight transpose (PROVEN rounds 21-28): 3 dispatches -> 1.
// ---------------------------------------------------------------------------
__global__ __launch_bounds__(256) void transpose3_kernel(
    const void* __restrict__ in0, const void* __restrict__ in1, const void* __restrict__ in2,
    bf16* __restrict__ out0, bf16* __restrict__ out1, bf16* __restrict__ out2,
    const int* __restrict__ flag)
{
    const int f32w = flag[0];
    const void* in = (blockIdx.z == 0) ? in0 : (blockIdx.z == 1 ? in1 : in2);
    bf16* out = (blockIdx.z == 0) ? out0 : (blockIdx.z == 1 ? out1 : out2);
    const int R = CD, C = 512;
    __shared__ short t[64][72];
    int tid = threadIdx.x;
    int c0 = blockIdx.x * 64, r0 = blockIdx.y * 64;
    int cc = tid & 63, rr = tid >> 6;
#pragma unroll
    for (int i = 0; i < 16; ++i) {
        bf16 v = __float2bfloat16(ldin(in, (size_t)(r0 + rr + i * 4) * C + c0 + cc, f32w));
        t[rr + i * 4][cc] = *(short*)&v;
    }
    __syncthreads();
#pragma unroll
    for (int i = 0; i < 16; ++i)
        ((short*)out)[(size_t)(c0 + rr + i * 4) * R + r0 + cc] = t[cc][rr + i * 4];
}

// ---------------------------------------------------------------------------
// Per-head 64x64 transpose of Wq1/Wk1/Wv1 (PROVEN rounds 15-28).
// ---------------------------------------------------------------------------
__global__ __launch_bounds__(256) void transposeH_kernel(
    const void* __restrict__ Wq1, const void* __restrict__ Wk1, const void* __restrict__ Wv1,
    bf16* __restrict__ oq, bf16* __restrict__ ok, bf16* __restrict__ ov,
    const int* __restrict__ flag)
{
    const int f32w = flag[0];
    int which = blockIdx.x >> 3, hh = blockIdx.x & 7;
    const void* in = (which == 0) ? Wq1 : (which == 1) ? Wk1 : Wv1;
    bf16* out = (which == 0) ? oq : (which == 1) ? ok : ov;
    __shared__ short t[64][72];
    int tid = threadIdx.x;
    int cc = tid & 63, rr = tid >> 6;
    size_t base = (size_t)hh * 4096;
#pragma unroll
    for (int i = 0; i < 16; ++i) {
        bf16 v = __float2bfloat16(ldin(in, base + (size_t)(rr + i * 4) * 64 + cc, f32w));
        t[rr + i * 4][cc] = *(short*)&v;
    }
    __syncthreads();
#pragma unroll
    for (int i = 0; i < 16; ++i)
        ((short*)out)[base + (size_t)(rr + i * 4) * 64 + cc] = t[cc][rr + i * 4];
}

// ---------------------------------------------------------------------------
// MFMA GEMM, register-staged LDS, BK=64, DEPTH-2 PREFETCH (PROVEN rounds
// 19-28) with THIS ROUND's change: LDS rows padded 64 -> GP=72 shorts
// (144B row stride). Old layout had 128B row stride -> all 16 lanes of an
// MFMA fragment read group hit one 4-bank slot (16-way conflict, 6.29M
// SQ_LDS_BANK_CONFLICT/dispatch). 144B stride spreads rows across bank
// quads (4r+8cl mod 32) -> minimum 8 accesses/bank. Same values, same
// sync structure, bit-identical math.
// OUTM=0: row-major C (+ACCUM). OUTM=2: state-only (small Wo).
// ---------------------------------------------------------------------------
template <typename TC, int ACT, int OUTM, int ACCUM>
__global__ __launch_bounds__(256) void mfma_lds(
    const bf16* __restrict__ A,
    const bf16* __restrict__ Bt0, const bf16* __restrict__ Bt1, const bf16* __restrict__ Bt2,
    TC* __restrict__ C0, TC* __restrict__ C1, TC* __restrict__ C2,
    float* __restrict__ ST,
    const void* __restrict__ bias, int boff,
    int M, int N, int K, int lda, int ldb, int seg,
    const int* __restrict__ flag)
{
    const int f32w = flag[0];
    const bf16* Bt = (blockIdx.z == 0) ? Bt0 : (blockIdx.z == 1 ? Bt1 : Bt2);
    TC* C = (blockIdx.z == 0) ? C0 : (blockIdx.z == 1 ? C1 : C2);

    __shared__ __align__(16) short As[128 * GP];
    __shared__ __align__(16) short Bs[128 * GP];

    const int tid = threadIdx.x;
    const int lane = tid & 63;
    const int w = tid >> 6;
    const int wm = w >> 1, wn = w & 1;
    const int bm = blockIdx.x * 128, bn = blockIdx.y * 128;

    f32x4 acc[4][4];
#pragma unroll
    for (int i = 0; i < 4; ++i)
#pragma unroll
        for (int j = 0; j < 4; ++j) acc[i][j] = (f32x4){0.f, 0.f, 0.f, 0.f};

    int srow[4], skc[4], soff[4];
#pragma unroll
    for (int i = 0; i < 4; ++i) {
        int c = i * 256 + tid;
        srow[i] = c >> 3;
        skc[i] = (c & 7) * 8;
        soff[i] = srow[i] * GP + skc[i];   // padded LDS store offset (shorts)
    }

    bf16x8 rA0[4], rB0[4], rA1[4], rB1[4];
#pragma unroll
    for (int i = 0; i < 4; ++i) {
        rA0[i] = *(const bf16x8*)(A + (size_t)(bm + srow[i]) * lda + skc[i]);
        rB0[i] = *(const bf16x8*)(Bt + (size_t)(bn + srow[i]) * ldb + skc[i]);
        rA1[i] = *(const bf16x8*)(A + (size_t)(bm + srow[i]) * lda + 64 + skc[i]);
        rB1[i] = *(const bf16x8*)(Bt + (size_t)(bn + srow[i]) * ldb + 64 + skc[i]);
    }

#define MFMA_PHASE                                                              \
    _Pragma("unroll")                                                           \
    for (int kh = 0; kh < 2; ++kh) {                                            \
        bf16x8 av[4], bv[4];                                                    \
        _Pragma("unroll")                                                       \
        for (int mi = 0; mi < 4; ++mi) {                                        \
            int r = wm * 64 + mi * 16 + (lane & 15);                            \
            int cl = kh * 4 + (lane >> 4);                                      \
            av[mi] = *(const bf16x8*)&As[r * GP + cl * 8];                      \
        }                                                                       \
        _Pragma("unroll")                                                       \
        for (int nj = 0; nj < 4; ++nj) {                                        \
            int r = wn * 64 + nj * 16 + (lane & 15);                            \
            int cl = kh * 4 + (lane >> 4);                                      \
            bv[nj] = *(const bf16x8*)&Bs[r * GP + cl * 8];                      \
        }                                                                       \
        _Pragma("unroll")                                                       \
        for (int mi = 0; mi < 4; ++mi)                                          \
            _Pragma("unroll")                                                   \
            for (int nj = 0; nj < 4; ++nj)                                      \
                acc[mi][nj] = __builtin_amdgcn_mfma_f32_16x16x32_bf16(          \
                    av[mi], bv[nj], acc[mi][nj], 0, 0, 0);                      \
    }

    for (int k0 = 0; k0 < K; k0 += 128) {
        __syncthreads();
#pragma unroll
        for (int i = 0; i < 4; ++i) {
            *(bf16x8*)&As[soff[i]] = rA0[i];
            *(bf16x8*)&Bs[soff[i]] = rB0[i];
        }
        if (k0 + 128 < K) {
            int kn = k0 + 128;
#pragma unroll
            for (int i = 0; i < 4; ++i) {
                rA0[i] = *(const bf16x8*)(A + (size_t)(bm + srow[i]) * lda + kn + skc[i]);
                rB0[i] = *(const bf16x8*)(Bt + (size_t)(bn + srow[i]) * ldb + kn + skc[i]);
            }
        }
        __syncthreads();
        MFMA_PHASE

        __syncthreads();
#pragma unroll
        for (int i = 0; i < 4; ++i) {
            *(bf16x8*)&As[soff[i]] = rA1[i];
            *(bf16x8*)&Bs[soff[i]] = rB1[i];
        }
        if (k0 + 192 < K) {
            int kn = k0 + 192;
#pragma unroll
            for (int i = 0; i < 4; ++i) {
                rA1[i] = *(const bf16x8*)(A + (size_t)(bm + srow[i]) * lda + kn + skc[i]);
                rB1[i] = *(const bf16x8*)(Bt + (size_t)(bn + srow[i]) * ldb + kn + skc[i]);
            }
        }
        __syncthreads();
        MFMA_PHASE
    }
#undef MFMA_PHASE

#pragma unroll
    for (int mi = 0; mi < 4; ++mi) {
#pragma unroll
        for (int nj = 0; nj < 4; ++nj) {
            int c = bn + wn * 64 + nj * 16 + (lane & 15);
            float bia = bias ? ldin(bias, boff + c, f32w) : 0.f;
#pragma unroll
            for (int r = 0; r < 4; ++r) {
                int row = bm + wm * 64 + mi * 16 + (lane >> 4) * 4 + r;
                float v = acc[mi][nj][r] + bia;
                if (ACT == 1) v = 0.5f * v * (1.0f + erff(v * 0.70710678118654752f));
                if (OUTM == 0) {
                    if (ACCUM) v += tof(C[(size_t)row * N + c]);
                    storev(C + (size_t)row * N + c, v);
                } else {  // OUTM == 2: small Wo -> fp32 state rows (row = b*64+t)
                    ST[(size_t)row * CD + c] = v;
                }
            }
        }
    }
}

// ---------------------------------------------------------------------------
// RoPE (in-place, bf16) on q and k + LDS-tiled transpose of v -> vt.
// PROVEN rounds 12-28.
// ---------------------------------------------------------------------------
__global__ __launch_bounds__(256) void ropeV_kernel(
    bf16* __restrict__ q, bf16* __restrict__ k,
    const bf16* __restrict__ v, bf16* __restrict__ vt)
{
    int t0 = blockIdx.x * 64, hh = blockIdx.y, b = blockIdx.z;
    int tid = threadIdx.x;
    __shared__ short lt[64][72];
    int c = tid & 63;
    int r0 = tid >> 6;
    int ip = c >> 1;
    float inv = powf(10000.f, -(float)(2 * ip) / 64.f);
#pragma unroll
    for (int i = 0; i < 16; ++i) {
        int r = r0 + i * 4;
        int t = t0 + r;
        size_t idx = ((size_t)b * CT + t) * 512 + hh * 64 + c;
        float qv = tof(q[idx]);
        float kv = tof(k[idx]);
        float ang = (float)t * inv;
        float sn, cs;
        sincosf(ang, &sn, &cs);
        float qp = __shfl_xor(qv, 1);
        float kp = __shfl_xor(kv, 1);
        float rq, rk;
        if (c & 1) { rq = qp * sn + qv * cs; rk = kp * sn + kv * cs; }
        else       { rq = qv * cs - qp * sn; rk = kv * cs - kp * sn; }
        q[idx] = __float2bfloat16(rq);
        k[idx] = __float2bfloat16(rk);
        lt[r][c] = ((const short*)v)[idx];
    }
    __syncthreads();
#pragma unroll
    for (int i = 0; i < 16; ++i) {
        int c2 = r0 + i * 4;
        int r2 = c;
        ((short*)vt)[((size_t)(b * CH + hh) * 64 + c2) * CT + t0 + r2] = lt[r2][c2];
    }
}

// ---------------------------------------------------------------------------
// MFMA flash attention (core PROVEN rounds 12-28).
// FUSE=1: grid x=10; epilogue proj1+RoPE -> q1/k1/v1t.
// FUSE=0: grid x=9; tiles 1..8 -> o1mid (batch-major), tile-9 -> o1s.
// ---------------------------------------------------------------------------
template <int FUSE>
__global__ __launch_bounds__(256) void attn_mfma(
    const bf16* __restrict__ q, const bf16* __restrict__ k, const bf16* __restrict__ vt,
    bf16* __restrict__ o,
    int qsb, int qsh, int qst,
    int ksb, int ksh, int kst,
    int seg,
    const bf16* __restrict__ Wq1t, const bf16* __restrict__ Wk1t, const bf16* __restrict__ Wv1t,
    bf16* __restrict__ q1o, bf16* __restrict__ k1o, bf16* __restrict__ v1to)
{
    const int tid = threadIdx.x;
    const int lane = tid & 63;
    const int wrow = tid >> 6;
    const int hh = blockIdx.y, b = blockIdx.z;
    const int qbase = (FUSE ? ((int)gridDim.x - 1 - (int)blockIdx.x)
                            : ((int)gridDim.x - (int)blockIdx.x)) * 64;

    __shared__ __align__(16) short Qs[64 * LP];
    __shared__ __align__(16) short Ks[64 * LP];
    __shared__ __align__(16) short Vs[64 * LP];
    __shared__ __align__(16) short Ps[64 * LP];

    const size_t qb0 = (size_t)b * qsb + (size_t)hh * qsh;
    const size_t kb0 = (size_t)b * ksb + (size_t)hh * ksh;
    const size_t vtb = (size_t)(b * CH + hh) * 64 * CT;

    int srow[2], skc[2], soff[2];
#pragma unroll
    for (int i = 0; i < 2; ++i) {
        int c = i * 256 + tid;
        srow[i] = c >> 3;
        skc[i] = c & 7;
        soff[i] = srow[i] * LP + skc[i] * 8;
    }

    bf16x8 rQ[2], rK[2], rV[2];
#pragma unroll
    for (int i = 0; i < 2; ++i) {
        rQ[i] = *(const bf16x8*)(q + qb0 + (size_t)(qbase + srow[i]) * qst + skc[i] * 8);
        rK[i] = *(const bf16x8*)(k + kb0 + (size_t)srow[i] * kst + skc[i] * 8);
        rV[i] = *(const bf16x8*)(vt + vtb + (size_t)srow[i] * CT + skc[i] * 8);
    }

    float mrow[4], lrow[4];
    f32x4 oacc[4];
#pragma unroll
    for (int r = 0; r < 4; ++r) { mrow[r] = -1e30f; lrow[r] = 0.f; }
#pragma unroll
    for (int nd = 0; nd < 4; ++nd) oacc[nd] = (f32x4){0.f, 0.f, 0.f, 0.f};

    const int ntiles = qbase / 64 + 1;
    for (int ti = 0; ti < ntiles; ++ti) {
        __syncthreads();
        if (ti == 0) {
#pragma unroll
            for (int i = 0; i < 2; ++i) *(bf16x8*)&Qs[soff[i]] = rQ[i];
        }
#pragma unroll
        for (int i = 0; i < 2; ++i) {
            *(bf16x8*)&Ks[soff[i]] = rK[i];
            *(bf16x8*)&Vs[soff[i]] = rV[i];
        }
        if (ti + 1 < ntiles) {
            int j1 = (ti + 1) * 64;
#pragma unroll
            for (int i = 0; i < 2; ++i) {
                rK[i] = *(const bf16x8*)(k + kb0 + (size_t)(j1 + srow[i]) * kst + skc[i] * 8);
                rV[i] = *(const bf16x8*)(vt + vtb + (size_t)srow[i] * CT + j1 + skc[i] * 8);
            }
        }
        __syncthreads();

        f32x4 sacc[4];
#pragma unroll
        for (int nj = 0; nj < 4; ++nj) sacc[nj] = (f32x4){0.f, 0.f, 0.f, 0.f};
#pragma unroll
        for (int kh = 0; kh < 2; ++kh) {
            int cl = kh * 4 + (lane >> 4);
            bf16x8 av = *(const bf16x8*)&Qs[(wrow * 16 + (lane & 15)) * LP + cl * 8];
#pragma unroll
            for (int nj = 0; nj < 4; ++nj) {
                bf16x8 bv = *(const bf16x8*)&Ks[(nj * 16 + (lane & 15)) * LP + cl * 8];
                sacc[nj] = __builtin_amdgcn_mfma_f32_16x16x32_bf16(av, bv, sacc[nj], 0, 0, 0);
            }
        }

        const bool diag = (ti == ntiles - 1);
        float pm[4] = {-1e30f, -1e30f, -1e30f, -1e30f};
#pragma unroll
        for (int nj = 0; nj < 4; ++nj) {
            int col_l = nj * 16 + (lane & 15);
#pragma unroll
            for (int r = 0; r < 4; ++r) {
                int row_l = wrow * 16 + ((lane >> 4) << 2) + r;
                float s = (diag && col_l > row_l) ? -1e30f : sacc[nj][r] * 0.125f;
                sacc[nj][r] = s;
                pm[r] = fmaxf(pm[r], s);
            }
        }
#pragma unroll
        for (int msk = 1; msk < 16; msk <<= 1)
#pragma unroll
            for (int r = 0; r < 4; ++r) pm[r] = fmaxf(pm[r], __shfl_xor(pm[r], msk));

        float corr[4], rs[4] = {0.f, 0.f, 0.f, 0.f};
#pragma unroll
        for (int r = 0; r < 4; ++r) {
            float mn = fmaxf(mrow[r], pm[r]);
            corr[r] = __expf(mrow[r] - mn);
            mrow[r] = mn;
        }
#pragma unroll
        for (int nj = 0; nj < 4; ++nj)
#pragma unroll
            for (int r = 0; r < 4; ++r) {
                float p = __expf(sacc[nj][r] - mrow[r]);
                sacc[nj][r] = p;
                rs[r] += p;
            }
#pragma unroll
        for (int msk = 1; msk < 16; msk <<= 1)
#pragma unroll
            for (int r = 0; r < 4; ++r) rs[r] += __shfl_xor(rs[r], msk);
#pragma unroll
        for (int r = 0; r < 4; ++r) lrow[r] = lrow[r] * corr[r] + rs[r];
#pragma unroll
        for (int nd = 0; nd < 4; ++nd)
#pragma unroll
            for (int r = 0; r < 4; ++r) oacc[nd][r] *= corr[r];

#pragma unroll
        for (int nj = 0; nj < 4; ++nj)
#pragma unroll
            for (int r = 0; r < 4; ++r) {
                bf16 pb = __float2bfloat16(sacc[nj][r]);
                Ps[(wrow * 16 + ((lane >> 4) << 2) + r) * LP + nj * 16 + (lane & 15)] =
                    *(short*)&pb;
            }

#pragma unroll
        for (int kh = 0; kh < 2; ++kh) {
            int cl = kh * 4 + (lane >> 4);
            bf16x8 pa = *(const bf16x8*)&Ps[(wrow * 16 + (lane & 15)) * LP + cl * 8];
#pragma unroll
            for (int nd = 0; nd < 4; ++nd) {
                bf16x8 bv = *(const bf16x8*)&Vs[(nd * 16 + (lane & 15)) * LP + cl * 8];
                oacc[nd] = __builtin_amdgcn_mfma_f32_16x16x32_bf16(pa, bv, oacc[nd], 0, 0, 0);
            }
        }
    }

    if (FUSE == 0) {
        // per-block-uniform destination select (tile granularity == 64)
        bf16* dst;
        int rbase;
        if (qbase == 576) { dst = q1o; rbase = b * 64 - 576; }          // o1s
        else              { dst = o;   rbase = (b * 8 + seg) * 512 - 64; }  // o1mid
#pragma unroll
        for (int nd = 0; nd < 4; ++nd) {
#pragma unroll
            for (int r = 0; r < 4; ++r) {
                int row_g = qbase + wrow * 16 + ((lane >> 4) << 2) + r;
                int col = nd * 16 + (lane & 15);
                dst[(size_t)(rbase + row_g) * 512 + hh * 64 + col] =
                    __float2bfloat16(oacc[nd][r] / lrow[r]);
            }
        }
    } else {
#pragma unroll
        for (int nd = 0; nd < 4; ++nd)
#pragma unroll
            for (int r = 0; r < 4; ++r) {
                int row_l = wrow * 16 + ((lane >> 4) << 2) + r;
                bf16 ob16 = __float2bfloat16(oacc[nd][r] / lrow[r]);
                Qs[row_l * LP + nd * 16 + (lane & 15)] = *(short*)&ob16;
            }
        __syncthreads();

        const size_t whb = (size_t)hh * 4096;
        f32x4 qa[4], ka[4], va[4];
#pragma unroll
        for (int nj = 0; nj < 4; ++nj) {
            qa[nj] = (f32x4){0.f, 0.f, 0.f, 0.f};
            ka[nj] = (f32x4){0.f, 0.f, 0.f, 0.f};
            va[nj] = (f32x4){0.f, 0.f, 0.f, 0.f};
        }
#pragma unroll
        for (int kh = 0; kh < 2; ++kh) {
            int cl = kh * 4 + (lane >> 4);
            bf16x8 av = *(const bf16x8*)&Qs[(wrow * 16 + (lane & 15)) * LP + cl * 8];
#pragma unroll
            for (int nj = 0; nj < 4; ++nj) {
                int rowb = nj * 16 + (lane & 15);
                bf16x8 bq = *(const bf16x8*)(Wq1t + whb + (size_t)rowb * 64 + cl * 8);
                bf16x8 bk = *(const bf16x8*)(Wk1t + whb + (size_t)rowb * 64 + cl * 8);
                bf16x8 bw = *(const bf16x8*)(Wv1t + whb + (size_t)rowb * 64 + cl * 8);
                qa[nj] = __builtin_amdgcn_mfma_f32_16x16x32_bf16(av, bq, qa[nj], 0, 0, 0);
                ka[nj] = __builtin_amdgcn_mfma_f32_16x16x32_bf16(av, bk, ka[nj], 0, 0, 0);
                va[nj] = __builtin_amdgcn_mfma_f32_16x16x32_bf16(av, bw, va[nj], 0, 0, 0);
            }
        }
        const size_t bh = (size_t)(b * CH + hh);
#pragma unroll
        for (int nj = 0; nj < 4; ++nj) {
            int col = nj * 16 + (lane & 15);
            int ip = col >> 1;
            float inv = powf(10000.f, -(float)(2 * ip) / 64.f);
#pragma unroll
            for (int r = 0; r < 4; ++r) {
                int row_l = wrow * 16 + ((lane >> 4) << 2) + r;
                int t = qbase + row_l;
                float ang = (float)t * inv;
                float sn, cs;
                sincosf(ang, &sn, &cs);
                float aq = qa[nj][r], ak = ka[nj][r];
                float pq = __shfl_xor(aq, 1);
                float pk = __shfl_xor(ak, 1);
                float rq, rk;
                if (col & 1) { rq = pq * sn + aq * cs; rk = pk * sn + ak * cs; }
                else         { rq = aq * cs - pq * sn; rk = ak * cs - pk * sn; }
                size_t roff = (bh * CT + t) * 64 + col;
                q1o[roff] = __float2bfloat16(rq);
                k1o[roff] = __float2bfloat16(rk);
                v1to[(bh * 64 + col) * CT + t] = __float2bfloat16(va[nj][r]);
            }
        }
    }
}

// toks = concat([state, x_seg, state]) -> bf16 (PROVEN; separate pass wins)
__global__ __launch_bounds__(256) void build_toks_kernel(
    const void* __restrict__ x, const float* __restrict__ state, bf16* __restrict__ toks,
    int seg, const int* __restrict__ flag)
{
    const int f32w = flag[0];
    int idx = blockIdx.x * 256 + threadIdx.x;  // B*T*D
    int d = idx & (CD - 1);
    int t = (idx >> 10) % CT;
    int b = idx / (CT * CD);
    float v;
    if (t < CST) v = state[(b * CST + t) * CD + d];
    else if (t < CST + CL) v = ldin(x, ((size_t)b * CS + seg * CL + (t - CST)) * CD + d, f32w);
    else v = state[(b * CST + (t - CST - CL)) * CD + d];
    toks[idx] = __float2bfloat16(v);
}

__global__ __launch_bounds__(256) void init_state_kernel(
    const void* __restrict__ s0, float* __restrict__ state, const int* __restrict__ flag)
{
    const int f32w = flag[0];
    int idx = blockIdx.x * 256 + threadIdx.x;  // B*ST*D
    state[idx] = ldin(s0, idx % (CST * CD), f32w);
}

// LayerNorm(ra + x) * g + b.  ra bf16 (PROVEN round 27).
__global__ __launch_bounds__(256) void ln_kernel(
    const bf16* __restrict__ ra, const void* __restrict__ x,
    const void* __restrict__ g, const void* __restrict__ bb,
    void* __restrict__ outp, int out_ext, const int* __restrict__ flag)
{
    const int f32w = flag[0];
    int row = blockIdx.x;
    int tid = threadIdx.x;
    __shared__ float buf[CD];
    __shared__ float red[4];

    float s = 0.f;
    for (int c = tid; c < CD; c += 256) {
        float v = tof(ra[(size_t)row * CD + c]) + ldin(x, (size_t)row * CD + c, f32w);
        buf[c] = v;
        s += v;
    }
#pragma unroll
    for (int off = 32; off; off >>= 1) s += __shfl_xor(s, off);
    if ((tid & 63) == 0) red[tid >> 6] = s;
    __syncthreads();
    float mu = (red[0] + red[1] + red[2] + red[3]) * (1.f / CD);
    __syncthreads();

    float vs = 0.f;
    for (int c = tid; c < CD; c += 256) {
        float d0 = buf[c] - mu;
        vs += d0 * d0;
    }
#pragma unroll
    for (int off = 32; off; off >>= 1) vs += __shfl_xor(vs, off);
    if ((tid & 63) == 0) red[tid >> 6] = vs;
    __syncthreads();
    float var = (red[0] + red[1] + red[2] + red[3]) * (1.f / CD);
    float rs = rsqrtf(var + 1e-5f);

    for (int c = tid; c < CD; c += 256) {
        float y = (buf[c] - mu) * rs * ldin(g, c, f32w) + ldin(bb, c, f32w);
        size_t idx = (size_t)row * CD + c;
        if (!out_ext) {
            ((bf16*)outp)[idx] = __float2bfloat16(y);
        } else if (f32w) {
            ((float*)outp)[idx] = y;
        } else {
            ((bf16*)outp)[idx] = __float2bfloat16(y);
        }
    }
}

extern "C" void kernel_launch(void* const* d_in, const int* in_sizes, int n_in,
                              void* d_out, int out_size, void* d_ws, size_t ws_size,
                              hipStream_t stream)
{
    const void* x      = d_in[0];
    const void* s0     = d_in[1];
    const void* Wq0    = d_in[2];
    const void* Wk0    = d_in[3];
    const void* Wv0    = d_in[4];
    const void* Wq1    = d_in[5];
    const void* Wk1    = d_in[6];
    const void* Wv1    = d_in[7];
    const void* Wo     = d_in[8];
    const void* bo     = d_in[9];
    const void* g_attn = d_in[10];
    const void* b_attn = d_in[11];
    const void* W1     = d_in[12];
    const void* b1     = d_in[13];
    const void* W2     = d_in[14];
    const void* b2     = d_in[15];
    const void* g_mlp  = d_in[16];
    const void* b_mlp  = d_in[17];

    // workspace slot layout BYTE-IDENTICAL to passing rounds 2/6-28 (~90.7 MB)
    int* flag = (int*)d_ws;
    float* f = (float*)((char*)d_ws + 16);
    float* toks_slot = f; f += (size_t)CB * CT * CD;       // bf16 toks
    float* q0_slot = f;  f += (size_t)CB * CH * CT * 64;   // bf16 q0 [1280][512]
    float* k0_slot = f;  f += (size_t)CB * CH * CT * 64;   // bf16 k0
    float* v0_slot = f;  f += (size_t)CB * CH * CT * 64;   // bf16 v0
    float* o0_slot = f;  f += (size_t)CB * CH * CT * 64;   // bf16 v0t
    float* q1_slot = f;  f += (size_t)CB * CH * CT * 64;   // bf16 q1
    float* k1_slot = f;  f += (size_t)CB * CH * CT * 64;   // bf16 k1
    float* v1_slot = f;  f += (size_t)CB * CH * CT * 64;   // bf16 v1t
    float* o1t_slot = f; f += (size_t)CB * CT * (CH * 64); // (unused during segments)
    float* seg_slot = f; f += (size_t)CB * CT * CD;        // (unused during segments)
    float* state = f;   f += (size_t)CB * CST * CD;        // fp32 state
    float* a_slot = f;  f += (size_t)CB * CS * CD;         // bf16 a (half used)
    bf16* h = (bf16*)f;                                    // LN1 out [B*S, D] bf16
    bf16* tail = h + (size_t)CB * CS * CD;                 // 8.39 MB tail slot

    bf16* toks = (bf16*)toks_slot;
    bf16* q0b = (bf16*)q0_slot;
    bf16* k0b = (bf16*)k0_slot;
    bf16* v0b = (bf16*)v0_slot;
    bf16* v0t = (bf16*)o0_slot;
    bf16* q1b = (bf16*)q1_slot;
    bf16* k1b = (bf16*)k1_slot;
    bf16* v1t = (bf16*)v1_slot;
    bf16* ab  = (bf16*)a_slot;                             // [8192][1024] bf16
    bf16* WtQ = h;                                         // h region dead until LN1
    bf16* WtK = WtQ + (size_t)512 * 1024;
    bf16* WtV = WtK + (size_t)512 * 1024;
    bf16* WtO = WtV + (size_t)512 * 1024;                  // [1024][512]
    bf16* WtQ1 = WtO + (size_t)1024 * 512;                 // per-head [8][64][64]
    bf16* WtK1 = WtQ1 + (size_t)8 * 4096;
    bf16* WtV1 = WtK1 + (size_t)8 * 4096;
    // o1mid/o1s after transposed weights in h region (round-26/27-proven fit).
    bf16* o1mid = WtV1 + (size_t)8 * 4096;                 // [B*NSEG*512][512]
    bf16* o1s = o1mid + (size_t)CB * NSEG * 512 * 512;     // [128][512]
    // MLP phase (toks..q1 region dead): g1 at region base, Wt1 after, Wt2 tail.
    bf16* g1  = (bf16*)toks_slot;                          // [8192][1024] 16.78 MB
    bf16* Wt1 = g1 + (size_t)CB * CS * CD;                 // [CDH][CD]    8.39 MB
    bf16* Wt2 = tail;                                      // [CD][CDH]    8.39 MB

    sniff_kernel<<<1, 64, 0, stream>>>(x, flag);
    init_state_kernel<<<(CB * CST * CD) / 256, 256, 0, stream>>>(s0, state, flag);

    transpose3_kernel<<<dim3(8, 16, 3), 256, 0, stream>>>(
        Wq0, Wk0, Wv0, WtQ, WtK, WtV, flag);
    transpose_kernel<<<dim3(16, 8), 256, 0, stream>>>(Wo, WtO, 512, CD, flag);
    transposeH_kernel<<<24, 256, 0, stream>>>(Wq1, Wk1, Wv1, WtQ1, WtK1, WtV1, flag);
    // W2 transpose at startup (PROVEN round 28): overlaps the segment loop.
    transpose_kernel<<<dim3(CD / 64, CDH / 64), 256, 0, stream>>>(W2, Wt2, CDH, CD, flag);

    for (int seg = 0; seg < NSEG; ++seg) {
        build_toks_kernel<<<(CB * CT * CD) / 256, 256, 0, stream>>>(x, state, toks, seg, flag);
        // QKV GEMM (proven path), row-major bf16 outputs
        mfma_lds<bf16, 0, 0, 0><<<dim3(10, 4, 3), 256, 0, stream>>>(
            toks, WtQ, WtK, WtV, q0b, k0b, v0b, nullptr, nullptr, 0,
            CB * CT, 512, CD, CD, CD, 0, flag);
        // RoPE q0,k0 in place + V transpose -> v0t (proven separate pass)
        ropeV_kernel<<<dim3(CT / 64, CH, CB), 256, 0, stream>>>(q0b, k0b, v0b, v0t);
        // attn1 (row-major Q/K + v0t) with FUSED proj1+RoPE epilogue (grid 10)
        attn_mfma<1><<<dim3(CT / 64, CH, CB), 256, 0, stream>>>(
            q0b, k0b, v0t, nullptr,
            CT * 512, 64, 512,
            CT * 512, 64, 512,
            seg,
            WtQ1, WtK1, WtV1, q1b, k1b, v1t);
        // attn2 (head-major Q/K + v1t), grid 9: middle -> o1mid, tile9 -> o1s
        attn_mfma<0><<<dim3(9, CH, CB), 256, 0, stream>>>(
            q1b, k1b, v1t, o1mid,
            CH * CT * 64, CT * 64, 64,
            CH * CT * 64, CT * 64, 64,
            seg,
            nullptr, nullptr, nullptr, o1s, nullptr, nullptr);
        // small Wo: state rows only (M=128, 8 blocks) -> fp32 state
        mfma_lds<bf16, 0, 2, 0><<<dim3(1, 8, 1), 256, 0, stream>>>(
            o1s, WtO, WtO, WtO, ab, ab, ab, state, bo, 0,
            128, CD, 512, 512, 512, seg, flag);
    }

    // big Wo: all middle rows (M=8192, grid 64x8=512 blocks) -> ab (bf16) + bo
    mfma_lds<bf16, 0, 0, 0><<<dim3(64, 8, 1), 256, 0, stream>>>(
        o1mid, WtO, WtO, WtO, ab, ab, ab, nullptr, bo, 0,
        CB * CS, CD, 512, 512, 512, 0, flag);

    // h = LN(ab + x) -> bf16 internal (overwrites WtQ..o1s — dead by now)
    ln_kernel<<<CB * CS, 256, 0, stream>>>(ab, x, g_attn, b_attn, h, 0, flag);

    transpose_kernel<<<dim3(CDH / 64, CD / 64), 256, 0, stream>>>(W1, Wt1, CD, CDH, flag);

    // MLP chunked over the hidden dim (PROVEN rounds 24-28); ab is bf16
    for (int c = 0; c < 4; ++c) {
        mfma_lds<bf16, 1, 0, 0><<<dim3(64, 8, 1), 256, 0, stream>>>(
            h, Wt1 + (size_t)c * 1024 * CD, Wt1, Wt1, g1, g1, g1, nullptr,
            b1, c * 1024, CB * CS, 1024, CD, CD, CD, 0, flag);
        if (c == 0)
            mfma_lds<bf16, 0, 0, 0><<<dim3(64, 8, 1), 256, 0, stream>>>(
                g1, Wt2 + (size_t)c * 1024, Wt2, Wt2, ab, ab, ab, nullptr,
                b2, 0, CB * CS, CD, 1024, 1024, CDH, 0, flag);
        else
            mfma_lds<bf16, 0, 0, 1><<<dim3(64, 8, 1), 256, 0, stream>>>(
                g1, Wt2 + (size_t)c * 1024, Wt2, Wt2, ab, ab, ab, nullptr,
                nullptr, 0, CB * CS, CD, 1024, 1024, CDH, 0, flag);
    }
    ln_kernel<<<CB * CS, 256, 0, stream>>>(ab, x, g_mlp, b_mlp, d_out, 1, flag);
}